// Round 23
// baseline (2563.638 us; speedup 1.0000x reference)
//
#include <hip/hip_runtime.h>

typedef unsigned short u16;
typedef __attribute__((ext_vector_type(8))) __bf16 bf16x8;
typedef __attribute__((ext_vector_type(4))) float f32x4;

#define DEV static __device__ __forceinline__

#define ARENA_BYTES 349700096ULL
__device__ __align__(256) char g_arena[ARENA_BYTES];

DEV float bf2f(u16 u) { return __uint_as_float(((unsigned)u) << 16); }
DEV u16 f2bf(float f) {
    unsigned u = __float_as_uint(f);
    return (u16)((u + 0x7fffu + ((u >> 16) & 1u)) >> 16);
}
// tanh-GELU via sigmoid identity + hw exp (proven r17)
DEV float gelu_fast(float x) {
    float x3 = x * x * x;
    float u = 1.5957691216057308f * x + 0.0713548162726009f * x3;
    return x / (1.f + __expf(-u));
}

// ---- async global->LDS, 16B per lane (m97 pattern; lane i -> ldsbase + i*16) ----
DEV void gload16(const u16* gp, u16* lp) {
    __builtin_amdgcn_global_load_lds((const __attribute__((address_space(1))) void*)gp,
                                     (__attribute__((address_space(3))) void*)lp, 16, 0, 0);
}

// ---- target_positions dtype sniff ----
__global__ __launch_bounds__(256) void k_detect_i64(const int* __restrict__ pos, int nhalf,
                                                    int* __restrict__ flagD) {
    int i = blockIdx.x * 256 + threadIdx.x;
    if (i < nhalf && pos[2 * i + 1] != 0) atomicAnd(flagD, 0);
}

// ---- gather rows of spatial_pos_embed -> bf16 (vectorized: 8 elems/thread) ----
__global__ __launch_bounds__(256) void k_gatherB(const float* __restrict__ spe,
                                                 const int* __restrict__ pos,
                                                 const int* __restrict__ flagD,
                                                 u16* __restrict__ qb) {
    int row = blockIdx.x;
    int p = (*flagD) ? pos[2 * row] : pos[row];
    p = (p < 0) ? 0 : (p > 195 ? 195 : p);
    const float* src = spe + (size_t)p * 768;
    u16* dst = qb + (size_t)row * 768;
    int j = threadIdx.x;               // 96 chunks of 8
    if (j < 96) {
        float4 a = *(const float4*)&src[j * 8];
        float4 b = *(const float4*)&src[j * 8 + 4];
        union { u16 u[8]; int4 v; } t;
        t.u[0] = f2bf(a.x); t.u[1] = f2bf(a.y); t.u[2] = f2bf(a.z); t.u[3] = f2bf(a.w);
        t.u[4] = f2bf(b.x); t.u[5] = f2bf(b.y); t.u[6] = f2bf(b.z); t.u[7] = f2bf(b.w);
        *(int4*)&dst[j * 8] = t.v;
    }
}

// ---- LayerNorm over 768: fp32 in, bf16 out (OUTF32=0) or fp32 out (final) ----
template <int OUTF32>
__global__ __launch_bounds__(256) void k_ln(const float* __restrict__ X,
                                            const float* __restrict__ g,
                                            const float* __restrict__ b,
                                            u16* __restrict__ Ob, float* __restrict__ Of) {
    const int row = blockIdx.x, tid = threadIdx.x;
    const float* xr = X + (size_t)row * 768;
    float v0 = xr[tid], v1 = xr[tid + 256], v2 = xr[tid + 512];
    float s = v0 + v1 + v2, s2 = v0 * v0 + v1 * v1 + v2 * v2;
#pragma unroll
    for (int off = 32; off; off >>= 1) {
        s += __shfl_xor(s, off);
        s2 += __shfl_xor(s2, off);
    }
    __shared__ float red[8];
    const int wid = tid >> 6, lane = tid & 63;
    if (lane == 0) { red[wid] = s; red[4 + wid] = s2; }
    __syncthreads();
    s = red[0] + red[1] + red[2] + red[3];
    s2 = red[4] + red[5] + red[6] + red[7];
    const float mu = s * (1.f / 768.f);
    const float var = fmaxf(s2 * (1.f / 768.f) - mu * mu, 0.f);
    const float rs = rsqrtf(var + 1e-5f);
    size_t o = (size_t)row * 768;
#pragma unroll
    for (int i = 0; i < 3; ++i) {
        int c = tid + 256 * i;
        float vv = (i == 0 ? v0 : (i == 1 ? v1 : v2));
        float y = (vv - mu) * rs * g[c] + b[c];
        if (OUTF32) Of[o + c] = y;
        else        Ob[o + c] = f2bf(y);
    }
}

// ---- batched weight transpose+convert: L layers, W[l][K,N] -> WT[l][N,K] ----
__global__ __launch_bounds__(256) void k_wtransL(const float* __restrict__ W,
                                                 u16* __restrict__ WT, int K, int N,
                                                 long long srcLs, long long dstLs,
                                                 long long per, int L) {
    long long idx = (long long)blockIdx.x * 256 + threadIdx.x;
    if (idx >= per * L) return;
    int l = (int)(idx / per);
    long long r = idx % per;
    int n = (int)(r % N);
    int kc = (int)(r / N);
    const float* Wl = W + (long long)l * srcLs;
    u16* WTl = WT + (long long)l * dstLs;
    union { u16 u[8]; int4 v; } tmp;
#pragma unroll
    for (int j = 0; j < 8; ++j) tmp.u[j] = f2bf(Wl[(size_t)(kc * 8 + j) * N + n]);
    *(int4*)&WTl[(size_t)n * K + kc * 8] = tmp.v;
}

// ---- bf16 MFMA GEMM (r17-proven): 128x128 tile, BK=64, double-buffered 2-phase
//      prefetch, XOR-swizzled gload_lds staging, bijective XCD block swizzle. ----
template <bool GELU_, bool RES_, bool OF32, bool OBF>
__global__ __launch_bounds__(256) void k_gemmB(const u16* __restrict__ A,
                                               const u16* __restrict__ BT,
                                               const float* __restrict__ bias,
                                               const float* __restrict__ R,
                                               float* __restrict__ Cf, u16* __restrict__ Cb,
                                               int M, int N, int K) {
    __shared__ __align__(16) u16 Asm[2][128 * 64];
    __shared__ __align__(16) u16 Bsm[2][128 * 64];
    const int tid = threadIdx.x;
    const int lane = tid & 63;
    const int wid = tid >> 6;
    const int wm = wid >> 1, wn = wid & 1;

    // XCD-chunked bijective swizzle; N-tile-fastest within a chunk (A-panel L2 reuse)
    const int nbx = gridDim.x, nby = gridDim.y;
    const int nwg = nbx * nby;
    const int bid = blockIdx.y * nbx + blockIdx.x;
    const int q8 = nwg >> 3, r8 = nwg & 7;
    const int xcd = bid & 7, pos = bid >> 3;
    const int swz = (xcd < r8 ? xcd * (q8 + 1) : r8 * (q8 + 1) + (xcd - r8) * q8) + pos;
    const int tyy = swz % nby;     // N-tile
    const int txx = swz / nby;     // M-tile

    // staging: lane covers row (lane>>3) in its 8-row group, phys granule (lane&7);
    // global (logical) granule = (lane&7) ^ (lane>>3)  [XOR swizzle, bit-exact r14]
    const int srow = lane >> 3;
    const int sgr = (lane & 7) ^ srow;
    const int fr = lane & 15, g = lane >> 4;
    const int s7 = fr & 7;          // read-side swizzle selector (= row & 7)

    const u16* Ab = A + (size_t)txx * 128 * K + (size_t)srow * K + sgr * 8;
    const u16* Bb = BT + (size_t)tyy * 128 * K + (size_t)srow * K + sgr * 8;

    f32x4 acc[4][4] = {};
    const int nIter = K >> 6;

    // prologue: stage tile 0 into buffer 0
#pragma unroll
    for (int n = 0; n < 4; ++n) {
        const int rg = wid * 32 + n * 8;
        gload16(Ab + (size_t)rg * K, &Asm[0][rg * 64]);
        gload16(Bb + (size_t)rg * K, &Bsm[0][rg * 64]);
    }
    __syncthreads();

    int cur = 0;
    for (int t = 0; t < nIter; ++t) {
        if (t + 1 < nIter) {
            const int k0 = (t + 1) << 6;
#pragma unroll
            for (int n = 0; n < 4; ++n) {
                const int rg = wid * 32 + n * 8;
                gload16(Ab + (size_t)rg * K + k0, &Asm[cur ^ 1][rg * 64]);
                gload16(Bb + (size_t)rg * K + k0, &Bsm[cur ^ 1][rg * 64]);
            }
        }
        const u16* As = &Asm[cur][0];
        const u16* Bs = &Bsm[cur][0];
#pragma unroll
        for (int kk = 0; kk < 2; ++kk) {
            const int gr8 = (((kk * 4 + g) ^ s7) << 3);
            bf16x8 af[4], bfr[4];
#pragma unroll
            for (int i = 0; i < 4; ++i)
                af[i] = *(const bf16x8*)&As[(wm * 64 + i * 16 + fr) * 64 + gr8];
#pragma unroll
            for (int j = 0; j < 4; ++j)
                bfr[j] = *(const bf16x8*)&Bs[(wn * 64 + j * 16 + fr) * 64 + gr8];
#pragma unroll
            for (int i = 0; i < 4; ++i)
#pragma unroll
                for (int j = 0; j < 4; ++j)
                    acc[i][j] = __builtin_amdgcn_mfma_f32_16x16x32_bf16(af[i], bfr[j], acc[i][j], 0, 0, 0);
        }
        __syncthreads();
        cur ^= 1;
    }

    // C/D layout: col=lane&15, row=(lane>>4)*4+reg  [HW-verified m89/m91]
    const int g4 = (lane >> 4) * 4;
#pragma unroll
    for (int j = 0; j < 4; ++j) {
        const int col = tyy * 128 + wn * 64 + j * 16 + fr;
        const float bc = bias[col];
#pragma unroll
        for (int i = 0; i < 4; ++i) {
#pragma unroll
            for (int r = 0; r < 4; ++r) {
                const int row = txx * 128 + wm * 64 + i * 16 + g4 + r;
                float v = acc[i][j][r] + bc;
                if (GELU_) v = gelu_fast(v);
                if (RES_)  v += R[(size_t)row * N + col];
                if (OF32)  Cf[(size_t)row * N + col] = v;
                if (OBF)   Cb[(size_t)row * N + col] = f2bf(v);
            }
        }
    }
}

// ---- MFMA flash attention, bf16 in/out (r22 structure; Q split across gridDim.y) ----
__global__ __launch_bounds__(256) void k_attnM(const u16* __restrict__ Qp, int qs,
                                               const u16* __restrict__ Kp, int ks,
                                               const u16* __restrict__ Vp, int vs,
                                               u16* __restrict__ Op, int os,
                                               int Tq, int Tk) {
    __shared__ u16 kl[208][72];
    __shared__ u16 vt[64][272];
    __shared__ u16 pl[4][16][72];
    const int bh = blockIdx.x, b = bh / 12, h = bh % 12;
    const int tid = threadIdx.x, lane = tid & 63, wid = tid >> 6;
    const int fr = lane & 15, g = lane >> 4, g4 = g * 4;

    // Q-chunk for this block (bit-exact: every row computed exactly once)
    const int chunk = (Tq + gridDim.y - 1) / gridDim.y;
    const int q0 = blockIdx.y * chunk;
    int q1 = q0 + chunk; if (q1 > Tq) q1 = Tq;
    if (q0 >= Tq) return;

    const int Tkp = (Tk + 15) & ~15;
    const int NC = (Tkp + 63) >> 6;
    const int TC = NC << 6;

    // K staging: 16B chunks (8 bf16); rows ks-strided are 16B-aligned for ks in {768,1536,2304}
    const int4 zero4 = {0, 0, 0, 0};
    for (int c = tid; c < Tkp * 8; c += 256) {
        int r = c >> 3, j = c & 7;
        int4 v = (r < Tk) ? *(const int4*)&Kp[((size_t)b * Tk + r) * ks + h * 64 + j * 8]
                          : zero4;
        *(int4*)&kl[r][j * 8] = v;
    }
    // V staging (transposed): vector global read, 8 scalar LDS scatter-writes
    for (int c = tid; c < TC * 8; c += 256) {
        int t = c >> 3, j = c & 7;
        union { u16 u[8]; int4 v; } w;
        w.v = (t < Tk) ? *(const int4*)&Vp[((size_t)b * Tk + t) * vs + h * 64 + j * 8]
                       : zero4;
#pragma unroll
        for (int i = 0; i < 8; ++i) vt[j * 8 + i][t] = w.u[i];
    }
    __syncthreads();

    const int rows = q1 - q0;
    const int NT = (rows + 63) >> 6;
    for (int it = 0; it < NT; ++it) {
        const int qb = q0 + (it << 6) + (wid << 4);
        if (qb >= q1) continue;

        int qr = qb + fr;
        if (qr >= q1) qr = q0;                 // finite dummy row; writes guarded
        const u16* Qrow = Qp + ((size_t)b * Tq + qr) * qs + h * 64;
        bf16x8 afq0 = *(const bf16x8*)&Qrow[g * 8];
        bf16x8 afq1 = *(const bf16x8*)&Qrow[32 + g * 8];

        f32x4 acc_o[4] = {};
        float m_r[4] = {-1e30f, -1e30f, -1e30f, -1e30f};
        float lp[4] = {0.f, 0.f, 0.f, 0.f};

        for (int c = 0; c < NC; ++c) {
            const int tk0 = c << 6;
            int NF = (Tkp - tk0) >> 4;
            if (NF > 4) NF = 4;

            f32x4 acc_s[4] = {};
#pragma unroll
            for (int nf = 0; nf < 4; ++nf) {
                if (nf < NF) {
                    const u16* kr = &kl[tk0 + nf * 16 + fr][0];
                    acc_s[nf] = __builtin_amdgcn_mfma_f32_16x16x32_bf16(
                        afq0, *(const bf16x8*)&kr[g * 8], acc_s[nf], 0, 0, 0);
                    acc_s[nf] = __builtin_amdgcn_mfma_f32_16x16x32_bf16(
                        afq1, *(const bf16x8*)&kr[32 + g * 8], acc_s[nf], 0, 0, 0);
                }
            }
            float pm[4] = {-1e30f, -1e30f, -1e30f, -1e30f};
#pragma unroll
            for (int nf = 0; nf < 4; ++nf) {
                if (nf < NF) {
                    const bool cv = (tk0 + nf * 16 + fr) < Tk;
#pragma unroll
                    for (int r = 0; r < 4; ++r) {
                        float sv = acc_s[nf][r] * 0.125f;
                        acc_s[nf][r] = sv;
                        if (cv) pm[r] = fmaxf(pm[r], sv);
                    }
                }
            }
#pragma unroll
            for (int off = 1; off < 16; off <<= 1)
#pragma unroll
                for (int r = 0; r < 4; ++r) pm[r] = fmaxf(pm[r], __shfl_xor(pm[r], off));
            float al[4];
#pragma unroll
            for (int r = 0; r < 4; ++r) {
                float mn = fmaxf(m_r[r], pm[r]);
                al[r] = __expf(m_r[r] - mn);
                m_r[r] = mn;
                lp[r] *= al[r];
            }
#pragma unroll
            for (int nfd = 0; nfd < 4; ++nfd)
#pragma unroll
                for (int r = 0; r < 4; ++r) acc_o[nfd][r] *= al[r];
#pragma unroll
            for (int nf = 0; nf < 4; ++nf) {
                const bool cv = (nf < NF) && ((tk0 + nf * 16 + fr) < Tk);
#pragma unroll
                for (int r = 0; r < 4; ++r) {
                    float w = cv ? __expf(acc_s[nf][r] - m_r[r]) : 0.f;
                    lp[r] += w;
                    pl[wid][g4 + r][nf * 16 + fr] = f2bf(w);
                }
            }
#pragma unroll
            for (int ksp = 0; ksp < 2; ++ksp) {
                bf16x8 ap = *(const bf16x8*)&pl[wid][fr][ksp * 32 + g * 8];
#pragma unroll
                for (int nfd = 0; nfd < 4; ++nfd)
                    acc_o[nfd] = __builtin_amdgcn_mfma_f32_16x16x32_bf16(
                        ap, *(const bf16x8*)&vt[nfd * 16 + fr][tk0 + ksp * 32 + g * 8],
                        acc_o[nfd], 0, 0, 0);
            }
        }
#pragma unroll
        for (int off = 1; off < 16; off <<= 1)
#pragma unroll
            for (int r = 0; r < 4; ++r) lp[r] += __shfl_xor(lp[r], off);
#pragma unroll
        for (int r = 0; r < 4; ++r) {
            int qrow = qb + g4 + r;
            if (qrow < q1) {
                float inv = 1.f / lp[r];
#pragma unroll
                for (int nfd = 0; nfd < 4; ++nfd)
                    Op[((size_t)b * Tq + qrow) * os + h * 64 + nfd * 16 + fr] =
                        f2bf(acc_o[nfd][r] * inv);
            }
        }
    }
}

// =======================================================================================
extern "C" void kernel_launch(void* const* d_in, const int* in_sizes, int n_in,
                              void* d_out, int out_size, void* d_ws, size_t ws_size,
                              hipStream_t stream) {
    const int D = 768, FF = 3072, NB = 64, S = 196, T = 98, NL = 3;
    const int Menc = NB * S;   // 12544
    const int Mdec = NB * T;   // 6272

    auto IN = [&](int i) { return (const float*)d_in[i]; };
    const int* tpos = (const int*)d_in[1];
    const float* spe = IN(2);
    const float* norm_g = IN(3);
    const float* norm_b = IN(4);

    char* base;
    if (ws_size >= ARENA_BYTES) {
        base = (char*)d_ws;
    } else {
        void* sym = nullptr;
        if (hipGetSymbolAddress(&sym, HIP_SYMBOL(g_arena)) == hipSuccess && sym)
            base = (char*)sym;
        else
            base = (char*)d_ws;
    }
    char* pp = base;
    auto alloc = [&](long long bytes) -> void* {
        void* r = (void*)pp;
        pp += (bytes + 255) & ~255LL;
        return r;
    };
    int* flag = (int*)alloc(256);
    int* flagD = flag + 1;

    // ---- batched weight pre-conversion: W[L][K,N] fp32 -> WT[L][N,K] bf16 ----
    auto cvb = [&](const float* W, int K, int N, int L, long long dstLs, u16* dst) {
        long long per = (long long)N * (K / 8);
        long long tot = per * L;
        k_wtransL<<<dim3((int)((tot + 255) / 256)), dim3(256), 0, stream>>>(
            W, dst, K, N, (long long)K * N, dstLs, per, L);
    };
    auto cva = [&](const float* W, int K, int N, int L) -> u16* {
        u16* dst = (u16*)alloc((long long)L * K * N * 2);
        cvb(W, K, N, L, (long long)K * N, dst);
        return dst;
    };
    u16* encWqkv = cva(IN(7), D, 3 * D, 3);
    u16* encWo = cva(IN(9), D, D, 3);
    u16* encW1 = cva(IN(13), D, FF, 3);
    u16* encW2 = cva(IN(15), FF, D, 3);
    u16* decWqkv = cva(IN(19), D, 3 * D, 3);
    u16* decWo = cva(IN(21), D, D, 3);
    u16* decW1 = cva(IN(25), D, FF, 3);
    u16* decW2 = cva(IN(27), FF, D, 3);
    u16* caWq = cva(IN(29), D, D, 3);
    u16* caWkv = (u16*)alloc((long long)3 * 2 * D * D * 2);   // [l][wk rows | wv rows][768]
    cvb(IN(31), D, D, 3, (long long)2 * D * D, caWkv);
    cvb(IN(33), D, D, 3, (long long)2 * D * D, caWkv + (long long)D * D);
    u16* caWo = cva(IN(35), D, D, 3);
    float* bkv[3];
    for (int l = 0; l < NL; ++l) {
        bkv[l] = (float*)alloc(2 * D * 4);
        hipMemcpyAsync(bkv[l], IN(32) + l * D, D * 4, hipMemcpyDeviceToDevice, stream);
        hipMemcpyAsync(bkv[l] + D, IN(34) + l * D, D * 4, hipMemcpyDeviceToDevice, stream);
    }

    float* x = (float*)alloc((long long)Menc * D * 4);   // fp32 residual (enc)
    float* q = (float*)alloc((long long)Mdec * D * 4);   // fp32 residual (dec)
    u16* xb = (u16*)alloc((long long)Menc * D * 2);      // bf16 mirror of x
    u16* qb = (u16*)alloc((long long)Mdec * D * 2);      // bf16 mirror of q
    u16* hb = (u16*)alloc((long long)Menc * D * 2);      // bf16 LN/attn out
    u16* s1b = (u16*)alloc((long long)Menc * FF * 2);    // bf16 qkv / ff1 / dec qq,kkvv

    hipMemsetAsync(flagD, 0x01, 4, stream);
    k_detect_i64<<<dim3((Mdec / 2 + 255) / 256), dim3(256), 0, stream>>>(tpos, Mdec / 2, flagD);

    // modes: 0 plain->bf16 | 1 res->fp32+bf16 | 2 gelu->bf16 | 3 plain->fp32+bf16
    auto gemm = [&](int mode, const u16* A, const u16* WT, const float* bias,
                    const float* R, float* Cf, u16* Cb, int M, int N, int K) {
        dim3 g(M / 128, N / 128), blk(256);
        switch (mode) {
            case 0: k_gemmB<false, false, false, true><<<g, blk, 0, stream>>>(A, WT, bias, nullptr, nullptr, Cb, M, N, K); break;
            case 1: k_gemmB<false, true, true, true><<<g, blk, 0, stream>>>(A, WT, bias, R, Cf, Cb, M, N, K); break;
            case 2: k_gemmB<true, false, false, true><<<g, blk, 0, stream>>>(A, WT, bias, nullptr, nullptr, Cb, M, N, K); break;
            case 3: k_gemmB<false, false, true, true><<<g, blk, 0, stream>>>(A, WT, bias, nullptr, Cf, Cb, M, N, K); break;
        }
    };
    auto ln = [&](const float* X, const float* gg, const float* bb, u16* Ob, float* Of, int M) {
        if (Ob) k_ln<0><<<dim3(M), dim3(256), 0, stream>>>(X, gg, bb, Ob, nullptr);
        else    k_ln<1><<<dim3(M), dim3(256), 0, stream>>>(X, gg, bb, nullptr, Of);
    };
    auto attn = [&](const u16* Q, int qs, const u16* Kp, int ks2, const u16* Vp, int vs,
                    u16* O, int Tq, int Tk) {
        int sp = (Tq >= 128) ? 2 : 1;             // split Q-rows across blocks (enc only)
        k_attnM<<<dim3(NB * 12, sp), dim3(256), 0, stream>>>(Q, qs, Kp, ks2, Vp, vs, O, D, Tq, Tk);
    };

    // pre-norm transformer block. Xin: residual input (read-only view for LN1 + first
    // residual-add); Xf/Xb: fp32 residual stream + bf16 mirror. Xin==Xf except enc L0.
    auto tblock = [&](const float* Xin, float* Xf, u16* Xb, int Mtok, int Tseq, int basei,
                      int l, const u16* Wqkv, const u16* Wo, const u16* W1, const u16* W2) {
        const float* ln1g = IN(basei + 0) + l * D;
        const float* ln1b = IN(basei + 1) + l * D;
        const float* bqkv = IN(basei + 3) + l * 3 * D;
        const float* bo = IN(basei + 5) + l * D;
        const float* ln2g = IN(basei + 6) + l * D;
        const float* ln2b = IN(basei + 7) + l * D;
        const float* b1 = IN(basei + 9) + l * FF;
        const float* b2 = IN(basei + 11) + l * D;

        ln(Xin, ln1g, ln1b, hb, nullptr, Mtok);
        gemm(0, hb, Wqkv, bqkv, nullptr, nullptr, s1b, Mtok, 3 * D, D);         // qkv -> bf16
        attn(s1b, 3 * D, s1b + D, 3 * D, s1b + 2 * D, 3 * D, hb, Tseq, Tseq);   // self-attn -> hb
        gemm(1, hb, Wo, bo, Xin, Xf, Xb, Mtok, D, D);                           // Xf = Xin + ao@wo+bo
        ln(Xf, ln2g, ln2b, hb, nullptr, Mtok);
        gemm(2, hb, W1, b1, nullptr, nullptr, s1b, Mtok, FF, D);                // gelu -> bf16
        gemm(1, s1b, W2, b2, Xf, Xf, Xb, Mtok, D, FF);                          // x += ff@w2+b2
    };

    // ---------------- encoder (layer 0 reads ctx directly; no memcpy) ----------------
    for (int l = 0; l < NL; ++l)
        tblock((l == 0) ? IN(0) : x, x, xb, Menc, S, 5, l,
               encWqkv + (long long)l * D * 3 * D, encWo + (long long)l * D * D,
               encW1 + (long long)l * D * FF, encW2 + (long long)l * FF * D);

    // ---------------- decoder ----------------
    k_gatherB<<<dim3(Mdec), dim3(256), 0, stream>>>(spe, tpos, flagD, qb);
    u16* qq = s1b;                                       // [Mdec, D]
    u16* kkvv = s1b + (long long)Mdec * D;               // [Menc, 1536] (kk | vv)
    for (int l = 0; l < NL; ++l) {
        gemm(0, qb, caWq + (long long)l * D * D, IN(30) + l * D, nullptr, nullptr, qq, Mdec, D, D);
        gemm(0, xb, caWkv + (long long)l * 2 * D * D, bkv[l], nullptr, nullptr, kkvv, Menc, 2 * D, D);
        attn(qq, D, kkvv, 2 * D, kkvv + D, 2 * D, hb, T, S);                    // cross-attn
        gemm(3, hb, caWo + (long long)l * D * D, IN(36) + l * D, nullptr, q, qb, Mdec, D, D);
        tblock(q, q, qb, Mdec, T, 17, l,
               decWqkv + (long long)l * D * 3 * D, decWo + (long long)l * D * D,
               decW1 + (long long)l * D * FF, decW2 + (long long)l * FF * D);
    }
    ln(q, norm_g, norm_b, nullptr, (float*)d_out, Mdec);
}

// Round 24
// 2559.207 us; speedup vs baseline: 1.0017x; 1.0017x over previous
//
#include <hip/hip_runtime.h>

typedef unsigned short u16;
typedef __attribute__((ext_vector_type(8))) __bf16 bf16x8;
typedef __attribute__((ext_vector_type(4))) float f32x4;

#define DEV static __device__ __forceinline__

#define ARENA_BYTES 349700096ULL
__device__ __align__(256) char g_arena[ARENA_BYTES];

DEV float bf2f(u16 u) { return __uint_as_float(((unsigned)u) << 16); }
DEV u16 f2bf(float f) {
    unsigned u = __float_as_uint(f);
    return (u16)((u + 0x7fffu + ((u >> 16) & 1u)) >> 16);
}
// tanh-GELU via sigmoid identity + hw exp (proven r17)
DEV float gelu_fast(float x) {
    float x3 = x * x * x;
    float u = 1.5957691216057308f * x + 0.0713548162726009f * x3;
    return x / (1.f + __expf(-u));
}

// ---- async global->LDS, 16B per lane (m97 pattern; lane i -> ldsbase + i*16) ----
DEV void gload16(const u16* gp, u16* lp) {
    __builtin_amdgcn_global_load_lds((const __attribute__((address_space(1))) void*)gp,
                                     (__attribute__((address_space(3))) void*)lp, 16, 0, 0);
}

// ---- target_positions dtype sniff ----
__global__ __launch_bounds__(256) void k_detect_i64(const int* __restrict__ pos, int nhalf,
                                                    int* __restrict__ flagD) {
    int i = blockIdx.x * 256 + threadIdx.x;
    if (i < nhalf && pos[2 * i + 1] != 0) atomicAnd(flagD, 0);
}

// ---- gather rows of spatial_pos_embed -> bf16 (vectorized: 8 elems/thread) ----
__global__ __launch_bounds__(256) void k_gatherB(const float* __restrict__ spe,
                                                 const int* __restrict__ pos,
                                                 const int* __restrict__ flagD,
                                                 u16* __restrict__ qb) {
    int row = blockIdx.x;
    int p = (*flagD) ? pos[2 * row] : pos[row];
    p = (p < 0) ? 0 : (p > 195 ? 195 : p);
    const float* src = spe + (size_t)p * 768;
    u16* dst = qb + (size_t)row * 768;
    int j = threadIdx.x;               // 96 chunks of 8
    if (j < 96) {
        float4 a = *(const float4*)&src[j * 8];
        float4 b = *(const float4*)&src[j * 8 + 4];
        union { u16 u[8]; int4 v; } t;
        t.u[0] = f2bf(a.x); t.u[1] = f2bf(a.y); t.u[2] = f2bf(a.z); t.u[3] = f2bf(a.w);
        t.u[4] = f2bf(b.x); t.u[5] = f2bf(b.y); t.u[6] = f2bf(b.z); t.u[7] = f2bf(b.w);
        *(int4*)&dst[j * 8] = t.v;
    }
}

// ---- LayerNorm over 768 (vectorized): float4 loads, packed stores.
//      threads 0..191 carry 4 elems each; all 256 join the reductions. ----
template <int OUTF32>
__global__ __launch_bounds__(256) void k_ln(const float* __restrict__ X,
                                            const float* __restrict__ g,
                                            const float* __restrict__ b,
                                            u16* __restrict__ Ob, float* __restrict__ Of) {
    const int row = blockIdx.x, tid = threadIdx.x;
    const float* xr = X + (size_t)row * 768;
    const bool act = tid < 192;
    float4 v = act ? *(const float4*)&xr[tid * 4] : float4{0.f, 0.f, 0.f, 0.f};
    float s = v.x + v.y + v.z + v.w;
    float s2 = v.x * v.x + v.y * v.y + v.z * v.z + v.w * v.w;
#pragma unroll
    for (int off = 32; off; off >>= 1) {
        s += __shfl_xor(s, off);
        s2 += __shfl_xor(s2, off);
    }
    __shared__ float red[8];
    const int wid = tid >> 6, lane = tid & 63;
    if (lane == 0) { red[wid] = s; red[4 + wid] = s2; }
    __syncthreads();
    s = red[0] + red[1] + red[2] + red[3];
    s2 = red[4] + red[5] + red[6] + red[7];
    const float mu = s * (1.f / 768.f);
    const float var = fmaxf(s2 * (1.f / 768.f) - mu * mu, 0.f);
    const float rs = rsqrtf(var + 1e-5f);
    if (act) {
        float4 gg = *(const float4*)&g[tid * 4];
        float4 bb = *(const float4*)&b[tid * 4];
        float y0 = (v.x - mu) * rs * gg.x + bb.x;
        float y1 = (v.y - mu) * rs * gg.y + bb.y;
        float y2 = (v.z - mu) * rs * gg.z + bb.z;
        float y3 = (v.w - mu) * rs * gg.w + bb.w;
        if (OUTF32) {
            *(float4*)&Of[(size_t)row * 768 + tid * 4] = float4{y0, y1, y2, y3};
        } else {
            union { u16 u[4]; int2 v2; } t;
            t.u[0] = f2bf(y0); t.u[1] = f2bf(y1); t.u[2] = f2bf(y2); t.u[3] = f2bf(y3);
            *(int2*)&Ob[(size_t)row * 768 + tid * 4] = t.v2;
        }
    }
}

// ---- batched weight transpose+convert: L layers, W[l][K,N] -> WT[l][N,K] ----
__global__ __launch_bounds__(256) void k_wtransL(const float* __restrict__ W,
                                                 u16* __restrict__ WT, int K, int N,
                                                 long long srcLs, long long dstLs,
                                                 long long per, int L) {
    long long idx = (long long)blockIdx.x * 256 + threadIdx.x;
    if (idx >= per * L) return;
    int l = (int)(idx / per);
    long long r = idx % per;
    int n = (int)(r % N);
    int kc = (int)(r / N);
    const float* Wl = W + (long long)l * srcLs;
    u16* WTl = WT + (long long)l * dstLs;
    union { u16 u[8]; int4 v; } tmp;
#pragma unroll
    for (int j = 0; j < 8; ++j) tmp.u[j] = f2bf(Wl[(size_t)(kc * 8 + j) * N + n]);
    *(int4*)&WTl[(size_t)n * K + kc * 8] = tmp.v;
}

// ---- bf16 MFMA GEMM (r17-proven): 128x128 tile, BK=64, double-buffered 2-phase
//      prefetch, XOR-swizzled gload_lds staging, bijective XCD block swizzle. ----
template <bool GELU_, bool RES_, bool OF32, bool OBF>
__global__ __launch_bounds__(256) void k_gemmB(const u16* __restrict__ A,
                                               const u16* __restrict__ BT,
                                               const float* __restrict__ bias,
                                               const float* __restrict__ R,
                                               float* __restrict__ Cf, u16* __restrict__ Cb,
                                               int M, int N, int K) {
    __shared__ __align__(16) u16 Asm[2][128 * 64];
    __shared__ __align__(16) u16 Bsm[2][128 * 64];
    const int tid = threadIdx.x;
    const int lane = tid & 63;
    const int wid = tid >> 6;
    const int wm = wid >> 1, wn = wid & 1;

    // XCD-chunked bijective swizzle; N-tile-fastest within a chunk (A-panel L2 reuse)
    const int nbx = gridDim.x, nby = gridDim.y;
    const int nwg = nbx * nby;
    const int bid = blockIdx.y * nbx + blockIdx.x;
    const int q8 = nwg >> 3, r8 = nwg & 7;
    const int xcd = bid & 7, pos = bid >> 3;
    const int swz = (xcd < r8 ? xcd * (q8 + 1) : r8 * (q8 + 1) + (xcd - r8) * q8) + pos;
    const int tyy = swz % nby;     // N-tile
    const int txx = swz / nby;     // M-tile

    // staging: lane covers row (lane>>3) in its 8-row group, phys granule (lane&7);
    // global (logical) granule = (lane&7) ^ (lane>>3)  [XOR swizzle, bit-exact r14]
    const int srow = lane >> 3;
    const int sgr = (lane & 7) ^ srow;
    const int fr = lane & 15, g = lane >> 4;
    const int s7 = fr & 7;          // read-side swizzle selector (= row & 7)

    const u16* Ab = A + (size_t)txx * 128 * K + (size_t)srow * K + sgr * 8;
    const u16* Bb = BT + (size_t)tyy * 128 * K + (size_t)srow * K + sgr * 8;

    f32x4 acc[4][4] = {};
    const int nIter = K >> 6;

    // prologue: stage tile 0 into buffer 0
#pragma unroll
    for (int n = 0; n < 4; ++n) {
        const int rg = wid * 32 + n * 8;
        gload16(Ab + (size_t)rg * K, &Asm[0][rg * 64]);
        gload16(Bb + (size_t)rg * K, &Bsm[0][rg * 64]);
    }
    __syncthreads();

    int cur = 0;
    for (int t = 0; t < nIter; ++t) {
        if (t + 1 < nIter) {
            const int k0 = (t + 1) << 6;
#pragma unroll
            for (int n = 0; n < 4; ++n) {
                const int rg = wid * 32 + n * 8;
                gload16(Ab + (size_t)rg * K + k0, &Asm[cur ^ 1][rg * 64]);
                gload16(Bb + (size_t)rg * K + k0, &Bsm[cur ^ 1][rg * 64]);
            }
        }
        const u16* As = &Asm[cur][0];
        const u16* Bs = &Bsm[cur][0];
#pragma unroll
        for (int kk = 0; kk < 2; ++kk) {
            const int gr8 = (((kk * 4 + g) ^ s7) << 3);
            bf16x8 af[4], bfr[4];
#pragma unroll
            for (int i = 0; i < 4; ++i)
                af[i] = *(const bf16x8*)&As[(wm * 64 + i * 16 + fr) * 64 + gr8];
#pragma unroll
            for (int j = 0; j < 4; ++j)
                bfr[j] = *(const bf16x8*)&Bs[(wn * 64 + j * 16 + fr) * 64 + gr8];
#pragma unroll
            for (int i = 0; i < 4; ++i)
#pragma unroll
                for (int j = 0; j < 4; ++j)
                    acc[i][j] = __builtin_amdgcn_mfma_f32_16x16x32_bf16(af[i], bfr[j], acc[i][j], 0, 0, 0);
        }
        __syncthreads();
        cur ^= 1;
    }

    // C/D layout: col=lane&15, row=(lane>>4)*4+reg  [HW-verified m89/m91]
    const int g4 = (lane >> 4) * 4;
#pragma unroll
    for (int j = 0; j < 4; ++j) {
        const int col = tyy * 128 + wn * 64 + j * 16 + fr;
        const float bc = bias[col];
#pragma unroll
        for (int i = 0; i < 4; ++i) {
#pragma unroll
            for (int r = 0; r < 4; ++r) {
                const int row = txx * 128 + wm * 64 + i * 16 + g4 + r;
                float v = acc[i][j][r] + bc;
                if (GELU_) v = gelu_fast(v);
                if (RES_)  v += R[(size_t)row * N + col];
                if (OF32)  Cf[(size_t)row * N + col] = v;
                if (OBF)   Cb[(size_t)row * N + col] = f2bf(v);
            }
        }
    }
}

// ---- MFMA flash attention, bf16 in/out (r22 structure; Q split across gridDim.y) ----
__global__ __launch_bounds__(256) void k_attnM(const u16* __restrict__ Qp, int qs,
                                               const u16* __restrict__ Kp, int ks,
                                               const u16* __restrict__ Vp, int vs,
                                               u16* __restrict__ Op, int os,
                                               int Tq, int Tk) {
    __shared__ u16 kl[208][72];
    __shared__ u16 vt[64][272];
    __shared__ u16 pl[4][16][72];
    const int bh = blockIdx.x, b = bh / 12, h = bh % 12;
    const int tid = threadIdx.x, lane = tid & 63, wid = tid >> 6;
    const int fr = lane & 15, g = lane >> 4, g4 = g * 4;

    // Q-chunk for this block (bit-exact: every row computed exactly once)
    const int chunk = (Tq + gridDim.y - 1) / gridDim.y;
    const int q0 = blockIdx.y * chunk;
    int q1 = q0 + chunk; if (q1 > Tq) q1 = Tq;
    if (q0 >= Tq) return;

    const int Tkp = (Tk + 15) & ~15;
    const int NC = (Tkp + 63) >> 6;
    const int TC = NC << 6;

    // K staging: 16B chunks (8 bf16)
    const int4 zero4 = {0, 0, 0, 0};
    for (int c = tid; c < Tkp * 8; c += 256) {
        int r = c >> 3, j = c & 7;
        int4 v = (r < Tk) ? *(const int4*)&Kp[((size_t)b * Tk + r) * ks + h * 64 + j * 8]
                          : zero4;
        *(int4*)&kl[r][j * 8] = v;
    }
    // V staging (transposed): vector global read, 8 scalar LDS scatter-writes
    for (int c = tid; c < TC * 8; c += 256) {
        int t = c >> 3, j = c & 7;
        union { u16 u[8]; int4 v; } w;
        w.v = (t < Tk) ? *(const int4*)&Vp[((size_t)b * Tk + t) * vs + h * 64 + j * 8]
                       : zero4;
#pragma unroll
        for (int i = 0; i < 8; ++i) vt[j * 8 + i][t] = w.u[i];
    }
    __syncthreads();

    const int rows = q1 - q0;
    const int NT = (rows + 63) >> 6;
    for (int it = 0; it < NT; ++it) {
        const int qb = q0 + (it << 6) + (wid << 4);
        if (qb >= q1) continue;

        int qr = qb + fr;
        if (qr >= q1) qr = q0;
        const u16* Qrow = Qp + ((size_t)b * Tq + qr) * qs + h * 64;
        bf16x8 afq0 = *(const bf16x8*)&Qrow[g * 8];
        bf16x8 afq1 = *(const bf16x8*)&Qrow[32 + g * 8];

        f32x4 acc_o[4] = {};
        float m_r[4] = {-1e30f, -1e30f, -1e30f, -1e30f};
        float lp[4] = {0.f, 0.f, 0.f, 0.f};

        for (int c = 0; c < NC; ++c) {
            const int tk0 = c << 6;
            int NF = (Tkp - tk0) >> 4;
            if (NF > 4) NF = 4;

            f32x4 acc_s[4] = {};
#pragma unroll
            for (int nf = 0; nf < 4; ++nf) {
                if (nf < NF) {
                    const u16* kr = &kl[tk0 + nf * 16 + fr][0];
                    acc_s[nf] = __builtin_amdgcn_mfma_f32_16x16x32_bf16(
                        afq0, *(const bf16x8*)&kr[g * 8], acc_s[nf], 0, 0, 0);
                    acc_s[nf] = __builtin_amdgcn_mfma_f32_16x16x32_bf16(
                        afq1, *(const bf16x8*)&kr[32 + g * 8], acc_s[nf], 0, 0, 0);
                }
            }
            float pm[4] = {-1e30f, -1e30f, -1e30f, -1e30f};
#pragma unroll
            for (int nf = 0; nf < 4; ++nf) {
                if (nf < NF) {
                    const bool cv = (tk0 + nf * 16 + fr) < Tk;
#pragma unroll
                    for (int r = 0; r < 4; ++r) {
                        float sv = acc_s[nf][r] * 0.125f;
                        acc_s[nf][r] = sv;
                        if (cv) pm[r] = fmaxf(pm[r], sv);
                    }
                }
            }
#pragma unroll
            for (int off = 1; off < 16; off <<= 1)
#pragma unroll
                for (int r = 0; r < 4; ++r) pm[r] = fmaxf(pm[r], __shfl_xor(pm[r], off));
            float al[4];
#pragma unroll
            for (int r = 0; r < 4; ++r) {
                float mn = fmaxf(m_r[r], pm[r]);
                al[r] = __expf(m_r[r] - mn);
                m_r[r] = mn;
                lp[r] *= al[r];
            }
#pragma unroll
            for (int nfd = 0; nfd < 4; ++nfd)
#pragma unroll
                for (int r = 0; r < 4; ++r) acc_o[nfd][r] *= al[r];
#pragma unroll
            for (int nf = 0; nf < 4; ++nf) {
                const bool cv = (nf < NF) && ((tk0 + nf * 16 + fr) < Tk);
#pragma unroll
                for (int r = 0; r < 4; ++r) {
                    float w = cv ? __expf(acc_s[nf][r] - m_r[r]) : 0.f;
                    lp[r] += w;
                    pl[wid][g4 + r][nf * 16 + fr] = f2bf(w);
                }
            }
#pragma unroll
            for (int ksp = 0; ksp < 2; ++ksp) {
                bf16x8 ap = *(const bf16x8*)&pl[wid][fr][ksp * 32 + g * 8];
#pragma unroll
                for (int nfd = 0; nfd < 4; ++nfd)
                    acc_o[nfd] = __builtin_amdgcn_mfma_f32_16x16x32_bf16(
                        ap, *(const bf16x8*)&vt[nfd * 16 + fr][tk0 + ksp * 32 + g * 8],
                        acc_o[nfd], 0, 0, 0);
            }
        }
#pragma unroll
        for (int off = 1; off < 16; off <<= 1)
#pragma unroll
            for (int r = 0; r < 4; ++r) lp[r] += __shfl_xor(lp[r], off);
#pragma unroll
        for (int r = 0; r < 4; ++r) {
            int qrow = qb + g4 + r;
            if (qrow < q1) {
                float inv = 1.f / lp[r];
#pragma unroll
                for (int nfd = 0; nfd < 4; ++nfd)
                    Op[((size_t)b * Tq + qrow) * os + h * 64 + nfd * 16 + fr] =
                        f2bf(acc_o[nfd][r] * inv);
            }
        }
    }
}

// =======================================================================================
extern "C" void kernel_launch(void* const* d_in, const int* in_sizes, int n_in,
                              void* d_out, int out_size, void* d_ws, size_t ws_size,
                              hipStream_t stream) {
    const int D = 768, FF = 3072, NB = 64, S = 196, T = 98, NL = 3;
    const int Menc = NB * S;   // 12544
    const int Mdec = NB * T;   // 6272

    auto IN = [&](int i) { return (const float*)d_in[i]; };
    const int* tpos = (const int*)d_in[1];
    const float* spe = IN(2);
    const float* norm_g = IN(3);
    const float* norm_b = IN(4);

    char* base;
    if (ws_size >= ARENA_BYTES) {
        base = (char*)d_ws;
    } else {
        void* sym = nullptr;
        if (hipGetSymbolAddress(&sym, HIP_SYMBOL(g_arena)) == hipSuccess && sym)
            base = (char*)sym;
        else
            base = (char*)d_ws;
    }
    char* pp = base;
    auto alloc = [&](long long bytes) -> void* {
        void* r = (void*)pp;
        pp += (bytes + 255) & ~255LL;
        return r;
    };
    int* flag = (int*)alloc(256);
    int* flagD = flag + 1;

    // ---- batched weight pre-conversion: W[L][K,N] fp32 -> WT[L][N,K] bf16 ----
    auto cvb = [&](const float* W, int K, int N, int L, long long dstLs, u16* dst) {
        long long per = (long long)N * (K / 8);
        long long tot = per * L;
        k_wtransL<<<dim3((int)((tot + 255) / 256)), dim3(256), 0, stream>>>(
            W, dst, K, N, (long long)K * N, dstLs, per, L);
    };
    auto cva = [&](const float* W, int K, int N, int L) -> u16* {
        u16* dst = (u16*)alloc((long long)L * K * N * 2);
        cvb(W, K, N, L, (long long)K * N, dst);
        return dst;
    };
    u16* encWqkv = cva(IN(7), D, 3 * D, 3);
    u16* encWo = cva(IN(9), D, D, 3);
    u16* encW1 = cva(IN(13), D, FF, 3);
    u16* encW2 = cva(IN(15), FF, D, 3);
    u16* decWqkv = cva(IN(19), D, 3 * D, 3);
    u16* decWo = cva(IN(21), D, D, 3);
    u16* decW1 = cva(IN(25), D, FF, 3);
    u16* decW2 = cva(IN(27), FF, D, 3);
    u16* caWq = cva(IN(29), D, D, 3);
    u16* caWkv = (u16*)alloc((long long)3 * 2 * D * D * 2);   // [l][wk rows | wv rows][768]
    cvb(IN(31), D, D, 3, (long long)2 * D * D, caWkv);
    cvb(IN(33), D, D, 3, (long long)2 * D * D, caWkv + (long long)D * D);
    u16* caWo = cva(IN(35), D, D, 3);
    float* bkv[3];
    for (int l = 0; l < NL; ++l) {
        bkv[l] = (float*)alloc(2 * D * 4);
        hipMemcpyAsync(bkv[l], IN(32) + l * D, D * 4, hipMemcpyDeviceToDevice, stream);
        hipMemcpyAsync(bkv[l] + D, IN(34) + l * D, D * 4, hipMemcpyDeviceToDevice, stream);
    }

    float* x = (float*)alloc((long long)Menc * D * 4);   // fp32 residual (enc)
    float* q = (float*)alloc((long long)Mdec * D * 4);   // fp32 residual (dec)
    u16* xb = (u16*)alloc((long long)Menc * D * 2);      // bf16 mirror of x
    u16* qb = (u16*)alloc((long long)Mdec * D * 2);      // bf16 mirror of q
    u16* hb = (u16*)alloc((long long)Menc * D * 2);      // bf16 LN/attn out
    u16* s1b = (u16*)alloc((long long)Menc * FF * 2);    // bf16 qkv / ff1 / dec qq,kkvv

    hipMemsetAsync(flagD, 0x01, 4, stream);
    k_detect_i64<<<dim3((Mdec / 2 + 255) / 256), dim3(256), 0, stream>>>(tpos, Mdec / 2, flagD);

    // modes: 0 plain->bf16 | 1 res->fp32+bf16 | 2 gelu->bf16 | 3 plain->fp32+bf16
    auto gemm = [&](int mode, const u16* A, const u16* WT, const float* bias,
                    const float* R, float* Cf, u16* Cb, int M, int N, int K) {
        dim3 g(M / 128, N / 128), blk(256);
        switch (mode) {
            case 0: k_gemmB<false, false, false, true><<<g, blk, 0, stream>>>(A, WT, bias, nullptr, nullptr, Cb, M, N, K); break;
            case 1: k_gemmB<false, true, true, true><<<g, blk, 0, stream>>>(A, WT, bias, R, Cf, Cb, M, N, K); break;
            case 2: k_gemmB<true, false, false, true><<<g, blk, 0, stream>>>(A, WT, bias, nullptr, nullptr, Cb, M, N, K); break;
            case 3: k_gemmB<false, false, true, true><<<g, blk, 0, stream>>>(A, WT, bias, nullptr, Cf, Cb, M, N, K); break;
        }
    };
    auto ln = [&](const float* X, const float* gg, const float* bb, u16* Ob, float* Of, int M) {
        if (Ob) k_ln<0><<<dim3(M), dim3(256), 0, stream>>>(X, gg, bb, Ob, nullptr);
        else    k_ln<1><<<dim3(M), dim3(256), 0, stream>>>(X, gg, bb, nullptr, Of);
    };
    auto attn = [&](const u16* Q, int qs, const u16* Kp, int ks2, const u16* Vp, int vs,
                    u16* O, int Tq, int Tk) {
        int sp = (Tq >= 128) ? 2 : 1;             // split Q-rows across blocks (enc only)
        k_attnM<<<dim3(NB * 12, sp), dim3(256), 0, stream>>>(Q, qs, Kp, ks2, Vp, vs, O, D, Tq, Tk);
    };

    // pre-norm transformer block. Xin: residual input; Xf/Xb: fp32 residual + bf16 mirror.
    auto tblock = [&](const float* Xin, float* Xf, u16* Xb, int Mtok, int Tseq, int basei,
                      int l, const u16* Wqkv, const u16* Wo, const u16* W1, const u16* W2) {
        const float* ln1g = IN(basei + 0) + l * D;
        const float* ln1b = IN(basei + 1) + l * D;
        const float* bqkv = IN(basei + 3) + l * 3 * D;
        const float* bo = IN(basei + 5) + l * D;
        const float* ln2g = IN(basei + 6) + l * D;
        const float* ln2b = IN(basei + 7) + l * D;
        const float* b1 = IN(basei + 9) + l * FF;
        const float* b2 = IN(basei + 11) + l * D;

        ln(Xin, ln1g, ln1b, hb, nullptr, Mtok);
        gemm(0, hb, Wqkv, bqkv, nullptr, nullptr, s1b, Mtok, 3 * D, D);         // qkv -> bf16
        attn(s1b, 3 * D, s1b + D, 3 * D, s1b + 2 * D, 3 * D, hb, Tseq, Tseq);   // self-attn -> hb
        gemm(1, hb, Wo, bo, Xin, Xf, Xb, Mtok, D, D);                           // Xf = Xin + ao@wo+bo
        ln(Xf, ln2g, ln2b, hb, nullptr, Mtok);
        gemm(2, hb, W1, b1, nullptr, nullptr, s1b, Mtok, FF, D);                // gelu -> bf16
        gemm(1, s1b, W2, b2, Xf, Xf, Xb, Mtok, D, FF);                          // x += ff@w2+b2
    };

    // ---------------- encoder (layer 0 reads ctx directly; no memcpy) ----------------
    for (int l = 0; l < NL; ++l)
        tblock((l == 0) ? IN(0) : x, x, xb, Menc, S, 5, l,
               encWqkv + (long long)l * D * 3 * D, encWo + (long long)l * D * D,
               encW1 + (long long)l * D * FF, encW2 + (long long)l * FF * D);

    // ---------------- decoder ----------------
    k_gatherB<<<dim3(Mdec), dim3(256), 0, stream>>>(spe, tpos, flagD, qb);
    u16* qq = s1b;                                       // [Mdec, D]
    u16* kkvv = s1b + (long long)Mdec * D;               // [Menc, 1536] (kk | vv)
    for (int l = 0; l < NL; ++l) {
        gemm(0, qb, caWq + (long long)l * D * D, IN(30) + l * D, nullptr, nullptr, qq, Mdec, D, D);
        gemm(0, xb, caWkv + (long long)l * 2 * D * D, bkv[l], nullptr, nullptr, kkvv, Menc, 2 * D, D);
        attn(qq, D, kkvv, 2 * D, kkvv + D, 2 * D, hb, T, S);                    // cross-attn
        gemm(3, hb, caWo + (long long)l * D * D, IN(36) + l * D, nullptr, q, qb, Mdec, D, D);
        tblock(q, q, qb, Mdec, T, 17, l,
               decWqkv + (long long)l * D * 3 * D, decWo + (long long)l * D * D,
               decW1 + (long long)l * D * FF, decW2 + (long long)l * FF * D);
    }
    ln(q, norm_g, norm_b, nullptr, (float*)d_out, Mdec);
}

// Round 25
// 2512.979 us; speedup vs baseline: 1.0202x; 1.0184x over previous
//
#include <hip/hip_runtime.h>

typedef unsigned short u16;
typedef __attribute__((ext_vector_type(8))) __bf16 bf16x8;
typedef __attribute__((ext_vector_type(4))) float f32x4;

#define DEV static __device__ __forceinline__

#define ARENA_BYTES 349700096ULL
__device__ __align__(256) char g_arena[ARENA_BYTES];

DEV float bf2f(u16 u) { return __uint_as_float(((unsigned)u) << 16); }
DEV u16 f2bf(float f) {
    unsigned u = __float_as_uint(f);
    return (u16)((u + 0x7fffu + ((u >> 16) & 1u)) >> 16);
}
// tanh-GELU via sigmoid identity + hw exp (proven r17)
DEV float gelu_fast(float x) {
    float x3 = x * x * x;
    float u = 1.5957691216057308f * x + 0.0713548162726009f * x3;
    return x / (1.f + __expf(-u));
}

// ---- async global->LDS, 16B per lane (m97 pattern; lane i -> ldsbase + i*16) ----
DEV void gload16(const u16* gp, u16* lp) {
    __builtin_amdgcn_global_load_lds((const __attribute__((address_space(1))) void*)gp,
                                     (__attribute__((address_space(3))) void*)lp, 16, 0, 0);
}

// ---- target_positions dtype sniff ----
__global__ __launch_bounds__(256) void k_detect_i64(const int* __restrict__ pos, int nhalf,
                                                    int* __restrict__ flagD) {
    int i = blockIdx.x * 256 + threadIdx.x;
    if (i < nhalf && pos[2 * i + 1] != 0) atomicAnd(flagD, 0);
}

// ---- gather rows of spatial_pos_embed -> bf16 (vectorized: 8 elems/thread) ----
__global__ __launch_bounds__(256) void k_gatherB(const float* __restrict__ spe,
                                                 const int* __restrict__ pos,
                                                 const int* __restrict__ flagD,
                                                 u16* __restrict__ qb) {
    int row = blockIdx.x;
    int p = (*flagD) ? pos[2 * row] : pos[row];
    p = (p < 0) ? 0 : (p > 195 ? 195 : p);
    const float* src = spe + (size_t)p * 768;
    u16* dst = qb + (size_t)row * 768;
    int j = threadIdx.x;               // 96 chunks of 8
    if (j < 96) {
        float4 a = *(const float4*)&src[j * 8];
        float4 b = *(const float4*)&src[j * 8 + 4];
        union { u16 u[8]; int4 v; } t;
        t.u[0] = f2bf(a.x); t.u[1] = f2bf(a.y); t.u[2] = f2bf(a.z); t.u[3] = f2bf(a.w);
        t.u[4] = f2bf(b.x); t.u[5] = f2bf(b.y); t.u[6] = f2bf(b.z); t.u[7] = f2bf(b.w);
        *(int4*)&dst[j * 8] = t.v;
    }
}

// ---- LayerNorm over 768 (vectorized, proven-neutral r24) ----
template <int OUTF32>
__global__ __launch_bounds__(256) void k_ln(const float* __restrict__ X,
                                            const float* __restrict__ g,
                                            const float* __restrict__ b,
                                            u16* __restrict__ Ob, float* __restrict__ Of) {
    const int row = blockIdx.x, tid = threadIdx.x;
    const float* xr = X + (size_t)row * 768;
    const bool act = tid < 192;
    float4 v = act ? *(const float4*)&xr[tid * 4] : float4{0.f, 0.f, 0.f, 0.f};
    float s = v.x + v.y + v.z + v.w;
    float s2 = v.x * v.x + v.y * v.y + v.z * v.z + v.w * v.w;
#pragma unroll
    for (int off = 32; off; off >>= 1) {
        s += __shfl_xor(s, off);
        s2 += __shfl_xor(s2, off);
    }
    __shared__ float red[8];
    const int wid = tid >> 6, lane = tid & 63;
    if (lane == 0) { red[wid] = s; red[4 + wid] = s2; }
    __syncthreads();
    s = red[0] + red[1] + red[2] + red[3];
    s2 = red[4] + red[5] + red[6] + red[7];
    const float mu = s * (1.f / 768.f);
    const float var = fmaxf(s2 * (1.f / 768.f) - mu * mu, 0.f);
    const float rs = rsqrtf(var + 1e-5f);
    if (act) {
        float4 gg = *(const float4*)&g[tid * 4];
        float4 bb = *(const float4*)&b[tid * 4];
        float y0 = (v.x - mu) * rs * gg.x + bb.x;
        float y1 = (v.y - mu) * rs * gg.y + bb.y;
        float y2 = (v.z - mu) * rs * gg.z + bb.z;
        float y3 = (v.w - mu) * rs * gg.w + bb.w;
        if (OUTF32) {
            *(float4*)&Of[(size_t)row * 768 + tid * 4] = float4{y0, y1, y2, y3};
        } else {
            union { u16 u[4]; int2 v2; } t;
            t.u[0] = f2bf(y0); t.u[1] = f2bf(y1); t.u[2] = f2bf(y2); t.u[3] = f2bf(y3);
            *(int2*)&Ob[(size_t)row * 768 + tid * 4] = t.v2;
        }
    }
}

// ---- batched weight transpose+convert: L layers, W[l][K,N] -> WT[l][N,K] ----
__global__ __launch_bounds__(256) void k_wtransL(const float* __restrict__ W,
                                                 u16* __restrict__ WT, int K, int N,
                                                 long long srcLs, long long dstLs,
                                                 long long per, int L) {
    long long idx = (long long)blockIdx.x * 256 + threadIdx.x;
    if (idx >= per * L) return;
    int l = (int)(idx / per);
    long long r = idx % per;
    int n = (int)(r % N);
    int kc = (int)(r / N);
    const float* Wl = W + (long long)l * srcLs;
    u16* WTl = WT + (long long)l * dstLs;
    union { u16 u[8]; int4 v; } tmp;
#pragma unroll
    for (int j = 0; j < 8; ++j) tmp.u[j] = f2bf(Wl[(size_t)(kc * 8 + j) * N + n]);
    *(int4*)&WTl[(size_t)n * K + kc * 8] = tmp.v;
}

// ---- bf16 MFMA GEMM (r17-proven): 128x128 tile, BK=64, double-buffered 2-phase
//      prefetch, XOR-swizzled gload_lds staging, bijective XCD block swizzle. ----
template <bool GELU_, bool RES_, bool OF32, bool OBF>
__global__ __launch_bounds__(256) void k_gemmB(const u16* __restrict__ A,
                                               const u16* __restrict__ BT,
                                               const float* __restrict__ bias,
                                               const float* __restrict__ R,
                                               float* __restrict__ Cf, u16* __restrict__ Cb,
                                               int M, int N, int K) {
    __shared__ __align__(16) u16 Asm[2][128 * 64];
    __shared__ __align__(16) u16 Bsm[2][128 * 64];
    const int tid = threadIdx.x;
    const int lane = tid & 63;
    const int wid = tid >> 6;
    const int wm = wid >> 1, wn = wid & 1;

    const int nbx = gridDim.x, nby = gridDim.y;
    const int nwg = nbx * nby;
    const int bid = blockIdx.y * nbx + blockIdx.x;
    const int q8 = nwg >> 3, r8 = nwg & 7;
    const int xcd = bid & 7, pos = bid >> 3;
    const int swz = (xcd < r8 ? xcd * (q8 + 1) : r8 * (q8 + 1) + (xcd - r8) * q8) + pos;
    const int tyy = swz % nby;     // N-tile
    const int txx = swz / nby;     // M-tile

    const int srow = lane >> 3;
    const int sgr = (lane & 7) ^ srow;
    const int fr = lane & 15, g = lane >> 4;
    const int s7 = fr & 7;

    const u16* Ab = A + (size_t)txx * 128 * K + (size_t)srow * K + sgr * 8;
    const u16* Bb = BT + (size_t)tyy * 128 * K + (size_t)srow * K + sgr * 8;

    f32x4 acc[4][4] = {};
    const int nIter = K >> 6;

#pragma unroll
    for (int n = 0; n < 4; ++n) {
        const int rg = wid * 32 + n * 8;
        gload16(Ab + (size_t)rg * K, &Asm[0][rg * 64]);
        gload16(Bb + (size_t)rg * K, &Bsm[0][rg * 64]);
    }
    __syncthreads();

    int cur = 0;
    for (int t = 0; t < nIter; ++t) {
        if (t + 1 < nIter) {
            const int k0 = (t + 1) << 6;
#pragma unroll
            for (int n = 0; n < 4; ++n) {
                const int rg = wid * 32 + n * 8;
                gload16(Ab + (size_t)rg * K + k0, &Asm[cur ^ 1][rg * 64]);
                gload16(Bb + (size_t)rg * K + k0, &Bsm[cur ^ 1][rg * 64]);
            }
        }
        const u16* As = &Asm[cur][0];
        const u16* Bs = &Bsm[cur][0];
#pragma unroll
        for (int kk = 0; kk < 2; ++kk) {
            const int gr8 = (((kk * 4 + g) ^ s7) << 3);
            bf16x8 af[4], bfr[4];
#pragma unroll
            for (int i = 0; i < 4; ++i)
                af[i] = *(const bf16x8*)&As[(wm * 64 + i * 16 + fr) * 64 + gr8];
#pragma unroll
            for (int j = 0; j < 4; ++j)
                bfr[j] = *(const bf16x8*)&Bs[(wn * 64 + j * 16 + fr) * 64 + gr8];
#pragma unroll
            for (int i = 0; i < 4; ++i)
#pragma unroll
                for (int j = 0; j < 4; ++j)
                    acc[i][j] = __builtin_amdgcn_mfma_f32_16x16x32_bf16(af[i], bfr[j], acc[i][j], 0, 0, 0);
        }
        __syncthreads();
        cur ^= 1;
    }

    const int g4 = (lane >> 4) * 4;
#pragma unroll
    for (int j = 0; j < 4; ++j) {
        const int col = tyy * 128 + wn * 64 + j * 16 + fr;
        const float bc = bias[col];
#pragma unroll
        for (int i = 0; i < 4; ++i) {
#pragma unroll
            for (int r = 0; r < 4; ++r) {
                const int row = txx * 128 + wm * 64 + i * 16 + g4 + r;
                float v = acc[i][j][r] + bc;
                if (GELU_) v = gelu_fast(v);
                if (RES_)  v += R[(size_t)row * N + col];
                if (OF32)  Cf[(size_t)row * N + col] = v;
                if (OBF)   Cb[(size_t)row * N + col] = f2bf(v);
            }
        }
    }
}

// ---- dual plain-GEMM: two independent mode-0 problems in one launch (1D grid).
//      Body byte-identical to k_gemmB mode 0; per-block parameter select only. ----
__global__ __launch_bounds__(256) void k_gemmD(const u16* __restrict__ A1,
                                               const u16* __restrict__ W1,
                                               const float* __restrict__ b1,
                                               u16* __restrict__ C1, int M1, int N1,
                                               const u16* __restrict__ A2,
                                               const u16* __restrict__ W2,
                                               const float* __restrict__ b2,
                                               u16* __restrict__ C2, int M2, int N2,
                                               int K, int nb1) {
    __shared__ __align__(16) u16 Asm[2][128 * 64];
    __shared__ __align__(16) u16 Bsm[2][128 * 64];
    const int tid = threadIdx.x;
    const int lane = tid & 63;
    const int wid = tid >> 6;
    const int wm = wid >> 1, wn = wid & 1;

    // select problem (wave-uniform)
    const bool p2 = (int)blockIdx.x >= nb1;
    const u16* A = p2 ? A2 : A1;
    const u16* BT = p2 ? W2 : W1;
    const float* bias = p2 ? b2 : b1;
    u16* Cb = p2 ? C2 : C1;
    const int M = p2 ? M2 : M1;
    const int N = p2 ? N2 : N1;
    const int bidl = (int)blockIdx.x - (p2 ? nb1 : 0);

    const int nbx = M >> 7, nby = N >> 7;
    const int nwg = nbx * nby;
    const int q8 = nwg >> 3, r8 = nwg & 7;
    const int xcd = bidl & 7, pos = bidl >> 3;
    const int swz = (xcd < r8 ? xcd * (q8 + 1) : r8 * (q8 + 1) + (xcd - r8) * q8) + pos;
    const int tyy = swz % nby;
    const int txx = swz / nby;

    const int srow = lane >> 3;
    const int sgr = (lane & 7) ^ srow;
    const int fr = lane & 15, g = lane >> 4;
    const int s7 = fr & 7;

    const u16* Ab = A + (size_t)txx * 128 * K + (size_t)srow * K + sgr * 8;
    const u16* Bb = BT + (size_t)tyy * 128 * K + (size_t)srow * K + sgr * 8;

    f32x4 acc[4][4] = {};
    const int nIter = K >> 6;

#pragma unroll
    for (int n = 0; n < 4; ++n) {
        const int rg = wid * 32 + n * 8;
        gload16(Ab + (size_t)rg * K, &Asm[0][rg * 64]);
        gload16(Bb + (size_t)rg * K, &Bsm[0][rg * 64]);
    }
    __syncthreads();

    int cur = 0;
    for (int t = 0; t < nIter; ++t) {
        if (t + 1 < nIter) {
            const int k0 = (t + 1) << 6;
#pragma unroll
            for (int n = 0; n < 4; ++n) {
                const int rg = wid * 32 + n * 8;
                gload16(Ab + (size_t)rg * K + k0, &Asm[cur ^ 1][rg * 64]);
                gload16(Bb + (size_t)rg * K + k0, &Bsm[cur ^ 1][rg * 64]);
            }
        }
        const u16* As = &Asm[cur][0];
        const u16* Bs = &Bsm[cur][0];
#pragma unroll
        for (int kk = 0; kk < 2; ++kk) {
            const int gr8 = (((kk * 4 + g) ^ s7) << 3);
            bf16x8 af[4], bfr[4];
#pragma unroll
            for (int i = 0; i < 4; ++i)
                af[i] = *(const bf16x8*)&As[(wm * 64 + i * 16 + fr) * 64 + gr8];
#pragma unroll
            for (int j = 0; j < 4; ++j)
                bfr[j] = *(const bf16x8*)&Bs[(wn * 64 + j * 16 + fr) * 64 + gr8];
#pragma unroll
            for (int i = 0; i < 4; ++i)
#pragma unroll
                for (int j = 0; j < 4; ++j)
                    acc[i][j] = __builtin_amdgcn_mfma_f32_16x16x32_bf16(af[i], bfr[j], acc[i][j], 0, 0, 0);
        }
        __syncthreads();
        cur ^= 1;
    }

    const int g4 = (lane >> 4) * 4;
#pragma unroll
    for (int j = 0; j < 4; ++j) {
        const int col = tyy * 128 + wn * 64 + j * 16 + fr;
        const float bc = bias[col];
#pragma unroll
        for (int i = 0; i < 4; ++i) {
#pragma unroll
            for (int r = 0; r < 4; ++r) {
                const int row = txx * 128 + wm * 64 + i * 16 + g4 + r;
                Cb[(size_t)row * N + col] = f2bf(acc[i][j][r] + bc);
            }
        }
    }
}

// ---- MFMA flash attention, bf16 in/out (r22 structure; Q split across gridDim.y) ----
__global__ __launch_bounds__(256) void k_attnM(const u16* __restrict__ Qp, int qs,
                                               const u16* __restrict__ Kp, int ks,
                                               const u16* __restrict__ Vp, int vs,
                                               u16* __restrict__ Op, int os,
                                               int Tq, int Tk) {
    __shared__ u16 kl[208][72];
    __shared__ u16 vt[64][272];
    __shared__ u16 pl[4][16][72];
    const int bh = blockIdx.x, b = bh / 12, h = bh % 12;
    const int tid = threadIdx.x, lane = tid & 63, wid = tid >> 6;
    const int fr = lane & 15, g = lane >> 4, g4 = g * 4;

    const int chunk = (Tq + gridDim.y - 1) / gridDim.y;
    const int q0 = blockIdx.y * chunk;
    int q1 = q0 + chunk; if (q1 > Tq) q1 = Tq;
    if (q0 >= Tq) return;

    const int Tkp = (Tk + 15) & ~15;
    const int NC = (Tkp + 63) >> 6;
    const int TC = NC << 6;

    const int4 zero4 = {0, 0, 0, 0};
    for (int c = tid; c < Tkp * 8; c += 256) {
        int r = c >> 3, j = c & 7;
        int4 v = (r < Tk) ? *(const int4*)&Kp[((size_t)b * Tk + r) * ks + h * 64 + j * 8]
                          : zero4;
        *(int4*)&kl[r][j * 8] = v;
    }
    for (int c = tid; c < TC * 8; c += 256) {
        int t = c >> 3, j = c & 7;
        union { u16 u[8]; int4 v; } w;
        w.v = (t < Tk) ? *(const int4*)&Vp[((size_t)b * Tk + t) * vs + h * 64 + j * 8]
                       : zero4;
#pragma unroll
        for (int i = 0; i < 8; ++i) vt[j * 8 + i][t] = w.u[i];
    }
    __syncthreads();

    const int rows = q1 - q0;
    const int NT = (rows + 63) >> 6;
    for (int it = 0; it < NT; ++it) {
        const int qb = q0 + (it << 6) + (wid << 4);
        if (qb >= q1) continue;

        int qr = qb + fr;
        if (qr >= q1) qr = q0;
        const u16* Qrow = Qp + ((size_t)b * Tq + qr) * qs + h * 64;
        bf16x8 afq0 = *(const bf16x8*)&Qrow[g * 8];
        bf16x8 afq1 = *(const bf16x8*)&Qrow[32 + g * 8];

        f32x4 acc_o[4] = {};
        float m_r[4] = {-1e30f, -1e30f, -1e30f, -1e30f};
        float lp[4] = {0.f, 0.f, 0.f, 0.f};

        for (int c = 0; c < NC; ++c) {
            const int tk0 = c << 6;
            int NF = (Tkp - tk0) >> 4;
            if (NF > 4) NF = 4;

            f32x4 acc_s[4] = {};
#pragma unroll
            for (int nf = 0; nf < 4; ++nf) {
                if (nf < NF) {
                    const u16* kr = &kl[tk0 + nf * 16 + fr][0];
                    acc_s[nf] = __builtin_amdgcn_mfma_f32_16x16x32_bf16(
                        afq0, *(const bf16x8*)&kr[g * 8], acc_s[nf], 0, 0, 0);
                    acc_s[nf] = __builtin_amdgcn_mfma_f32_16x16x32_bf16(
                        afq1, *(const bf16x8*)&kr[32 + g * 8], acc_s[nf], 0, 0, 0);
                }
            }
            float pm[4] = {-1e30f, -1e30f, -1e30f, -1e30f};
#pragma unroll
            for (int nf = 0; nf < 4; ++nf) {
                if (nf < NF) {
                    const bool cv = (tk0 + nf * 16 + fr) < Tk;
#pragma unroll
                    for (int r = 0; r < 4; ++r) {
                        float sv = acc_s[nf][r] * 0.125f;
                        acc_s[nf][r] = sv;
                        if (cv) pm[r] = fmaxf(pm[r], sv);
                    }
                }
            }
#pragma unroll
            for (int off = 1; off < 16; off <<= 1)
#pragma unroll
                for (int r = 0; r < 4; ++r) pm[r] = fmaxf(pm[r], __shfl_xor(pm[r], off));
            float al[4];
#pragma unroll
            for (int r = 0; r < 4; ++r) {
                float mn = fmaxf(m_r[r], pm[r]);
                al[r] = __expf(m_r[r] - mn);
                m_r[r] = mn;
                lp[r] *= al[r];
            }
#pragma unroll
            for (int nfd = 0; nfd < 4; ++nfd)
#pragma unroll
                for (int r = 0; r < 4; ++r) acc_o[nfd][r] *= al[r];
#pragma unroll
            for (int nf = 0; nf < 4; ++nf) {
                const bool cv = (nf < NF) && ((tk0 + nf * 16 + fr) < Tk);
#pragma unroll
                for (int r = 0; r < 4; ++r) {
                    float w = cv ? __expf(acc_s[nf][r] - m_r[r]) : 0.f;
                    lp[r] += w;
                    pl[wid][g4 + r][nf * 16 + fr] = f2bf(w);
                }
            }
#pragma unroll
            for (int ksp = 0; ksp < 2; ++ksp) {
                bf16x8 ap = *(const bf16x8*)&pl[wid][fr][ksp * 32 + g * 8];
#pragma unroll
                for (int nfd = 0; nfd < 4; ++nfd)
                    acc_o[nfd] = __builtin_amdgcn_mfma_f32_16x16x32_bf16(
                        ap, *(const bf16x8*)&vt[nfd * 16 + fr][tk0 + ksp * 32 + g * 8],
                        acc_o[nfd], 0, 0, 0);
            }
        }
#pragma unroll
        for (int off = 1; off < 16; off <<= 1)
#pragma unroll
            for (int r = 0; r < 4; ++r) lp[r] += __shfl_xor(lp[r], off);
#pragma unroll
        for (int r = 0; r < 4; ++r) {
            int qrow = qb + g4 + r;
            if (qrow < q1) {
                float inv = 1.f / lp[r];
#pragma unroll
                for (int nfd = 0; nfd < 4; ++nfd)
                    Op[((size_t)b * Tq + qrow) * os + h * 64 + nfd * 16 + fr] =
                        f2bf(acc_o[nfd][r] * inv);
            }
        }
    }
}

// =======================================================================================
extern "C" void kernel_launch(void* const* d_in, const int* in_sizes, int n_in,
                              void* d_out, int out_size, void* d_ws, size_t ws_size,
                              hipStream_t stream) {
    const int D = 768, FF = 3072, NB = 64, S = 196, T = 98, NL = 3;
    const int Menc = NB * S;   // 12544
    const int Mdec = NB * T;   // 6272

    auto IN = [&](int i) { return (const float*)d_in[i]; };
    const int* tpos = (const int*)d_in[1];
    const float* spe = IN(2);
    const float* norm_g = IN(3);
    const float* norm_b = IN(4);

    char* base;
    if (ws_size >= ARENA_BYTES) {
        base = (char*)d_ws;
    } else {
        void* sym = nullptr;
        if (hipGetSymbolAddress(&sym, HIP_SYMBOL(g_arena)) == hipSuccess && sym)
            base = (char*)sym;
        else
            base = (char*)d_ws;
    }
    char* pp = base;
    auto alloc = [&](long long bytes) -> void* {
        void* r = (void*)pp;
        pp += (bytes + 255) & ~255LL;
        return r;
    };
    int* flag = (int*)alloc(256);
    int* flagD = flag + 1;

    // ---- batched weight pre-conversion: W[L][K,N] fp32 -> WT[L][N,K] bf16 ----
    auto cvb = [&](const float* W, int K, int N, int L, long long dstLs, u16* dst) {
        long long per = (long long)N * (K / 8);
        long long tot = per * L;
        k_wtransL<<<dim3((int)((tot + 255) / 256)), dim3(256), 0, stream>>>(
            W, dst, K, N, (long long)K * N, dstLs, per, L);
    };
    auto cva = [&](const float* W, int K, int N, int L) -> u16* {
        u16* dst = (u16*)alloc((long long)L * K * N * 2);
        cvb(W, K, N, L, (long long)K * N, dst);
        return dst;
    };
    u16* encWqkv = cva(IN(7), D, 3 * D, 3);
    u16* encWo = cva(IN(9), D, D, 3);
    u16* encW1 = cva(IN(13), D, FF, 3);
    u16* encW2 = cva(IN(15), FF, D, 3);
    u16* decWqkv = cva(IN(19), D, 3 * D, 3);
    u16* decWo = cva(IN(21), D, D, 3);
    u16* decW1 = cva(IN(25), D, FF, 3);
    u16* decW2 = cva(IN(27), FF, D, 3);
    u16* caWq = cva(IN(29), D, D, 3);
    u16* caWkv = (u16*)alloc((long long)3 * 2 * D * D * 2);   // [l][wk rows | wv rows][768]
    cvb(IN(31), D, D, 3, (long long)2 * D * D, caWkv);
    cvb(IN(33), D, D, 3, (long long)2 * D * D, caWkv + (long long)D * D);
    u16* caWo = cva(IN(35), D, D, 3);
    float* bkv[3];
    for (int l = 0; l < NL; ++l) {
        bkv[l] = (float*)alloc(2 * D * 4);
        hipMemcpyAsync(bkv[l], IN(32) + l * D, D * 4, hipMemcpyDeviceToDevice, stream);
        hipMemcpyAsync(bkv[l] + D, IN(34) + l * D, D * 4, hipMemcpyDeviceToDevice, stream);
    }

    float* x = (float*)alloc((long long)Menc * D * 4);   // fp32 residual (enc)
    float* q = (float*)alloc((long long)Mdec * D * 4);   // fp32 residual (dec)
    u16* xb = (u16*)alloc((long long)Menc * D * 2);      // bf16 mirror of x
    u16* qb = (u16*)alloc((long long)Mdec * D * 2);      // bf16 mirror of q
    u16* hb = (u16*)alloc((long long)Menc * D * 2);      // bf16 LN/attn out
    u16* s1b = (u16*)alloc((long long)Menc * FF * 2);    // bf16 qkv / ff1 / dec qq,kkvv

    hipMemsetAsync(flagD, 0x01, 4, stream);
    k_detect_i64<<<dim3((Mdec / 2 + 255) / 256), dim3(256), 0, stream>>>(tpos, Mdec / 2, flagD);

    // modes: 0 plain->bf16 | 1 res->fp32+bf16 | 2 gelu->bf16 | 3 plain->fp32+bf16
    auto gemm = [&](int mode, const u16* A, const u16* WT, const float* bias,
                    const float* R, float* Cf, u16* Cb, int M, int N, int K) {
        dim3 g(M / 128, N / 128), blk(256);
        switch (mode) {
            case 0: k_gemmB<false, false, false, true><<<g, blk, 0, stream>>>(A, WT, bias, nullptr, nullptr, Cb, M, N, K); break;
            case 1: k_gemmB<false, true, true, true><<<g, blk, 0, stream>>>(A, WT, bias, R, Cf, Cb, M, N, K); break;
            case 2: k_gemmB<true, false, false, true><<<g, blk, 0, stream>>>(A, WT, bias, nullptr, nullptr, Cb, M, N, K); break;
            case 3: k_gemmB<false, false, true, true><<<g, blk, 0, stream>>>(A, WT, bias, nullptr, Cf, Cb, M, N, K); break;
        }
    };
    auto ln = [&](const float* X, const float* gg, const float* bb, u16* Ob, float* Of, int M) {
        if (Ob) k_ln<0><<<dim3(M), dim3(256), 0, stream>>>(X, gg, bb, Ob, nullptr);
        else    k_ln<1><<<dim3(M), dim3(256), 0, stream>>>(X, gg, bb, nullptr, Of);
    };
    auto attn = [&](const u16* Q, int qs, const u16* Kp, int ks2, const u16* Vp, int vs,
                    u16* O, int Tq, int Tk) {
        int sp = (Tq >= 128) ? 2 : 1;
        k_attnM<<<dim3(NB * 12, sp), dim3(256), 0, stream>>>(Q, qs, Kp, ks2, Vp, vs, O, D, Tq, Tk);
    };

    // pre-norm transformer block. Xin: residual input; Xf/Xb: fp32 residual + bf16 mirror.
    auto tblock = [&](const float* Xin, float* Xf, u16* Xb, int Mtok, int Tseq, int basei,
                      int l, const u16* Wqkv, const u16* Wo, const u16* W1, const u16* W2) {
        const float* ln1g = IN(basei + 0) + l * D;
        const float* ln1b = IN(basei + 1) + l * D;
        const float* bqkv = IN(basei + 3) + l * 3 * D;
        const float* bo = IN(basei + 5) + l * D;
        const float* ln2g = IN(basei + 6) + l * D;
        const float* ln2b = IN(basei + 7) + l * D;
        const float* b1 = IN(basei + 9) + l * FF;
        const float* b2 = IN(basei + 11) + l * D;

        ln(Xin, ln1g, ln1b, hb, nullptr, Mtok);
        gemm(0, hb, Wqkv, bqkv, nullptr, nullptr, s1b, Mtok, 3 * D, D);         // qkv -> bf16
        attn(s1b, 3 * D, s1b + D, 3 * D, s1b + 2 * D, 3 * D, hb, Tseq, Tseq);   // self-attn -> hb
        gemm(1, hb, Wo, bo, Xin, Xf, Xb, Mtok, D, D);                           // Xf = Xin + ao@wo+bo
        ln(Xf, ln2g, ln2b, hb, nullptr, Mtok);
        gemm(2, hb, W1, b1, nullptr, nullptr, s1b, Mtok, FF, D);                // gelu -> bf16
        gemm(1, s1b, W2, b2, Xf, Xf, Xb, Mtok, D, FF);                          // x += ff@w2+b2
    };

    // ---------------- encoder (layer 0 reads ctx directly; no memcpy) ----------------
    for (int l = 0; l < NL; ++l)
        tblock((l == 0) ? IN(0) : x, x, xb, Menc, S, 5, l,
               encWqkv + (long long)l * D * 3 * D, encWo + (long long)l * D * D,
               encW1 + (long long)l * D * FF, encW2 + (long long)l * FF * D);

    // ---------------- decoder ----------------
    k_gatherB<<<dim3(Mdec), dim3(256), 0, stream>>>(spe, tpos, flagD, qb);
    u16* qq = s1b;                                       // [Mdec, D]
    u16* kkvv = s1b + (long long)Mdec * D;               // [Menc, 1536] (kk | vv)
    for (int l = 0; l < NL; ++l) {
        // fused independent pair: qq = qb@wq+bq  AND  kkvv = xb@(wk|wv)+bkv  (one launch)
        {
            const int nb1 = (Mdec / 128) * (D / 128);          // 294
            const int nb2 = (Menc / 128) * (2 * D / 128);      // 1176
            k_gemmD<<<dim3(nb1 + nb2), dim3(256), 0, stream>>>(
                qb, caWq + (long long)l * D * D, IN(30) + l * D, qq, Mdec, D,
                xb, caWkv + (long long)l * 2 * D * D, bkv[l], kkvv, Menc, 2 * D,
                D, nb1);
        }
        attn(qq, D, kkvv, 2 * D, kkvv + D, 2 * D, hb, T, S);                    // cross-attn
        gemm(3, hb, caWo + (long long)l * D * D, IN(36) + l * D, nullptr, q, qb, Mdec, D, D);
        tblock(q, q, qb, Mdec, T, 17, l,
               decWqkv + (long long)l * D * 3 * D, decWo + (long long)l * D * D,
               decW1 + (long long)l * D * FF, decW2 + (long long)l * FF * D);
    }
    ln(q, norm_g, norm_b, nullptr, (float*)d_out, Mdec);
}

// Round 26
// 2462.393 us; speedup vs baseline: 1.0411x; 1.0205x over previous
//
#include <hip/hip_runtime.h>

typedef unsigned short u16;
typedef __attribute__((ext_vector_type(8))) __bf16 bf16x8;
typedef __attribute__((ext_vector_type(4))) float f32x4;

#define DEV static __device__ __forceinline__

#define ARENA_BYTES 349700096ULL
__device__ __align__(256) char g_arena[ARENA_BYTES];

DEV float bf2f(u16 u) { return __uint_as_float(((unsigned)u) << 16); }
DEV u16 f2bf(float f) {
    unsigned u = __float_as_uint(f);
    return (u16)((u + 0x7fffu + ((u >> 16) & 1u)) >> 16);
}
// tanh-GELU via sigmoid identity + hw exp (proven r17)
DEV float gelu_fast(float x) {
    float x3 = x * x * x;
    float u = 1.5957691216057308f * x + 0.0713548162726009f * x3;
    return x / (1.f + __expf(-u));
}

// ---- async global->LDS, 16B per lane (m97 pattern; lane i -> ldsbase + i*16) ----
DEV void gload16(const u16* gp, u16* lp) {
    __builtin_amdgcn_global_load_lds((const __attribute__((address_space(1))) void*)gp,
                                     (__attribute__((address_space(3))) void*)lp, 16, 0, 0);
}

// ---- target_positions dtype sniff ----
__global__ __launch_bounds__(256) void k_detect_i64(const int* __restrict__ pos, int nhalf,
                                                    int* __restrict__ flagD) {
    int i = blockIdx.x * 256 + threadIdx.x;
    if (i < nhalf && pos[2 * i + 1] != 0) atomicAnd(flagD, 0);
}

// ---- gather rows of spatial_pos_embed -> bf16 (vectorized: 8 elems/thread) ----
__global__ __launch_bounds__(256) void k_gatherB(const float* __restrict__ spe,
                                                 const int* __restrict__ pos,
                                                 const int* __restrict__ flagD,
                                                 u16* __restrict__ qb) {
    int row = blockIdx.x;
    int p = (*flagD) ? pos[2 * row] : pos[row];
    p = (p < 0) ? 0 : (p > 195 ? 195 : p);
    const float* src = spe + (size_t)p * 768;
    u16* dst = qb + (size_t)row * 768;
    int j = threadIdx.x;               // 96 chunks of 8
    if (j < 96) {
        float4 a = *(const float4*)&src[j * 8];
        float4 b = *(const float4*)&src[j * 8 + 4];
        union { u16 u[8]; int4 v; } t;
        t.u[0] = f2bf(a.x); t.u[1] = f2bf(a.y); t.u[2] = f2bf(a.z); t.u[3] = f2bf(a.w);
        t.u[4] = f2bf(b.x); t.u[5] = f2bf(b.y); t.u[6] = f2bf(b.z); t.u[7] = f2bf(b.w);
        *(int4*)&dst[j * 8] = t.v;
    }
}

// ---- LayerNorm over 768 (vectorized, proven r24) ----
template <int OUTF32>
__global__ __launch_bounds__(256) void k_ln(const float* __restrict__ X,
                                            const float* __restrict__ g,
                                            const float* __restrict__ b,
                                            u16* __restrict__ Ob, float* __restrict__ Of) {
    const int row = blockIdx.x, tid = threadIdx.x;
    const float* xr = X + (size_t)row * 768;
    const bool act = tid < 192;
    float4 v = act ? *(const float4*)&xr[tid * 4] : float4{0.f, 0.f, 0.f, 0.f};
    float s = v.x + v.y + v.z + v.w;
    float s2 = v.x * v.x + v.y * v.y + v.z * v.z + v.w * v.w;
#pragma unroll
    for (int off = 32; off; off >>= 1) {
        s += __shfl_xor(s, off);
        s2 += __shfl_xor(s2, off);
    }
    __shared__ float red[8];
    const int wid = tid >> 6, lane = tid & 63;
    if (lane == 0) { red[wid] = s; red[4 + wid] = s2; }
    __syncthreads();
    s = red[0] + red[1] + red[2] + red[3];
    s2 = red[4] + red[5] + red[6] + red[7];
    const float mu = s * (1.f / 768.f);
    const float var = fmaxf(s2 * (1.f / 768.f) - mu * mu, 0.f);
    const float rs = rsqrtf(var + 1e-5f);
    if (act) {
        float4 gg = *(const float4*)&g[tid * 4];
        float4 bb = *(const float4*)&b[tid * 4];
        float y0 = (v.x - mu) * rs * gg.x + bb.x;
        float y1 = (v.y - mu) * rs * gg.y + bb.y;
        float y2 = (v.z - mu) * rs * gg.z + bb.z;
        float y3 = (v.w - mu) * rs * gg.w + bb.w;
        if (OUTF32) {
            *(float4*)&Of[(size_t)row * 768 + tid * 4] = float4{y0, y1, y2, y3};
        } else {
            union { u16 u[4]; int2 v2; } t;
            t.u[0] = f2bf(y0); t.u[1] = f2bf(y1); t.u[2] = f2bf(y2); t.u[3] = f2bf(y3);
            *(int2*)&Ob[(size_t)row * 768 + tid * 4] = t.v2;
        }
    }
}

// ---- single-launch batched weight conversion: 12 tensors via descriptor table ----
struct CvD { const float* src; u16* dst; int K; int N; int L;
             long long srcLs; long long dstLs; long long bStart; };
struct CvTab { CvD d[12]; };

__global__ __launch_bounds__(256) void k_wtransAll(CvTab tab) {
    const long long bid = blockIdx.x;
    int di = 0;
#pragma unroll
    for (int i = 1; i < 12; ++i)
        if (bid >= tab.d[i].bStart) di = i;          // wave-uniform scan
    const CvD dd = tab.d[di];
    const long long per = (long long)dd.N * (dd.K >> 3);
    const long long idx = (bid - dd.bStart) * 256 + threadIdx.x;
    if (idx >= per * dd.L) return;
    const int l = (int)(idx / per);
    const long long r = idx % per;
    const int n = (int)(r % dd.N);
    const int kc = (int)(r / dd.N);
    const float* Wl = dd.src + (long long)l * dd.srcLs;
    u16* WTl = dd.dst + (long long)l * dd.dstLs;
    union { u16 u[8]; int4 v; } tmp;
#pragma unroll
    for (int j = 0; j < 8; ++j) tmp.u[j] = f2bf(Wl[(size_t)(kc * 8 + j) * dd.N + n]);
    *(int4*)&WTl[(size_t)n * dd.K + kc * 8] = tmp.v;
}

// ---- bkv assembly: dst[l][0:768]=bk[l], dst[l][768:1536]=bv[l]; 6 blocks ----
__global__ __launch_bounds__(256) void k_bkv(const float* __restrict__ bk,
                                             const float* __restrict__ bv,
                                             float* __restrict__ dst) {
    int l = blockIdx.x >> 1, half = blockIdx.x & 1;
    const float* s = (half ? bv : bk) + l * 768;
    float* d = dst + (long long)l * 1536 + half * 768;
    for (int i = threadIdx.x; i < 768; i += 256) d[i] = s[i];
}

// ---- bf16 MFMA GEMM (r17-proven): 128x128 tile, BK=64, double-buffered 2-phase
//      prefetch, XOR-swizzled gload_lds staging, bijective XCD block swizzle. ----
template <bool GELU_, bool RES_, bool OF32, bool OBF>
__global__ __launch_bounds__(256) void k_gemmB(const u16* __restrict__ A,
                                               const u16* __restrict__ BT,
                                               const float* __restrict__ bias,
                                               const float* __restrict__ R,
                                               float* __restrict__ Cf, u16* __restrict__ Cb,
                                               int M, int N, int K) {
    __shared__ __align__(16) u16 Asm[2][128 * 64];
    __shared__ __align__(16) u16 Bsm[2][128 * 64];
    const int tid = threadIdx.x;
    const int lane = tid & 63;
    const int wid = tid >> 6;
    const int wm = wid >> 1, wn = wid & 1;

    const int nbx = gridDim.x, nby = gridDim.y;
    const int nwg = nbx * nby;
    const int bid = blockIdx.y * nbx + blockIdx.x;
    const int q8 = nwg >> 3, r8 = nwg & 7;
    const int xcd = bid & 7, pos = bid >> 3;
    const int swz = (xcd < r8 ? xcd * (q8 + 1) : r8 * (q8 + 1) + (xcd - r8) * q8) + pos;
    const int tyy = swz % nby;     // N-tile
    const int txx = swz / nby;     // M-tile

    const int srow = lane >> 3;
    const int sgr = (lane & 7) ^ srow;
    const int fr = lane & 15, g = lane >> 4;
    const int s7 = fr & 7;

    const u16* Ab = A + (size_t)txx * 128 * K + (size_t)srow * K + sgr * 8;
    const u16* Bb = BT + (size_t)tyy * 128 * K + (size_t)srow * K + sgr * 8;

    f32x4 acc[4][4] = {};
    const int nIter = K >> 6;

#pragma unroll
    for (int n = 0; n < 4; ++n) {
        const int rg = wid * 32 + n * 8;
        gload16(Ab + (size_t)rg * K, &Asm[0][rg * 64]);
        gload16(Bb + (size_t)rg * K, &Bsm[0][rg * 64]);
    }
    __syncthreads();

    int cur = 0;
    for (int t = 0; t < nIter; ++t) {
        if (t + 1 < nIter) {
            const int k0 = (t + 1) << 6;
#pragma unroll
            for (int n = 0; n < 4; ++n) {
                const int rg = wid * 32 + n * 8;
                gload16(Ab + (size_t)rg * K + k0, &Asm[cur ^ 1][rg * 64]);
                gload16(Bb + (size_t)rg * K + k0, &Bsm[cur ^ 1][rg * 64]);
            }
        }
        const u16* As = &Asm[cur][0];
        const u16* Bs = &Bsm[cur][0];
#pragma unroll
        for (int kk = 0; kk < 2; ++kk) {
            const int gr8 = (((kk * 4 + g) ^ s7) << 3);
            bf16x8 af[4], bfr[4];
#pragma unroll
            for (int i = 0; i < 4; ++i)
                af[i] = *(const bf16x8*)&As[(wm * 64 + i * 16 + fr) * 64 + gr8];
#pragma unroll
            for (int j = 0; j < 4; ++j)
                bfr[j] = *(const bf16x8*)&Bs[(wn * 64 + j * 16 + fr) * 64 + gr8];
#pragma unroll
            for (int i = 0; i < 4; ++i)
#pragma unroll
                for (int j = 0; j < 4; ++j)
                    acc[i][j] = __builtin_amdgcn_mfma_f32_16x16x32_bf16(af[i], bfr[j], acc[i][j], 0, 0, 0);
        }
        __syncthreads();
        cur ^= 1;
    }

    const int g4 = (lane >> 4) * 4;
#pragma unroll
    for (int j = 0; j < 4; ++j) {
        const int col = tyy * 128 + wn * 64 + j * 16 + fr;
        const float bc = bias[col];
#pragma unroll
        for (int i = 0; i < 4; ++i) {
#pragma unroll
            for (int r = 0; r < 4; ++r) {
                const int row = txx * 128 + wm * 64 + i * 16 + g4 + r;
                float v = acc[i][j][r] + bc;
                if (GELU_) v = gelu_fast(v);
                if (RES_)  v += R[(size_t)row * N + col];
                if (OF32)  Cf[(size_t)row * N + col] = v;
                if (OBF)   Cb[(size_t)row * N + col] = f2bf(v);
            }
        }
    }
}

// ---- dual plain-GEMM: two independent mode-0 problems in one launch (proven r25) ----
__global__ __launch_bounds__(256) void k_gemmD(const u16* __restrict__ A1,
                                               const u16* __restrict__ W1,
                                               const float* __restrict__ b1,
                                               u16* __restrict__ C1, int M1, int N1,
                                               const u16* __restrict__ A2,
                                               const u16* __restrict__ W2,
                                               const float* __restrict__ b2,
                                               u16* __restrict__ C2, int M2, int N2,
                                               int K, int nb1) {
    __shared__ __align__(16) u16 Asm[2][128 * 64];
    __shared__ __align__(16) u16 Bsm[2][128 * 64];
    const int tid = threadIdx.x;
    const int lane = tid & 63;
    const int wid = tid >> 6;
    const int wm = wid >> 1, wn = wid & 1;

    const bool p2 = (int)blockIdx.x >= nb1;
    const u16* A = p2 ? A2 : A1;
    const u16* BT = p2 ? W2 : W1;
    const float* bias = p2 ? b2 : b1;
    u16* Cb = p2 ? C2 : C1;
    const int M = p2 ? M2 : M1;
    const int N = p2 ? N2 : N1;
    const int bidl = (int)blockIdx.x - (p2 ? nb1 : 0);

    const int nbx = M >> 7, nby = N >> 7;
    const int nwg = nbx * nby;
    const int q8 = nwg >> 3, r8 = nwg & 7;
    const int xcd = bidl & 7, pos = bidl >> 3;
    const int swz = (xcd < r8 ? xcd * (q8 + 1) : r8 * (q8 + 1) + (xcd - r8) * q8) + pos;
    const int tyy = swz % nby;
    const int txx = swz / nby;

    const int srow = lane >> 3;
    const int sgr = (lane & 7) ^ srow;
    const int fr = lane & 15, g = lane >> 4;
    const int s7 = fr & 7;

    const u16* Ab = A + (size_t)txx * 128 * K + (size_t)srow * K + sgr * 8;
    const u16* Bb = BT + (size_t)tyy * 128 * K + (size_t)srow * K + sgr * 8;

    f32x4 acc[4][4] = {};
    const int nIter = K >> 6;

#pragma unroll
    for (int n = 0; n < 4; ++n) {
        const int rg = wid * 32 + n * 8;
        gload16(Ab + (size_t)rg * K, &Asm[0][rg * 64]);
        gload16(Bb + (size_t)rg * K, &Bsm[0][rg * 64]);
    }
    __syncthreads();

    int cur = 0;
    for (int t = 0; t < nIter; ++t) {
        if (t + 1 < nIter) {
            const int k0 = (t + 1) << 6;
#pragma unroll
            for (int n = 0; n < 4; ++n) {
                const int rg = wid * 32 + n * 8;
                gload16(Ab + (size_t)rg * K + k0, &Asm[cur ^ 1][rg * 64]);
                gload16(Bb + (size_t)rg * K + k0, &Bsm[cur ^ 1][rg * 64]);
            }
        }
        const u16* As = &Asm[cur][0];
        const u16* Bs = &Bsm[cur][0];
#pragma unroll
        for (int kk = 0; kk < 2; ++kk) {
            const int gr8 = (((kk * 4 + g) ^ s7) << 3);
            bf16x8 af[4], bfr[4];
#pragma unroll
            for (int i = 0; i < 4; ++i)
                af[i] = *(const bf16x8*)&As[(wm * 64 + i * 16 + fr) * 64 + gr8];
#pragma unroll
            for (int j = 0; j < 4; ++j)
                bfr[j] = *(const bf16x8*)&Bs[(wn * 64 + j * 16 + fr) * 64 + gr8];
#pragma unroll
            for (int i = 0; i < 4; ++i)
#pragma unroll
                for (int j = 0; j < 4; ++j)
                    acc[i][j] = __builtin_amdgcn_mfma_f32_16x16x32_bf16(af[i], bfr[j], acc[i][j], 0, 0, 0);
        }
        __syncthreads();
        cur ^= 1;
    }

    const int g4 = (lane >> 4) * 4;
#pragma unroll
    for (int j = 0; j < 4; ++j) {
        const int col = tyy * 128 + wn * 64 + j * 16 + fr;
        const float bc = bias[col];
#pragma unroll
        for (int i = 0; i < 4; ++i) {
#pragma unroll
            for (int r = 0; r < 4; ++r) {
                const int row = txx * 128 + wm * 64 + i * 16 + g4 + r;
                Cb[(size_t)row * N + col] = f2bf(acc[i][j][r] + bc);
            }
        }
    }
}

// ---- MFMA flash attention, bf16 in/out (r22 structure; Q split across gridDim.y) ----
__global__ __launch_bounds__(256) void k_attnM(const u16* __restrict__ Qp, int qs,
                                               const u16* __restrict__ Kp, int ks,
                                               const u16* __restrict__ Vp, int vs,
                                               u16* __restrict__ Op, int os,
                                               int Tq, int Tk) {
    __shared__ u16 kl[208][72];
    __shared__ u16 vt[64][272];
    __shared__ u16 pl[4][16][72];
    const int bh = blockIdx.x, b = bh / 12, h = bh % 12;
    const int tid = threadIdx.x, lane = tid & 63, wid = tid >> 6;
    const int fr = lane & 15, g = lane >> 4, g4 = g * 4;

    const int chunk = (Tq + gridDim.y - 1) / gridDim.y;
    const int q0 = blockIdx.y * chunk;
    int q1 = q0 + chunk; if (q1 > Tq) q1 = Tq;
    if (q0 >= Tq) return;

    const int Tkp = (Tk + 15) & ~15;
    const int NC = (Tkp + 63) >> 6;
    const int TC = NC << 6;

    const int4 zero4 = {0, 0, 0, 0};
    for (int c = tid; c < Tkp * 8; c += 256) {
        int r = c >> 3, j = c & 7;
        int4 v = (r < Tk) ? *(const int4*)&Kp[((size_t)b * Tk + r) * ks + h * 64 + j * 8]
                          : zero4;
        *(int4*)&kl[r][j * 8] = v;
    }
    for (int c = tid; c < TC * 8; c += 256) {
        int t = c >> 3, j = c & 7;
        union { u16 u[8]; int4 v; } w;
        w.v = (t < Tk) ? *(const int4*)&Vp[((size_t)b * Tk + t) * vs + h * 64 + j * 8]
                       : zero4;
#pragma unroll
        for (int i = 0; i < 8; ++i) vt[j * 8 + i][t] = w.u[i];
    }
    __syncthreads();

    const int rows = q1 - q0;
    const int NT = (rows + 63) >> 6;
    for (int it = 0; it < NT; ++it) {
        const int qb = q0 + (it << 6) + (wid << 4);
        if (qb >= q1) continue;

        int qr = qb + fr;
        if (qr >= q1) qr = q0;
        const u16* Qrow = Qp + ((size_t)b * Tq + qr) * qs + h * 64;
        bf16x8 afq0 = *(const bf16x8*)&Qrow[g * 8];
        bf16x8 afq1 = *(const bf16x8*)&Qrow[32 + g * 8];

        f32x4 acc_o[4] = {};
        float m_r[4] = {-1e30f, -1e30f, -1e30f, -1e30f};
        float lp[4] = {0.f, 0.f, 0.f, 0.f};

        for (int c = 0; c < NC; ++c) {
            const int tk0 = c << 6;
            int NF = (Tkp - tk0) >> 4;
            if (NF > 4) NF = 4;

            f32x4 acc_s[4] = {};
#pragma unroll
            for (int nf = 0; nf < 4; ++nf) {
                if (nf < NF) {
                    const u16* kr = &kl[tk0 + nf * 16 + fr][0];
                    acc_s[nf] = __builtin_amdgcn_mfma_f32_16x16x32_bf16(
                        afq0, *(const bf16x8*)&kr[g * 8], acc_s[nf], 0, 0, 0);
                    acc_s[nf] = __builtin_amdgcn_mfma_f32_16x16x32_bf16(
                        afq1, *(const bf16x8*)&kr[32 + g * 8], acc_s[nf], 0, 0, 0);
                }
            }
            float pm[4] = {-1e30f, -1e30f, -1e30f, -1e30f};
#pragma unroll
            for (int nf = 0; nf < 4; ++nf) {
                if (nf < NF) {
                    const bool cv = (tk0 + nf * 16 + fr) < Tk;
#pragma unroll
                    for (int r = 0; r < 4; ++r) {
                        float sv = acc_s[nf][r] * 0.125f;
                        acc_s[nf][r] = sv;
                        if (cv) pm[r] = fmaxf(pm[r], sv);
                    }
                }
            }
#pragma unroll
            for (int off = 1; off < 16; off <<= 1)
#pragma unroll
                for (int r = 0; r < 4; ++r) pm[r] = fmaxf(pm[r], __shfl_xor(pm[r], off));
            float al[4];
#pragma unroll
            for (int r = 0; r < 4; ++r) {
                float mn = fmaxf(m_r[r], pm[r]);
                al[r] = __expf(m_r[r] - mn);
                m_r[r] = mn;
                lp[r] *= al[r];
            }
#pragma unroll
            for (int nfd = 0; nfd < 4; ++nfd)
#pragma unroll
                for (int r = 0; r < 4; ++r) acc_o[nfd][r] *= al[r];
#pragma unroll
            for (int nf = 0; nf < 4; ++nf) {
                const bool cv = (nf < NF) && ((tk0 + nf * 16 + fr) < Tk);
#pragma unroll
                for (int r = 0; r < 4; ++r) {
                    float w = cv ? __expf(acc_s[nf][r] - m_r[r]) : 0.f;
                    lp[r] += w;
                    pl[wid][g4 + r][nf * 16 + fr] = f2bf(w);
                }
            }
#pragma unroll
            for (int ksp = 0; ksp < 2; ++ksp) {
                bf16x8 ap = *(const bf16x8*)&pl[wid][fr][ksp * 32 + g * 8];
#pragma unroll
                for (int nfd = 0; nfd < 4; ++nfd)
                    acc_o[nfd] = __builtin_amdgcn_mfma_f32_16x16x32_bf16(
                        ap, *(const bf16x8*)&vt[nfd * 16 + fr][tk0 + ksp * 32 + g * 8],
                        acc_o[nfd], 0, 0, 0);
            }
        }
#pragma unroll
        for (int off = 1; off < 16; off <<= 1)
#pragma unroll
            for (int r = 0; r < 4; ++r) lp[r] += __shfl_xor(lp[r], off);
#pragma unroll
        for (int r = 0; r < 4; ++r) {
            int qrow = qb + g4 + r;
            if (qrow < q1) {
                float inv = 1.f / lp[r];
#pragma unroll
                for (int nfd = 0; nfd < 4; ++nfd)
                    Op[((size_t)b * Tq + qrow) * os + h * 64 + nfd * 16 + fr] =
                        f2bf(acc_o[nfd][r] * inv);
            }
        }
    }
}

// =======================================================================================
extern "C" void kernel_launch(void* const* d_in, const int* in_sizes, int n_in,
                              void* d_out, int out_size, void* d_ws, size_t ws_size,
                              hipStream_t stream) {
    const int D = 768, FF = 3072, NB = 64, S = 196, T = 98, NL = 3;
    const int Menc = NB * S;   // 12544
    const int Mdec = NB * T;   // 6272

    auto IN = [&](int i) { return (const float*)d_in[i]; };
    const int* tpos = (const int*)d_in[1];
    const float* spe = IN(2);
    const float* norm_g = IN(3);
    const float* norm_b = IN(4);

    char* base;
    if (ws_size >= ARENA_BYTES) {
        base = (char*)d_ws;
    } else {
        void* sym = nullptr;
        if (hipGetSymbolAddress(&sym, HIP_SYMBOL(g_arena)) == hipSuccess && sym)
            base = (char*)sym;
        else
            base = (char*)d_ws;
    }
    char* pp = base;
    auto alloc = [&](long long bytes) -> void* {
        void* r = (void*)pp;
        pp += (bytes + 255) & ~255LL;
        return r;
    };
    int* flag = (int*)alloc(256);
    int* flagD = flag + 1;

    // ---- single-launch weight conversion: build descriptor table, allocate dsts ----
    CvTab tab;
    long long bcur = 0;
    int slot = 0;
    auto addcv = [&](const float* src, u16* dst, int K, int N, int L,
                     long long srcLs, long long dstLs) {
        long long per = (long long)N * (K / 8);
        tab.d[slot] = CvD{src, dst, K, N, L, srcLs, dstLs, bcur};
        bcur += (per * L + 255) / 256;
        ++slot;
    };
    auto cvaT = [&](const float* W, int K, int N, int L) -> u16* {
        u16* dst = (u16*)alloc((long long)L * K * N * 2);
        addcv(W, dst, K, N, L, (long long)K * N, (long long)K * N);
        return dst;
    };
    u16* encWqkv = cvaT(IN(7), D, 3 * D, 3);
    u16* encWo = cvaT(IN(9), D, D, 3);
    u16* encW1 = cvaT(IN(13), D, FF, 3);
    u16* encW2 = cvaT(IN(15), FF, D, 3);
    u16* decWqkv = cvaT(IN(19), D, 3 * D, 3);
    u16* decWo = cvaT(IN(21), D, D, 3);
    u16* decW1 = cvaT(IN(25), D, FF, 3);
    u16* decW2 = cvaT(IN(27), FF, D, 3);
    u16* caWq = cvaT(IN(29), D, D, 3);
    u16* caWkv = (u16*)alloc((long long)3 * 2 * D * D * 2);   // [l][wk rows | wv rows][768]
    addcv(IN(31), caWkv, D, D, 3, (long long)D * D, (long long)2 * D * D);
    addcv(IN(33), caWkv + (long long)D * D, D, D, 3, (long long)D * D, (long long)2 * D * D);
    u16* caWo = cvaT(IN(35), D, D, 3);
    k_wtransAll<<<dim3((int)bcur), dim3(256), 0, stream>>>(tab);

    // bkv[3] contiguous (each 2*D*4 = 6144 B, 256-aligned -> stride 1536 floats)
    float* bkv0 = (float*)alloc(2 * D * 4);
    float* bkv1 = (float*)alloc(2 * D * 4);
    float* bkv2 = (float*)alloc(2 * D * 4);
    (void)bkv1; (void)bkv2;
    k_bkv<<<dim3(6), dim3(256), 0, stream>>>(IN(32), IN(34), bkv0);

    float* x = (float*)alloc((long long)Menc * D * 4);   // fp32 residual (enc)
    float* q = (float*)alloc((long long)Mdec * D * 4);   // fp32 residual (dec)
    u16* xb = (u16*)alloc((long long)Menc * D * 2);      // bf16 mirror of x
    u16* qb = (u16*)alloc((long long)Mdec * D * 2);      // bf16 mirror of q
    u16* hb = (u16*)alloc((long long)Menc * D * 2);      // bf16 LN/attn out
    u16* s1b = (u16*)alloc((long long)Menc * FF * 2);    // bf16 qkv / ff1 / dec qq,kkvv

    hipMemsetAsync(flagD, 0x01, 4, stream);
    k_detect_i64<<<dim3((Mdec / 2 + 255) / 256), dim3(256), 0, stream>>>(tpos, Mdec / 2, flagD);

    // modes: 0 plain->bf16 | 1 res->fp32+bf16 | 2 gelu->bf16 | 3 plain->fp32+bf16
    auto gemm = [&](int mode, const u16* A, const u16* WT, const float* bias,
                    const float* R, float* Cf, u16* Cb, int M, int N, int K) {
        dim3 g(M / 128, N / 128), blk(256);
        switch (mode) {
            case 0: k_gemmB<false, false, false, true><<<g, blk, 0, stream>>>(A, WT, bias, nullptr, nullptr, Cb, M, N, K); break;
            case 1: k_gemmB<false, true, true, true><<<g, blk, 0, stream>>>(A, WT, bias, R, Cf, Cb, M, N, K); break;
            case 2: k_gemmB<true, false, false, true><<<g, blk, 0, stream>>>(A, WT, bias, nullptr, nullptr, Cb, M, N, K); break;
            case 3: k_gemmB<false, false, true, true><<<g, blk, 0, stream>>>(A, WT, bias, nullptr, Cf, Cb, M, N, K); break;
        }
    };
    auto ln = [&](const float* X, const float* gg, const float* bb, u16* Ob, float* Of, int M) {
        if (Ob) k_ln<0><<<dim3(M), dim3(256), 0, stream>>>(X, gg, bb, Ob, nullptr);
        else    k_ln<1><<<dim3(M), dim3(256), 0, stream>>>(X, gg, bb, nullptr, Of);
    };
    auto attn = [&](const u16* Q, int qs, const u16* Kp, int ks2, const u16* Vp, int vs,
                    u16* O, int Tq, int Tk) {
        int sp = (Tq >= 128) ? 2 : 1;
        k_attnM<<<dim3(NB * 12, sp), dim3(256), 0, stream>>>(Q, qs, Kp, ks2, Vp, vs, O, D, Tq, Tk);
    };

    // pre-norm transformer block. Xin: residual input; Xf/Xb: fp32 residual + bf16 mirror.
    auto tblock = [&](const float* Xin, float* Xf, u16* Xb, int Mtok, int Tseq, int basei,
                      int l, const u16* Wqkv, const u16* Wo, const u16* W1, const u16* W2) {
        const float* ln1g = IN(basei + 0) + l * D;
        const float* ln1b = IN(basei + 1) + l * D;
        const float* bqkv = IN(basei + 3) + l * 3 * D;
        const float* bo = IN(basei + 5) + l * D;
        const float* ln2g = IN(basei + 6) + l * D;
        const float* ln2b = IN(basei + 7) + l * D;
        const float* b1 = IN(basei + 9) + l * FF;
        const float* b2 = IN(basei + 11) + l * D;

        ln(Xin, ln1g, ln1b, hb, nullptr, Mtok);
        gemm(0, hb, Wqkv, bqkv, nullptr, nullptr, s1b, Mtok, 3 * D, D);         // qkv -> bf16
        attn(s1b, 3 * D, s1b + D, 3 * D, s1b + 2 * D, 3 * D, hb, Tseq, Tseq);   // self-attn -> hb
        gemm(1, hb, Wo, bo, Xin, Xf, Xb, Mtok, D, D);                           // Xf = Xin + ao@wo+bo
        ln(Xf, ln2g, ln2b, hb, nullptr, Mtok);
        gemm(2, hb, W1, b1, nullptr, nullptr, s1b, Mtok, FF, D);                // gelu -> bf16
        gemm(1, s1b, W2, b2, Xf, Xf, Xb, Mtok, D, FF);                          // x += ff@w2+b2
    };

    // ---------------- encoder (layer 0 reads ctx directly; no memcpy) ----------------
    for (int l = 0; l < NL; ++l)
        tblock((l == 0) ? IN(0) : x, x, xb, Menc, S, 5, l,
               encWqkv + (long long)l * D * 3 * D, encWo + (long long)l * D * D,
               encW1 + (long long)l * D * FF, encW2 + (long long)l * FF * D);

    // ---------------- decoder ----------------
    k_gatherB<<<dim3(Mdec), dim3(256), 0, stream>>>(spe, tpos, flagD, qb);
    u16* qq = s1b;                                       // [Mdec, D]
    u16* kkvv = s1b + (long long)Mdec * D;               // [Menc, 1536] (kk | vv)
    for (int l = 0; l < NL; ++l) {
        // fused independent pair: qq = qb@wq+bq  AND  kkvv = xb@(wk|wv)+bkv  (one launch)
        {
            const int nb1 = (Mdec / 128) * (D / 128);          // 294
            const int nb2 = (Menc / 128) * (2 * D / 128);      // 1176
            k_gemmD<<<dim3(nb1 + nb2), dim3(256), 0, stream>>>(
                qb, caWq + (long long)l * D * D, IN(30) + l * D, qq, Mdec, D,
                xb, caWkv + (long long)l * 2 * D * D, bkv0 + (long long)l * 1536, kkvv, Menc, 2 * D,
                D, nb1);
        }
        attn(qq, D, kkvv, 2 * D, kkvv + D, 2 * D, hb, T, S);                    // cross-attn
        gemm(3, hb, caWo + (long long)l * D * D, IN(36) + l * D, nullptr, q, qb, Mdec, D, D);
        tblock(q, q, qb, Mdec, T, 17, l,
               decWqkv + (long long)l * D * 3 * D, decWo + (long long)l * D * D,
               decW1 + (long long)l * D * FF, decW2 + (long long)l * FF * D);
    }
    ln(q, norm_g, norm_b, nullptr, (float*)d_out, Mdec);
}

// Round 27
// 2419.273 us; speedup vs baseline: 1.0597x; 1.0178x over previous
//
#include <hip/hip_runtime.h>

typedef unsigned short u16;
typedef __attribute__((ext_vector_type(8))) __bf16 bf16x8;
typedef __attribute__((ext_vector_type(4))) float f32x4;

#define DEV static __device__ __forceinline__

#define ARENA_BYTES 349700096ULL
__device__ __align__(256) char g_arena[ARENA_BYTES];

DEV float bf2f(u16 u) { return __uint_as_float(((unsigned)u) << 16); }
DEV u16 f2bf(float f) {
    unsigned u = __float_as_uint(f);
    return (u16)((u + 0x7fffu + ((u >> 16) & 1u)) >> 16);
}
// tanh-GELU via sigmoid identity + hw exp (proven r17)
DEV float gelu_fast(float x) {
    float x3 = x * x * x;
    float u = 1.5957691216057308f * x + 0.0713548162726009f * x3;
    return x / (1.f + __expf(-u));
}

// ---- async global->LDS, 16B per lane (m97 pattern; lane i -> ldsbase + i*16) ----
DEV void gload16(const u16* gp, u16* lp) {
    __builtin_amdgcn_global_load_lds((const __attribute__((address_space(1))) void*)gp,
                                     (__attribute__((address_space(3))) void*)lp, 16, 0, 0);
}

// ---- target_positions dtype sniff ----
__global__ __launch_bounds__(256) void k_detect_i64(const int* __restrict__ pos, int nhalf,
                                                    int* __restrict__ flagD) {
    int i = blockIdx.x * 256 + threadIdx.x;
    if (i < nhalf && pos[2 * i + 1] != 0) atomicAnd(flagD, 0);
}

// ---- gather rows of spatial_pos_embed -> bf16 (vectorized: 8 elems/thread) ----
__global__ __launch_bounds__(256) void k_gatherB(const float* __restrict__ spe,
                                                 const int* __restrict__ pos,
                                                 const int* __restrict__ flagD,
                                                 u16* __restrict__ qb) {
    int row = blockIdx.x;
    int p = (*flagD) ? pos[2 * row] : pos[row];
    p = (p < 0) ? 0 : (p > 195 ? 195 : p);
    const float* src = spe + (size_t)p * 768;
    u16* dst = qb + (size_t)row * 768;
    int j = threadIdx.x;               // 96 chunks of 8
    if (j < 96) {
        float4 a = *(const float4*)&src[j * 8];
        float4 b = *(const float4*)&src[j * 8 + 4];
        union { u16 u[8]; int4 v; } t;
        t.u[0] = f2bf(a.x); t.u[1] = f2bf(a.y); t.u[2] = f2bf(a.z); t.u[3] = f2bf(a.w);
        t.u[4] = f2bf(b.x); t.u[5] = f2bf(b.y); t.u[6] = f2bf(b.z); t.u[7] = f2bf(b.w);
        *(int4*)&dst[j * 8] = t.v;
    }
}

// ---- LayerNorm over 768 (vectorized, proven r24) ----
template <int OUTF32>
__global__ __launch_bounds__(256) void k_ln(const float* __restrict__ X,
                                            const float* __restrict__ g,
                                            const float* __restrict__ b,
                                            u16* __restrict__ Ob, float* __restrict__ Of) {
    const int row = blockIdx.x, tid = threadIdx.x;
    const float* xr = X + (size_t)row * 768;
    const bool act = tid < 192;
    float4 v = act ? *(const float4*)&xr[tid * 4] : float4{0.f, 0.f, 0.f, 0.f};
    float s = v.x + v.y + v.z + v.w;
    float s2 = v.x * v.x + v.y * v.y + v.z * v.z + v.w * v.w;
#pragma unroll
    for (int off = 32; off; off >>= 1) {
        s += __shfl_xor(s, off);
        s2 += __shfl_xor(s2, off);
    }
    __shared__ float red[8];
    const int wid = tid >> 6, lane = tid & 63;
    if (lane == 0) { red[wid] = s; red[4 + wid] = s2; }
    __syncthreads();
    s = red[0] + red[1] + red[2] + red[3];
    s2 = red[4] + red[5] + red[6] + red[7];
    const float mu = s * (1.f / 768.f);
    const float var = fmaxf(s2 * (1.f / 768.f) - mu * mu, 0.f);
    const float rs = rsqrtf(var + 1e-5f);
    if (act) {
        float4 gg = *(const float4*)&g[tid * 4];
        float4 bb = *(const float4*)&b[tid * 4];
        float y0 = (v.x - mu) * rs * gg.x + bb.x;
        float y1 = (v.y - mu) * rs * gg.y + bb.y;
        float y2 = (v.z - mu) * rs * gg.z + bb.z;
        float y3 = (v.w - mu) * rs * gg.w + bb.w;
        if (OUTF32) {
            *(float4*)&Of[(size_t)row * 768 + tid * 4] = float4{y0, y1, y2, y3};
        } else {
            union { u16 u[4]; int2 v2; } t;
            t.u[0] = f2bf(y0); t.u[1] = f2bf(y1); t.u[2] = f2bf(y2); t.u[3] = f2bf(y3);
            *(int2*)&Ob[(size_t)row * 768 + tid * 4] = t.v2;
        }
    }
}

// ---- single-launch LDS-transpose weight conversion: 12 tensors, 64x64 tiles ----
// Reads coalesced (256B rows), writes coalesced (128B per n-row per 8-lane group).
// Per-element math identical to scalar path (same f2bf, same destinations) -> bit-exact.
struct CvD { const float* src; u16* dst; int K; int N; int L;
             long long srcLs; long long dstLs; long long tStart; };
struct CvTab { CvD d[12]; };

__global__ __launch_bounds__(256) void k_wtransT(CvTab tab) {
    __shared__ u16 lds[64][65];        // stride 65 u16: write-phase reads conflict-free
    const long long bid = blockIdx.x;
    int di = 0;
#pragma unroll
    for (int i = 1; i < 12; ++i)
        if (bid >= tab.d[i].tStart) di = i;          // wave-uniform scan
    const CvD dd = tab.d[di];
    const int tid = threadIdx.x;
    const int ntn = dd.N >> 6;
    const int perL = ntn * (dd.K >> 6);
    const long long tloc = bid - dd.tStart;
    const int l = (int)(tloc / perL);
    const int t = (int)(tloc % perL);
    const int kbase = (t / ntn) << 6;
    const int nbase = (t % ntn) << 6;
    const float* Wl = dd.src + (long long)l * dd.srcLs;
    u16* WTl = dd.dst + (long long)l * dd.dstLs;

    // read 64x64 fp32 tile, coalesced (4 rows x 64 cols per step)
    const int rn = tid & 63;
    const int rk0 = tid >> 6;
#pragma unroll
    for (int it = 0; it < 16; ++it) {
        const int k = rk0 + it * 4;
        lds[k][rn] = f2bf(Wl[(size_t)(kbase + k) * dd.N + nbase + rn]);
    }
    __syncthreads();

    // write: chunk c -> n_local = c>>3, kc = c&7; 8 consecutive lanes cover one
    // n-row's 128B contiguous span in WT
#pragma unroll
    for (int c = tid; c < 512; c += 256) {
        const int n_local = c >> 3, kc = c & 7;
        union { u16 u[8]; int4 v; } tcv;
#pragma unroll
        for (int j = 0; j < 8; ++j) tcv.u[j] = lds[kc * 8 + j][n_local];
        *(int4*)&WTl[(size_t)(nbase + n_local) * dd.K + kbase + kc * 8] = tcv.v;
    }
}

// ---- bkv assembly: dst[l][0:768]=bk[l], dst[l][768:1536]=bv[l]; 6 blocks ----
__global__ __launch_bounds__(256) void k_bkv(const float* __restrict__ bk,
                                             const float* __restrict__ bv,
                                             float* __restrict__ dst) {
    int l = blockIdx.x >> 1, half = blockIdx.x & 1;
    const float* s = (half ? bv : bk) + l * 768;
    float* d = dst + (long long)l * 1536 + half * 768;
    for (int i = threadIdx.x; i < 768; i += 256) d[i] = s[i];
}

// ---- bf16 MFMA GEMM (r17-proven): 128x128 tile, BK=64, double-buffered 2-phase
//      prefetch, XOR-swizzled gload_lds staging, bijective XCD block swizzle. ----
template <bool GELU_, bool RES_, bool OF32, bool OBF>
__global__ __launch_bounds__(256) void k_gemmB(const u16* __restrict__ A,
                                               const u16* __restrict__ BT,
                                               const float* __restrict__ bias,
                                               const float* __restrict__ R,
                                               float* __restrict__ Cf, u16* __restrict__ Cb,
                                               int M, int N, int K) {
    __shared__ __align__(16) u16 Asm[2][128 * 64];
    __shared__ __align__(16) u16 Bsm[2][128 * 64];
    const int tid = threadIdx.x;
    const int lane = tid & 63;
    const int wid = tid >> 6;
    const int wm = wid >> 1, wn = wid & 1;

    const int nbx = gridDim.x, nby = gridDim.y;
    const int nwg = nbx * nby;
    const int bid = blockIdx.y * nbx + blockIdx.x;
    const int q8 = nwg >> 3, r8 = nwg & 7;
    const int xcd = bid & 7, pos = bid >> 3;
    const int swz = (xcd < r8 ? xcd * (q8 + 1) : r8 * (q8 + 1) + (xcd - r8) * q8) + pos;
    const int tyy = swz % nby;     // N-tile
    const int txx = swz / nby;     // M-tile

    const int srow = lane >> 3;
    const int sgr = (lane & 7) ^ srow;
    const int fr = lane & 15, g = lane >> 4;
    const int s7 = fr & 7;

    const u16* Ab = A + (size_t)txx * 128 * K + (size_t)srow * K + sgr * 8;
    const u16* Bb = BT + (size_t)tyy * 128 * K + (size_t)srow * K + sgr * 8;

    f32x4 acc[4][4] = {};
    const int nIter = K >> 6;

#pragma unroll
    for (int n = 0; n < 4; ++n) {
        const int rg = wid * 32 + n * 8;
        gload16(Ab + (size_t)rg * K, &Asm[0][rg * 64]);
        gload16(Bb + (size_t)rg * K, &Bsm[0][rg * 64]);
    }
    __syncthreads();

    int cur = 0;
    for (int t = 0; t < nIter; ++t) {
        if (t + 1 < nIter) {
            const int k0 = (t + 1) << 6;
#pragma unroll
            for (int n = 0; n < 4; ++n) {
                const int rg = wid * 32 + n * 8;
                gload16(Ab + (size_t)rg * K + k0, &Asm[cur ^ 1][rg * 64]);
                gload16(Bb + (size_t)rg * K + k0, &Bsm[cur ^ 1][rg * 64]);
            }
        }
        const u16* As = &Asm[cur][0];
        const u16* Bs = &Bsm[cur][0];
#pragma unroll
        for (int kk = 0; kk < 2; ++kk) {
            const int gr8 = (((kk * 4 + g) ^ s7) << 3);
            bf16x8 af[4], bfr[4];
#pragma unroll
            for (int i = 0; i < 4; ++i)
                af[i] = *(const bf16x8*)&As[(wm * 64 + i * 16 + fr) * 64 + gr8];
#pragma unroll
            for (int j = 0; j < 4; ++j)
                bfr[j] = *(const bf16x8*)&Bs[(wn * 64 + j * 16 + fr) * 64 + gr8];
#pragma unroll
            for (int i = 0; i < 4; ++i)
#pragma unroll
                for (int j = 0; j < 4; ++j)
                    acc[i][j] = __builtin_amdgcn_mfma_f32_16x16x32_bf16(af[i], bfr[j], acc[i][j], 0, 0, 0);
        }
        __syncthreads();
        cur ^= 1;
    }

    const int g4 = (lane >> 4) * 4;
#pragma unroll
    for (int j = 0; j < 4; ++j) {
        const int col = tyy * 128 + wn * 64 + j * 16 + fr;
        const float bc = bias[col];
#pragma unroll
        for (int i = 0; i < 4; ++i) {
#pragma unroll
            for (int r = 0; r < 4; ++r) {
                const int row = txx * 128 + wm * 64 + i * 16 + g4 + r;
                float v = acc[i][j][r] + bc;
                if (GELU_) v = gelu_fast(v);
                if (RES_)  v += R[(size_t)row * N + col];
                if (OF32)  Cf[(size_t)row * N + col] = v;
                if (OBF)   Cb[(size_t)row * N + col] = f2bf(v);
            }
        }
    }
}

// ---- dual plain-GEMM: two independent mode-0 problems in one launch (proven r25) ----
__global__ __launch_bounds__(256) void k_gemmD(const u16* __restrict__ A1,
                                               const u16* __restrict__ W1,
                                               const float* __restrict__ b1,
                                               u16* __restrict__ C1, int M1, int N1,
                                               const u16* __restrict__ A2,
                                               const u16* __restrict__ W2,
                                               const float* __restrict__ b2,
                                               u16* __restrict__ C2, int M2, int N2,
                                               int K, int nb1) {
    __shared__ __align__(16) u16 Asm[2][128 * 64];
    __shared__ __align__(16) u16 Bsm[2][128 * 64];
    const int tid = threadIdx.x;
    const int lane = tid & 63;
    const int wid = tid >> 6;
    const int wm = wid >> 1, wn = wid & 1;

    const bool p2 = (int)blockIdx.x >= nb1;
    const u16* A = p2 ? A2 : A1;
    const u16* BT = p2 ? W2 : W1;
    const float* bias = p2 ? b2 : b1;
    u16* Cb = p2 ? C2 : C1;
    const int M = p2 ? M2 : M1;
    const int N = p2 ? N2 : N1;
    const int bidl = (int)blockIdx.x - (p2 ? nb1 : 0);

    const int nbx = M >> 7, nby = N >> 7;
    const int nwg = nbx * nby;
    const int q8 = nwg >> 3, r8 = nwg & 7;
    const int xcd = bidl & 7, pos = bidl >> 3;
    const int swz = (xcd < r8 ? xcd * (q8 + 1) : r8 * (q8 + 1) + (xcd - r8) * q8) + pos;
    const int tyy = swz % nby;
    const int txx = swz / nby;

    const int srow = lane >> 3;
    const int sgr = (lane & 7) ^ srow;
    const int fr = lane & 15, g = lane >> 4;
    const int s7 = fr & 7;

    const u16* Ab = A + (size_t)txx * 128 * K + (size_t)srow * K + sgr * 8;
    const u16* Bb = BT + (size_t)tyy * 128 * K + (size_t)srow * K + sgr * 8;

    f32x4 acc[4][4] = {};
    const int nIter = K >> 6;

#pragma unroll
    for (int n = 0; n < 4; ++n) {
        const int rg = wid * 32 + n * 8;
        gload16(Ab + (size_t)rg * K, &Asm[0][rg * 64]);
        gload16(Bb + (size_t)rg * K, &Bsm[0][rg * 64]);
    }
    __syncthreads();

    int cur = 0;
    for (int t = 0; t < nIter; ++t) {
        if (t + 1 < nIter) {
            const int k0 = (t + 1) << 6;
#pragma unroll
            for (int n = 0; n < 4; ++n) {
                const int rg = wid * 32 + n * 8;
                gload16(Ab + (size_t)rg * K + k0, &Asm[cur ^ 1][rg * 64]);
                gload16(Bb + (size_t)rg * K + k0, &Bsm[cur ^ 1][rg * 64]);
            }
        }
        const u16* As = &Asm[cur][0];
        const u16* Bs = &Bsm[cur][0];
#pragma unroll
        for (int kk = 0; kk < 2; ++kk) {
            const int gr8 = (((kk * 4 + g) ^ s7) << 3);
            bf16x8 af[4], bfr[4];
#pragma unroll
            for (int i = 0; i < 4; ++i)
                af[i] = *(const bf16x8*)&As[(wm * 64 + i * 16 + fr) * 64 + gr8];
#pragma unroll
            for (int j = 0; j < 4; ++j)
                bfr[j] = *(const bf16x8*)&Bs[(wn * 64 + j * 16 + fr) * 64 + gr8];
#pragma unroll
            for (int i = 0; i < 4; ++i)
#pragma unroll
                for (int j = 0; j < 4; ++j)
                    acc[i][j] = __builtin_amdgcn_mfma_f32_16x16x32_bf16(af[i], bfr[j], acc[i][j], 0, 0, 0);
        }
        __syncthreads();
        cur ^= 1;
    }

    const int g4 = (lane >> 4) * 4;
#pragma unroll
    for (int j = 0; j < 4; ++j) {
        const int col = tyy * 128 + wn * 64 + j * 16 + fr;
        const float bc = bias[col];
#pragma unroll
        for (int i = 0; i < 4; ++i) {
#pragma unroll
            for (int r = 0; r < 4; ++r) {
                const int row = txx * 128 + wm * 64 + i * 16 + g4 + r;
                Cb[(size_t)row * N + col] = f2bf(acc[i][j][r] + bc);
            }
        }
    }
}

// ---- MFMA flash attention, bf16 in/out (r22 structure; Q split across gridDim.y) ----
__global__ __launch_bounds__(256) void k_attnM(const u16* __restrict__ Qp, int qs,
                                               const u16* __restrict__ Kp, int ks,
                                               const u16* __restrict__ Vp, int vs,
                                               u16* __restrict__ Op, int os,
                                               int Tq, int Tk) {
    __shared__ u16 kl[208][72];
    __shared__ u16 vt[64][272];
    __shared__ u16 pl[4][16][72];
    const int bh = blockIdx.x, b = bh / 12, h = bh % 12;
    const int tid = threadIdx.x, lane = tid & 63, wid = tid >> 6;
    const int fr = lane & 15, g = lane >> 4, g4 = g * 4;

    const int chunk = (Tq + gridDim.y - 1) / gridDim.y;
    const int q0 = blockIdx.y * chunk;
    int q1 = q0 + chunk; if (q1 > Tq) q1 = Tq;
    if (q0 >= Tq) return;

    const int Tkp = (Tk + 15) & ~15;
    const int NC = (Tkp + 63) >> 6;
    const int TC = NC << 6;

    const int4 zero4 = {0, 0, 0, 0};
    for (int c = tid; c < Tkp * 8; c += 256) {
        int r = c >> 3, j = c & 7;
        int4 v = (r < Tk) ? *(const int4*)&Kp[((size_t)b * Tk + r) * ks + h * 64 + j * 8]
                          : zero4;
        *(int4*)&kl[r][j * 8] = v;
    }
    for (int c = tid; c < TC * 8; c += 256) {
        int t = c >> 3, j = c & 7;
        union { u16 u[8]; int4 v; } w;
        w.v = (t < Tk) ? *(const int4*)&Vp[((size_t)b * Tk + t) * vs + h * 64 + j * 8]
                       : zero4;
#pragma unroll
        for (int i = 0; i < 8; ++i) vt[j * 8 + i][t] = w.u[i];
    }
    __syncthreads();

    const int rows = q1 - q0;
    const int NT = (rows + 63) >> 6;
    for (int it = 0; it < NT; ++it) {
        const int qb = q0 + (it << 6) + (wid << 4);
        if (qb >= q1) continue;

        int qr = qb + fr;
        if (qr >= q1) qr = q0;
        const u16* Qrow = Qp + ((size_t)b * Tq + qr) * qs + h * 64;
        bf16x8 afq0 = *(const bf16x8*)&Qrow[g * 8];
        bf16x8 afq1 = *(const bf16x8*)&Qrow[32 + g * 8];

        f32x4 acc_o[4] = {};
        float m_r[4] = {-1e30f, -1e30f, -1e30f, -1e30f};
        float lp[4] = {0.f, 0.f, 0.f, 0.f};

        for (int c = 0; c < NC; ++c) {
            const int tk0 = c << 6;
            int NF = (Tkp - tk0) >> 4;
            if (NF > 4) NF = 4;

            f32x4 acc_s[4] = {};
#pragma unroll
            for (int nf = 0; nf < 4; ++nf) {
                if (nf < NF) {
                    const u16* kr = &kl[tk0 + nf * 16 + fr][0];
                    acc_s[nf] = __builtin_amdgcn_mfma_f32_16x16x32_bf16(
                        afq0, *(const bf16x8*)&kr[g * 8], acc_s[nf], 0, 0, 0);
                    acc_s[nf] = __builtin_amdgcn_mfma_f32_16x16x32_bf16(
                        afq1, *(const bf16x8*)&kr[32 + g * 8], acc_s[nf], 0, 0, 0);
                }
            }
            float pm[4] = {-1e30f, -1e30f, -1e30f, -1e30f};
#pragma unroll
            for (int nf = 0; nf < 4; ++nf) {
                if (nf < NF) {
                    const bool cv = (tk0 + nf * 16 + fr) < Tk;
#pragma unroll
                    for (int r = 0; r < 4; ++r) {
                        float sv = acc_s[nf][r] * 0.125f;
                        acc_s[nf][r] = sv;
                        if (cv) pm[r] = fmaxf(pm[r], sv);
                    }
                }
            }
#pragma unroll
            for (int off = 1; off < 16; off <<= 1)
#pragma unroll
                for (int r = 0; r < 4; ++r) pm[r] = fmaxf(pm[r], __shfl_xor(pm[r], off));
            float al[4];
#pragma unroll
            for (int r = 0; r < 4; ++r) {
                float mn = fmaxf(m_r[r], pm[r]);
                al[r] = __expf(m_r[r] - mn);
                m_r[r] = mn;
                lp[r] *= al[r];
            }
#pragma unroll
            for (int nfd = 0; nfd < 4; ++nfd)
#pragma unroll
                for (int r = 0; r < 4; ++r) acc_o[nfd][r] *= al[r];
#pragma unroll
            for (int nf = 0; nf < 4; ++nf) {
                const bool cv = (nf < NF) && ((tk0 + nf * 16 + fr) < Tk);
#pragma unroll
                for (int r = 0; r < 4; ++r) {
                    float w = cv ? __expf(acc_s[nf][r] - m_r[r]) : 0.f;
                    lp[r] += w;
                    pl[wid][g4 + r][nf * 16 + fr] = f2bf(w);
                }
            }
#pragma unroll
            for (int ksp = 0; ksp < 2; ++ksp) {
                bf16x8 ap = *(const bf16x8*)&pl[wid][fr][ksp * 32 + g * 8];
#pragma unroll
                for (int nfd = 0; nfd < 4; ++nfd)
                    acc_o[nfd] = __builtin_amdgcn_mfma_f32_16x16x32_bf16(
                        ap, *(const bf16x8*)&vt[nfd * 16 + fr][tk0 + ksp * 32 + g * 8],
                        acc_o[nfd], 0, 0, 0);
            }
        }
#pragma unroll
        for (int off = 1; off < 16; off <<= 1)
#pragma unroll
            for (int r = 0; r < 4; ++r) lp[r] += __shfl_xor(lp[r], off);
#pragma unroll
        for (int r = 0; r < 4; ++r) {
            int qrow = qb + g4 + r;
            if (qrow < q1) {
                float inv = 1.f / lp[r];
#pragma unroll
                for (int nfd = 0; nfd < 4; ++nfd)
                    Op[((size_t)b * Tq + qrow) * os + h * 64 + nfd * 16 + fr] =
                        f2bf(acc_o[nfd][r] * inv);
            }
        }
    }
}

// =======================================================================================
extern "C" void kernel_launch(void* const* d_in, const int* in_sizes, int n_in,
                              void* d_out, int out_size, void* d_ws, size_t ws_size,
                              hipStream_t stream) {
    const int D = 768, FF = 3072, NB = 64, S = 196, T = 98, NL = 3;
    const int Menc = NB * S;   // 12544
    const int Mdec = NB * T;   // 6272

    auto IN = [&](int i) { return (const float*)d_in[i]; };
    const int* tpos = (const int*)d_in[1];
    const float* spe = IN(2);
    const float* norm_g = IN(3);
    const float* norm_b = IN(4);

    char* base;
    if (ws_size >= ARENA_BYTES) {
        base = (char*)d_ws;
    } else {
        void* sym = nullptr;
        if (hipGetSymbolAddress(&sym, HIP_SYMBOL(g_arena)) == hipSuccess && sym)
            base = (char*)sym;
        else
            base = (char*)d_ws;
    }
    char* pp = base;
    auto alloc = [&](long long bytes) -> void* {
        void* r = (void*)pp;
        pp += (bytes + 255) & ~255LL;
        return r;
    };
    int* flag = (int*)alloc(256);
    int* flagD = flag + 1;

    // ---- single-launch tiled weight conversion: build descriptor table ----
    CvTab tab;
    long long tcur = 0;
    int slot = 0;
    auto addcv = [&](const float* src, u16* dst, int K, int N, int L,
                     long long srcLs, long long dstLs) {
        tab.d[slot] = CvD{src, dst, K, N, L, srcLs, dstLs, tcur};
        tcur += (long long)L * (K >> 6) * (N >> 6);
        ++slot;
    };
    auto cvaT = [&](const float* W, int K, int N, int L) -> u16* {
        u16* dst = (u16*)alloc((long long)L * K * N * 2);
        addcv(W, dst, K, N, L, (long long)K * N, (long long)K * N);
        return dst;
    };
    u16* encWqkv = cvaT(IN(7), D, 3 * D, 3);
    u16* encWo = cvaT(IN(9), D, D, 3);
    u16* encW1 = cvaT(IN(13), D, FF, 3);
    u16* encW2 = cvaT(IN(15), FF, D, 3);
    u16* decWqkv = cvaT(IN(19), D, 3 * D, 3);
    u16* decWo = cvaT(IN(21), D, D, 3);
    u16* decW1 = cvaT(IN(25), D, FF, 3);
    u16* decW2 = cvaT(IN(27), FF, D, 3);
    u16* caWq = cvaT(IN(29), D, D, 3);
    u16* caWkv = (u16*)alloc((long long)3 * 2 * D * D * 2);   // [l][wk rows | wv rows][768]
    addcv(IN(31), caWkv, D, D, 3, (long long)D * D, (long long)2 * D * D);
    addcv(IN(33), caWkv + (long long)D * D, D, D, 3, (long long)D * D, (long long)2 * D * D);
    u16* caWo = cvaT(IN(35), D, D, 3);
    k_wtransT<<<dim3((int)tcur), dim3(256), 0, stream>>>(tab);

    // bkv[3] contiguous (each 2*D*4 = 6144 B, 256-aligned -> stride 1536 floats)
    float* bkv0 = (float*)alloc(2 * D * 4);
    float* bkv1 = (float*)alloc(2 * D * 4);
    float* bkv2 = (float*)alloc(2 * D * 4);
    (void)bkv1; (void)bkv2;
    k_bkv<<<dim3(6), dim3(256), 0, stream>>>(IN(32), IN(34), bkv0);

    float* x = (float*)alloc((long long)Menc * D * 4);   // fp32 residual (enc)
    float* q = (float*)alloc((long long)Mdec * D * 4);   // fp32 residual (dec)
    u16* xb = (u16*)alloc((long long)Menc * D * 2);      // bf16 mirror of x
    u16* qb = (u16*)alloc((long long)Mdec * D * 2);      // bf16 mirror of q
    u16* hb = (u16*)alloc((long long)Menc * D * 2);      // bf16 LN/attn out
    u16* s1b = (u16*)alloc((long long)Menc * FF * 2);    // bf16 qkv / ff1 / dec qq,kkvv

    hipMemsetAsync(flagD, 0x01, 4, stream);
    k_detect_i64<<<dim3((Mdec / 2 + 255) / 256), dim3(256), 0, stream>>>(tpos, Mdec / 2, flagD);

    // modes: 0 plain->bf16 | 1 res->fp32+bf16 | 2 gelu->bf16 | 3 plain->fp32+bf16
    auto gemm = [&](int mode, const u16* A, const u16* WT, const float* bias,
                    const float* R, float* Cf, u16* Cb, int M, int N, int K) {
        dim3 g(M / 128, N / 128), blk(256);
        switch (mode) {
            case 0: k_gemmB<false, false, false, true><<<g, blk, 0, stream>>>(A, WT, bias, nullptr, nullptr, Cb, M, N, K); break;
            case 1: k_gemmB<false, true, true, true><<<g, blk, 0, stream>>>(A, WT, bias, R, Cf, Cb, M, N, K); break;
            case 2: k_gemmB<true, false, false, true><<<g, blk, 0, stream>>>(A, WT, bias, nullptr, nullptr, Cb, M, N, K); break;
            case 3: k_gemmB<false, false, true, true><<<g, blk, 0, stream>>>(A, WT, bias, nullptr, Cf, Cb, M, N, K); break;
        }
    };
    auto ln = [&](const float* X, const float* gg, const float* bb, u16* Ob, float* Of, int M) {
        if (Ob) k_ln<0><<<dim3(M), dim3(256), 0, stream>>>(X, gg, bb, Ob, nullptr);
        else    k_ln<1><<<dim3(M), dim3(256), 0, stream>>>(X, gg, bb, nullptr, Of);
    };
    auto attn = [&](const u16* Q, int qs, const u16* Kp, int ks2, const u16* Vp, int vs,
                    u16* O, int Tq, int Tk) {
        int sp = (Tq >= 128) ? 2 : 1;
        k_attnM<<<dim3(NB * 12, sp), dim3(256), 0, stream>>>(Q, qs, Kp, ks2, Vp, vs, O, D, Tq, Tk);
    };

    // pre-norm transformer block. Xin: residual input; Xf/Xb: fp32 residual + bf16 mirror.
    auto tblock = [&](const float* Xin, float* Xf, u16* Xb, int Mtok, int Tseq, int basei,
                      int l, const u16* Wqkv, const u16* Wo, const u16* W1, const u16* W2) {
        const float* ln1g = IN(basei + 0) + l * D;
        const float* ln1b = IN(basei + 1) + l * D;
        const float* bqkv = IN(basei + 3) + l * 3 * D;
        const float* bo = IN(basei + 5) + l * D;
        const float* ln2g = IN(basei + 6) + l * D;
        const float* ln2b = IN(basei + 7) + l * D;
        const float* b1 = IN(basei + 9) + l * FF;
        const float* b2 = IN(basei + 11) + l * D;

        ln(Xin, ln1g, ln1b, hb, nullptr, Mtok);
        gemm(0, hb, Wqkv, bqkv, nullptr, nullptr, s1b, Mtok, 3 * D, D);         // qkv -> bf16
        attn(s1b, 3 * D, s1b + D, 3 * D, s1b + 2 * D, 3 * D, hb, Tseq, Tseq);   // self-attn -> hb
        gemm(1, hb, Wo, bo, Xin, Xf, Xb, Mtok, D, D);                           // Xf = Xin + ao@wo+bo
        ln(Xf, ln2g, ln2b, hb, nullptr, Mtok);
        gemm(2, hb, W1, b1, nullptr, nullptr, s1b, Mtok, FF, D);                // gelu -> bf16
        gemm(1, s1b, W2, b2, Xf, Xf, Xb, Mtok, D, FF);                          // x += ff@w2+b2
    };

    // ---------------- encoder (layer 0 reads ctx directly; no memcpy) ----------------
    for (int l = 0; l < NL; ++l)
        tblock((l == 0) ? IN(0) : x, x, xb, Menc, S, 5, l,
               encWqkv + (long long)l * D * 3 * D, encWo + (long long)l * D * D,
               encW1 + (long long)l * D * FF, encW2 + (long long)l * FF * D);

    // ---------------- decoder ----------------
    k_gatherB<<<dim3(Mdec), dim3(256), 0, stream>>>(spe, tpos, flagD, qb);
    u16* qq = s1b;                                       // [Mdec, D]
    u16* kkvv = s1b + (long long)Mdec * D;               // [Menc, 1536] (kk | vv)
    for (int l = 0; l < NL; ++l) {
        // fused independent pair: qq = qb@wq+bq  AND  kkvv = xb@(wk|wv)+bkv  (one launch)
        {
            const int nb1 = (Mdec / 128) * (D / 128);          // 294
            const int nb2 = (Menc / 128) * (2 * D / 128);      // 1176
            k_gemmD<<<dim3(nb1 + nb2), dim3(256), 0, stream>>>(
                qb, caWq + (long long)l * D * D, IN(30) + l * D, qq, Mdec, D,
                xb, caWkv + (long long)l * 2 * D * D, bkv0 + (long long)l * 1536, kkvv, Menc, 2 * D,
                D, nb1);
        }
        attn(qq, D, kkvv, 2 * D, kkvv + D, 2 * D, hb, T, S);                    // cross-attn
        gemm(3, hb, caWo + (long long)l * D * D, IN(36) + l * D, nullptr, q, qb, Mdec, D, D);
        tblock(q, q, qb, Mdec, T, 17, l,
               decWqkv + (long long)l * D * 3 * D, decWo + (long long)l * D * D,
               decW1 + (long long)l * D * FF, decW2 + (long long)l * FF * D);
    }
    ln(q, norm_g, norm_b, nullptr, (float*)d_out, Mdec);
}

// Round 28
// 2367.685 us; speedup vs baseline: 1.0828x; 1.0218x over previous
//
#include <hip/hip_runtime.h>

typedef unsigned short u16;
typedef __attribute__((ext_vector_type(8))) __bf16 bf16x8;
typedef __attribute__((ext_vector_type(4))) float f32x4;

#define DEV static __device__ __forceinline__

#define ARENA_BYTES 349700096ULL
__device__ __align__(256) char g_arena[ARENA_BYTES];

DEV float bf2f(u16 u) { return __uint_as_float(((unsigned)u) << 16); }
DEV u16 f2bf(float f) {
    unsigned u = __float_as_uint(f);
    return (u16)((u + 0x7fffu + ((u >> 16) & 1u)) >> 16);
}
// tanh-GELU via sigmoid identity + hw exp (proven r17)
DEV float gelu_fast(float x) {
    float x3 = x * x * x;
    float u = 1.5957691216057308f * x + 0.0713548162726009f * x3;
    return x / (1.f + __expf(-u));
}

// ---- async global->LDS, 16B per lane (m97 pattern; lane i -> ldsbase + i*16) ----
DEV void gload16(const u16* gp, u16* lp) {
    __builtin_amdgcn_global_load_lds((const __attribute__((address_space(1))) void*)gp,
                                     (__attribute__((address_space(3))) void*)lp, 16, 0, 0);
}

// ---- target_positions dtype sniff ----
__global__ __launch_bounds__(256) void k_detect_i64(const int* __restrict__ pos, int nhalf,
                                                    int* __restrict__ flagD) {
    int i = blockIdx.x * 256 + threadIdx.x;
    if (i < nhalf && pos[2 * i + 1] != 0) atomicAnd(flagD, 0);
}

// ---- gather rows of spatial_pos_embed -> bf16 (vectorized: 8 elems/thread) ----
__global__ __launch_bounds__(256) void k_gatherB(const float* __restrict__ spe,
                                                 const int* __restrict__ pos,
                                                 const int* __restrict__ flagD,
                                                 u16* __restrict__ qb) {
    int row = blockIdx.x;
    int p = (*flagD) ? pos[2 * row] : pos[row];
    p = (p < 0) ? 0 : (p > 195 ? 195 : p);
    const float* src = spe + (size_t)p * 768;
    u16* dst = qb + (size_t)row * 768;
    int j = threadIdx.x;               // 96 chunks of 8
    if (j < 96) {
        float4 a = *(const float4*)&src[j * 8];
        float4 b = *(const float4*)&src[j * 8 + 4];
        union { u16 u[8]; int4 v; } t;
        t.u[0] = f2bf(a.x); t.u[1] = f2bf(a.y); t.u[2] = f2bf(a.z); t.u[3] = f2bf(a.w);
        t.u[4] = f2bf(b.x); t.u[5] = f2bf(b.y); t.u[6] = f2bf(b.z); t.u[7] = f2bf(b.w);
        *(int4*)&dst[j * 8] = t.v;
    }
}

// ---- LayerNorm over 768 (vectorized, proven r24) ----
template <int OUTF32>
__global__ __launch_bounds__(256) void k_ln(const float* __restrict__ X,
                                            const float* __restrict__ g,
                                            const float* __restrict__ b,
                                            u16* __restrict__ Ob, float* __restrict__ Of) {
    const int row = blockIdx.x, tid = threadIdx.x;
    const float* xr = X + (size_t)row * 768;
    const bool act = tid < 192;
    float4 v = act ? *(const float4*)&xr[tid * 4] : float4{0.f, 0.f, 0.f, 0.f};
    float s = v.x + v.y + v.z + v.w;
    float s2 = v.x * v.x + v.y * v.y + v.z * v.z + v.w * v.w;
#pragma unroll
    for (int off = 32; off; off >>= 1) {
        s += __shfl_xor(s, off);
        s2 += __shfl_xor(s2, off);
    }
    __shared__ float red[8];
    const int wid = tid >> 6, lane = tid & 63;
    if (lane == 0) { red[wid] = s; red[4 + wid] = s2; }
    __syncthreads();
    s = red[0] + red[1] + red[2] + red[3];
    s2 = red[4] + red[5] + red[6] + red[7];
    const float mu = s * (1.f / 768.f);
    const float var = fmaxf(s2 * (1.f / 768.f) - mu * mu, 0.f);
    const float rs = rsqrtf(var + 1e-5f);
    if (act) {
        float4 gg = *(const float4*)&g[tid * 4];
        float4 bb = *(const float4*)&b[tid * 4];
        float y0 = (v.x - mu) * rs * gg.x + bb.x;
        float y1 = (v.y - mu) * rs * gg.y + bb.y;
        float y2 = (v.z - mu) * rs * gg.z + bb.z;
        float y3 = (v.w - mu) * rs * gg.w + bb.w;
        if (OUTF32) {
            *(float4*)&Of[(size_t)row * 768 + tid * 4] = float4{y0, y1, y2, y3};
        } else {
            union { u16 u[4]; int2 v2; } t;
            t.u[0] = f2bf(y0); t.u[1] = f2bf(y1); t.u[2] = f2bf(y2); t.u[3] = f2bf(y3);
            *(int2*)&Ob[(size_t)row * 768 + tid * 4] = t.v2;
        }
    }
}

// ---- single-launch LDS-transpose weight conversion (proven r27) ----
struct CvD { const float* src; u16* dst; int K; int N; int L;
             long long srcLs; long long dstLs; long long tStart; };
struct CvTab { CvD d[12]; };

__global__ __launch_bounds__(256) void k_wtransT(CvTab tab) {
    __shared__ u16 lds[64][65];
    const long long bid = blockIdx.x;
    int di = 0;
#pragma unroll
    for (int i = 1; i < 12; ++i)
        if (bid >= tab.d[i].tStart) di = i;
    const CvD dd = tab.d[di];
    const int tid = threadIdx.x;
    const int ntn = dd.N >> 6;
    const int perL = ntn * (dd.K >> 6);
    const long long tloc = bid - dd.tStart;
    const int l = (int)(tloc / perL);
    const int t = (int)(tloc % perL);
    const int kbase = (t / ntn) << 6;
    const int nbase = (t % ntn) << 6;
    const float* Wl = dd.src + (long long)l * dd.srcLs;
    u16* WTl = dd.dst + (long long)l * dd.dstLs;

    const int rn = tid & 63;
    const int rk0 = tid >> 6;
#pragma unroll
    for (int it = 0; it < 16; ++it) {
        const int k = rk0 + it * 4;
        lds[k][rn] = f2bf(Wl[(size_t)(kbase + k) * dd.N + nbase + rn]);
    }
    __syncthreads();

#pragma unroll
    for (int c = tid; c < 512; c += 256) {
        const int n_local = c >> 3, kc = c & 7;
        union { u16 u[8]; int4 v; } tcv;
#pragma unroll
        for (int j = 0; j < 8; ++j) tcv.u[j] = lds[kc * 8 + j][n_local];
        *(int4*)&WTl[(size_t)(nbase + n_local) * dd.K + kbase + kc * 8] = tcv.v;
    }
}

// ---- bkv assembly (proven r25) ----
__global__ __launch_bounds__(256) void k_bkv(const float* __restrict__ bk,
                                             const float* __restrict__ bv,
                                             float* __restrict__ dst) {
    int l = blockIdx.x >> 1, half = blockIdx.x & 1;
    const float* s = (half ? bv : bk) + l * 768;
    float* d = dst + (long long)l * 1536 + half * 768;
    for (int i = threadIdx.x; i < 768; i += 256) d[i] = s[i];
}

// ---- bf16 MFMA GEMM (r17-proven): 128x128 tile, BK=64, dbuf 2-phase prefetch,
//      XOR-swizzled gload_lds staging, bijective XCD block swizzle. ----
template <bool GELU_, bool RES_, bool OF32, bool OBF>
__global__ __launch_bounds__(256) void k_gemmB(const u16* __restrict__ A,
                                               const u16* __restrict__ BT,
                                               const float* __restrict__ bias,
                                               const float* __restrict__ R,
                                               float* __restrict__ Cf, u16* __restrict__ Cb,
                                               int M, int N, int K) {
    __shared__ __align__(16) u16 Asm[2][128 * 64];
    __shared__ __align__(16) u16 Bsm[2][128 * 64];
    const int tid = threadIdx.x;
    const int lane = tid & 63;
    const int wid = tid >> 6;
    const int wm = wid >> 1, wn = wid & 1;

    const int nbx = gridDim.x, nby = gridDim.y;
    const int nwg = nbx * nby;
    const int bid = blockIdx.y * nbx + blockIdx.x;
    const int q8 = nwg >> 3, r8 = nwg & 7;
    const int xcd = bid & 7, pos = bid >> 3;
    const int swz = (xcd < r8 ? xcd * (q8 + 1) : r8 * (q8 + 1) + (xcd - r8) * q8) + pos;
    const int tyy = swz % nby;
    const int txx = swz / nby;

    const int srow = lane >> 3;
    const int sgr = (lane & 7) ^ srow;
    const int fr = lane & 15, g = lane >> 4;
    const int s7 = fr & 7;

    const u16* Ab = A + (size_t)txx * 128 * K + (size_t)srow * K + sgr * 8;
    const u16* Bb = BT + (size_t)tyy * 128 * K + (size_t)srow * K + sgr * 8;

    f32x4 acc[4][4] = {};
    const int nIter = K >> 6;

#pragma unroll
    for (int n = 0; n < 4; ++n) {
        const int rg = wid * 32 + n * 8;
        gload16(Ab + (size_t)rg * K, &Asm[0][rg * 64]);
        gload16(Bb + (size_t)rg * K, &Bsm[0][rg * 64]);
    }
    __syncthreads();

    int cur = 0;
    for (int t = 0; t < nIter; ++t) {
        if (t + 1 < nIter) {
            const int k0 = (t + 1) << 6;
#pragma unroll
            for (int n = 0; n < 4; ++n) {
                const int rg = wid * 32 + n * 8;
                gload16(Ab + (size_t)rg * K + k0, &Asm[cur ^ 1][rg * 64]);
                gload16(Bb + (size_t)rg * K + k0, &Bsm[cur ^ 1][rg * 64]);
            }
        }
        const u16* As = &Asm[cur][0];
        const u16* Bs = &Bsm[cur][0];
#pragma unroll
        for (int kk = 0; kk < 2; ++kk) {
            const int gr8 = (((kk * 4 + g) ^ s7) << 3);
            bf16x8 af[4], bfr[4];
#pragma unroll
            for (int i = 0; i < 4; ++i)
                af[i] = *(const bf16x8*)&As[(wm * 64 + i * 16 + fr) * 64 + gr8];
#pragma unroll
            for (int j = 0; j < 4; ++j)
                bfr[j] = *(const bf16x8*)&Bs[(wn * 64 + j * 16 + fr) * 64 + gr8];
#pragma unroll
            for (int i = 0; i < 4; ++i)
#pragma unroll
                for (int j = 0; j < 4; ++j)
                    acc[i][j] = __builtin_amdgcn_mfma_f32_16x16x32_bf16(af[i], bfr[j], acc[i][j], 0, 0, 0);
        }
        __syncthreads();
        cur ^= 1;
    }

    const int g4 = (lane >> 4) * 4;
#pragma unroll
    for (int j = 0; j < 4; ++j) {
        const int col = tyy * 128 + wn * 64 + j * 16 + fr;
        const float bc = bias[col];
#pragma unroll
        for (int i = 0; i < 4; ++i) {
#pragma unroll
            for (int r = 0; r < 4; ++r) {
                const int row = txx * 128 + wm * 64 + i * 16 + g4 + r;
                float v = acc[i][j][r] + bc;
                if (GELU_) v = gelu_fast(v);
                if (RES_)  v += R[(size_t)row * N + col];
                if (OF32)  Cf[(size_t)row * N + col] = v;
                if (OBF)   Cb[(size_t)row * N + col] = f2bf(v);
            }
        }
    }
}

// ---- narrow-N GEMM: 128x64 tile for under-filled small-N launches (M=6272,N=768).
//      Same 4 waves (2Mx2N, wave=64x32, acc[4][2]); staging/read swizzle and K-order
//      identical to k_gemmB -> bit-exact per output element. LDS 48KB -> 3 blocks/CU. ----
template <bool GELU_, bool RES_, bool OF32, bool OBF>
__global__ __launch_bounds__(256) void k_gemmN(const u16* __restrict__ A,
                                               const u16* __restrict__ BT,
                                               const float* __restrict__ bias,
                                               const float* __restrict__ R,
                                               float* __restrict__ Cf, u16* __restrict__ Cb,
                                               int M, int N, int K) {
    __shared__ __align__(16) u16 Asm[2][128 * 64];
    __shared__ __align__(16) u16 Bsm[2][64 * 64];
    const int tid = threadIdx.x;
    const int lane = tid & 63;
    const int wid = tid >> 6;
    const int wm = wid >> 1, wn = wid & 1;

    const int nbx = gridDim.x, nby = gridDim.y;   // (M/128, N/64)
    const int nwg = nbx * nby;
    const int bid = blockIdx.y * nbx + blockIdx.x;
    const int q8 = nwg >> 3, r8 = nwg & 7;
    const int xcd = bid & 7, pos = bid >> 3;
    const int swz = (xcd < r8 ? xcd * (q8 + 1) : r8 * (q8 + 1) + (xcd - r8) * q8) + pos;
    const int tyy = swz % nby;
    const int txx = swz / nby;

    const int srow = lane >> 3;
    const int sgr = (lane & 7) ^ srow;
    const int fr = lane & 15, g = lane >> 4;
    const int s7 = fr & 7;

    const u16* Ab = A + (size_t)txx * 128 * K + (size_t)srow * K + sgr * 8;
    const u16* Bb = BT + (size_t)tyy * 64 * K + (size_t)srow * K + sgr * 8;

    f32x4 acc[4][2] = {};
    const int nIter = K >> 6;

    // prologue: A 4 row-groups/wave (128 rows), B 2 row-groups/wave (64 rows)
#pragma unroll
    for (int n = 0; n < 4; ++n) {
        const int rg = wid * 32 + n * 8;
        gload16(Ab + (size_t)rg * K, &Asm[0][rg * 64]);
    }
#pragma unroll
    for (int n = 0; n < 2; ++n) {
        const int rg = wid * 16 + n * 8;
        gload16(Bb + (size_t)rg * K, &Bsm[0][rg * 64]);
    }
    __syncthreads();

    int cur = 0;
    for (int t = 0; t < nIter; ++t) {
        if (t + 1 < nIter) {
            const int k0 = (t + 1) << 6;
#pragma unroll
            for (int n = 0; n < 4; ++n) {
                const int rg = wid * 32 + n * 8;
                gload16(Ab + (size_t)rg * K + k0, &Asm[cur ^ 1][rg * 64]);
            }
#pragma unroll
            for (int n = 0; n < 2; ++n) {
                const int rg = wid * 16 + n * 8;
                gload16(Bb + (size_t)rg * K + k0, &Bsm[cur ^ 1][rg * 64]);
            }
        }
        const u16* As = &Asm[cur][0];
        const u16* Bs = &Bsm[cur][0];
#pragma unroll
        for (int kk = 0; kk < 2; ++kk) {
            const int gr8 = (((kk * 4 + g) ^ s7) << 3);
            bf16x8 af[4], bfr[2];
#pragma unroll
            for (int i = 0; i < 4; ++i)
                af[i] = *(const bf16x8*)&As[(wm * 64 + i * 16 + fr) * 64 + gr8];
#pragma unroll
            for (int j = 0; j < 2; ++j)
                bfr[j] = *(const bf16x8*)&Bs[(wn * 32 + j * 16 + fr) * 64 + gr8];
#pragma unroll
            for (int i = 0; i < 4; ++i)
#pragma unroll
                for (int j = 0; j < 2; ++j)
                    acc[i][j] = __builtin_amdgcn_mfma_f32_16x16x32_bf16(af[i], bfr[j], acc[i][j], 0, 0, 0);
        }
        __syncthreads();
        cur ^= 1;
    }

    const int g4 = (lane >> 4) * 4;
#pragma unroll
    for (int j = 0; j < 2; ++j) {
        const int col = tyy * 64 + wn * 32 + j * 16 + fr;
        const float bc = bias[col];
#pragma unroll
        for (int i = 0; i < 4; ++i) {
#pragma unroll
            for (int r = 0; r < 4; ++r) {
                const int row = txx * 128 + wm * 64 + i * 16 + g4 + r;
                float v = acc[i][j][r] + bc;
                if (GELU_) v = gelu_fast(v);
                if (RES_)  v += R[(size_t)row * N + col];
                if (OF32)  Cf[(size_t)row * N + col] = v;
                if (OBF)   Cb[(size_t)row * N + col] = f2bf(v);
            }
        }
    }
}

// ---- dual plain-GEMM (proven r25) ----
__global__ __launch_bounds__(256) void k_gemmD(const u16* __restrict__ A1,
                                               const u16* __restrict__ W1,
                                               const float* __restrict__ b1,
                                               u16* __restrict__ C1, int M1, int N1,
                                               const u16* __restrict__ A2,
                                               const u16* __restrict__ W2,
                                               const float* __restrict__ b2,
                                               u16* __restrict__ C2, int M2, int N2,
                                               int K, int nb1) {
    __shared__ __align__(16) u16 Asm[2][128 * 64];
    __shared__ __align__(16) u16 Bsm[2][128 * 64];
    const int tid = threadIdx.x;
    const int lane = tid & 63;
    const int wid = tid >> 6;
    const int wm = wid >> 1, wn = wid & 1;

    const bool p2 = (int)blockIdx.x >= nb1;
    const u16* A = p2 ? A2 : A1;
    const u16* BT = p2 ? W2 : W1;
    const float* bias = p2 ? b2 : b1;
    u16* Cb = p2 ? C2 : C1;
    const int M = p2 ? M2 : M1;
    const int N = p2 ? N2 : N1;
    const int bidl = (int)blockIdx.x - (p2 ? nb1 : 0);

    const int nbx = M >> 7, nby = N >> 7;
    const int nwg = nbx * nby;
    const int q8 = nwg >> 3, r8 = nwg & 7;
    const int xcd = bidl & 7, pos = bidl >> 3;
    const int swz = (xcd < r8 ? xcd * (q8 + 1) : r8 * (q8 + 1) + (xcd - r8) * q8) + pos;
    const int tyy = swz % nby;
    const int txx = swz / nby;

    const int srow = lane >> 3;
    const int sgr = (lane & 7) ^ srow;
    const int fr = lane & 15, g = lane >> 4;
    const int s7 = fr & 7;

    const u16* Ab = A + (size_t)txx * 128 * K + (size_t)srow * K + sgr * 8;
    const u16* Bb = BT + (size_t)tyy * 128 * K + (size_t)srow * K + sgr * 8;

    f32x4 acc[4][4] = {};
    const int nIter = K >> 6;

#pragma unroll
    for (int n = 0; n < 4; ++n) {
        const int rg = wid * 32 + n * 8;
        gload16(Ab + (size_t)rg * K, &Asm[0][rg * 64]);
        gload16(Bb + (size_t)rg * K, &Bsm[0][rg * 64]);
    }
    __syncthreads();

    int cur = 0;
    for (int t = 0; t < nIter; ++t) {
        if (t + 1 < nIter) {
            const int k0 = (t + 1) << 6;
#pragma unroll
            for (int n = 0; n < 4; ++n) {
                const int rg = wid * 32 + n * 8;
                gload16(Ab + (size_t)rg * K + k0, &Asm[cur ^ 1][rg * 64]);
                gload16(Bb + (size_t)rg * K + k0, &Bsm[cur ^ 1][rg * 64]);
            }
        }
        const u16* As = &Asm[cur][0];
        const u16* Bs = &Bsm[cur][0];
#pragma unroll
        for (int kk = 0; kk < 2; ++kk) {
            const int gr8 = (((kk * 4 + g) ^ s7) << 3);
            bf16x8 af[4], bfr[4];
#pragma unroll
            for (int i = 0; i < 4; ++i)
                af[i] = *(const bf16x8*)&As[(wm * 64 + i * 16 + fr) * 64 + gr8];
#pragma unroll
            for (int j = 0; j < 4; ++j)
                bfr[j] = *(const bf16x8*)&Bs[(wn * 64 + j * 16 + fr) * 64 + gr8];
#pragma unroll
            for (int i = 0; i < 4; ++i)
#pragma unroll
                for (int j = 0; j < 4; ++j)
                    acc[i][j] = __builtin_amdgcn_mfma_f32_16x16x32_bf16(af[i], bfr[j], acc[i][j], 0, 0, 0);
        }
        __syncthreads();
        cur ^= 1;
    }

    const int g4 = (lane >> 4) * 4;
#pragma unroll
    for (int j = 0; j < 4; ++j) {
        const int col = tyy * 128 + wn * 64 + j * 16 + fr;
        const float bc = bias[col];
#pragma unroll
        for (int i = 0; i < 4; ++i) {
#pragma unroll
            for (int r = 0; r < 4; ++r) {
                const int row = txx * 128 + wm * 64 + i * 16 + g4 + r;
                Cb[(size_t)row * N + col] = f2bf(acc[i][j][r] + bc);
            }
        }
    }
}

// ---- MFMA flash attention, bf16 in/out (r22 structure; Q split across gridDim.y) ----
__global__ __launch_bounds__(256) void k_attnM(const u16* __restrict__ Qp, int qs,
                                               const u16* __restrict__ Kp, int ks,
                                               const u16* __restrict__ Vp, int vs,
                                               u16* __restrict__ Op, int os,
                                               int Tq, int Tk) {
    __shared__ u16 kl[208][72];
    __shared__ u16 vt[64][272];
    __shared__ u16 pl[4][16][72];
    const int bh = blockIdx.x, b = bh / 12, h = bh % 12;
    const int tid = threadIdx.x, lane = tid & 63, wid = tid >> 6;
    const int fr = lane & 15, g = lane >> 4, g4 = g * 4;

    const int chunk = (Tq + gridDim.y - 1) / gridDim.y;
    const int q0 = blockIdx.y * chunk;
    int q1 = q0 + chunk; if (q1 > Tq) q1 = Tq;
    if (q0 >= Tq) return;

    const int Tkp = (Tk + 15) & ~15;
    const int NC = (Tkp + 63) >> 6;
    const int TC = NC << 6;

    const int4 zero4 = {0, 0, 0, 0};
    for (int c = tid; c < Tkp * 8; c += 256) {
        int r = c >> 3, j = c & 7;
        int4 v = (r < Tk) ? *(const int4*)&Kp[((size_t)b * Tk + r) * ks + h * 64 + j * 8]
                          : zero4;
        *(int4*)&kl[r][j * 8] = v;
    }
    for (int c = tid; c < TC * 8; c += 256) {
        int t = c >> 3, j = c & 7;
        union { u16 u[8]; int4 v; } w;
        w.v = (t < Tk) ? *(const int4*)&Vp[((size_t)b * Tk + t) * vs + h * 64 + j * 8]
                       : zero4;
#pragma unroll
        for (int i = 0; i < 8; ++i) vt[j * 8 + i][t] = w.u[i];
    }
    __syncthreads();

    const int rows = q1 - q0;
    const int NT = (rows + 63) >> 6;
    for (int it = 0; it < NT; ++it) {
        const int qb = q0 + (it << 6) + (wid << 4);
        if (qb >= q1) continue;

        int qr = qb + fr;
        if (qr >= q1) qr = q0;
        const u16* Qrow = Qp + ((size_t)b * Tq + qr) * qs + h * 64;
        bf16x8 afq0 = *(const bf16x8*)&Qrow[g * 8];
        bf16x8 afq1 = *(const bf16x8*)&Qrow[32 + g * 8];

        f32x4 acc_o[4] = {};
        float m_r[4] = {-1e30f, -1e30f, -1e30f, -1e30f};
        float lp[4] = {0.f, 0.f, 0.f, 0.f};

        for (int c = 0; c < NC; ++c) {
            const int tk0 = c << 6;
            int NF = (Tkp - tk0) >> 4;
            if (NF > 4) NF = 4;

            f32x4 acc_s[4] = {};
#pragma unroll
            for (int nf = 0; nf < 4; ++nf) {
                if (nf < NF) {
                    const u16* kr = &kl[tk0 + nf * 16 + fr][0];
                    acc_s[nf] = __builtin_amdgcn_mfma_f32_16x16x32_bf16(
                        afq0, *(const bf16x8*)&kr[g * 8], acc_s[nf], 0, 0, 0);
                    acc_s[nf] = __builtin_amdgcn_mfma_f32_16x16x32_bf16(
                        afq1, *(const bf16x8*)&kr[32 + g * 8], acc_s[nf], 0, 0, 0);
                }
            }
            float pm[4] = {-1e30f, -1e30f, -1e30f, -1e30f};
#pragma unroll
            for (int nf = 0; nf < 4; ++nf) {
                if (nf < NF) {
                    const bool cv = (tk0 + nf * 16 + fr) < Tk;
#pragma unroll
                    for (int r = 0; r < 4; ++r) {
                        float sv = acc_s[nf][r] * 0.125f;
                        acc_s[nf][r] = sv;
                        if (cv) pm[r] = fmaxf(pm[r], sv);
                    }
                }
            }
#pragma unroll
            for (int off = 1; off < 16; off <<= 1)
#pragma unroll
                for (int r = 0; r < 4; ++r) pm[r] = fmaxf(pm[r], __shfl_xor(pm[r], off));
            float al[4];
#pragma unroll
            for (int r = 0; r < 4; ++r) {
                float mn = fmaxf(m_r[r], pm[r]);
                al[r] = __expf(m_r[r] - mn);
                m_r[r] = mn;
                lp[r] *= al[r];
            }
#pragma unroll
            for (int nfd = 0; nfd < 4; ++nfd)
#pragma unroll
                for (int r = 0; r < 4; ++r) acc_o[nfd][r] *= al[r];
#pragma unroll
            for (int nf = 0; nf < 4; ++nf) {
                const bool cv = (nf < NF) && ((tk0 + nf * 16 + fr) < Tk);
#pragma unroll
                for (int r = 0; r < 4; ++r) {
                    float w = cv ? __expf(acc_s[nf][r] - m_r[r]) : 0.f;
                    lp[r] += w;
                    pl[wid][g4 + r][nf * 16 + fr] = f2bf(w);
                }
            }
#pragma unroll
            for (int ksp = 0; ksp < 2; ++ksp) {
                bf16x8 ap = *(const bf16x8*)&pl[wid][fr][ksp * 32 + g * 8];
#pragma unroll
                for (int nfd = 0; nfd < 4; ++nfd)
                    acc_o[nfd] = __builtin_amdgcn_mfma_f32_16x16x32_bf16(
                        ap, *(const bf16x8*)&vt[nfd * 16 + fr][tk0 + ksp * 32 + g * 8],
                        acc_o[nfd], 0, 0, 0);
            }
        }
#pragma unroll
        for (int off = 1; off < 16; off <<= 1)
#pragma unroll
            for (int r = 0; r < 4; ++r) lp[r] += __shfl_xor(lp[r], off);
#pragma unroll
        for (int r = 0; r < 4; ++r) {
            int qrow = qb + g4 + r;
            if (qrow < q1) {
                float inv = 1.f / lp[r];
#pragma unroll
                for (int nfd = 0; nfd < 4; ++nfd)
                    Op[((size_t)b * Tq + qrow) * os + h * 64 + nfd * 16 + fr] =
                        f2bf(acc_o[nfd][r] * inv);
            }
        }
    }
}

// =======================================================================================
extern "C" void kernel_launch(void* const* d_in, const int* in_sizes, int n_in,
                              void* d_out, int out_size, void* d_ws, size_t ws_size,
                              hipStream_t stream) {
    const int D = 768, FF = 3072, NB = 64, S = 196, T = 98, NL = 3;
    const int Menc = NB * S;   // 12544
    const int Mdec = NB * T;   // 6272

    auto IN = [&](int i) { return (const float*)d_in[i]; };
    const int* tpos = (const int*)d_in[1];
    const float* spe = IN(2);
    const float* norm_g = IN(3);
    const float* norm_b = IN(4);

    char* base;
    if (ws_size >= ARENA_BYTES) {
        base = (char*)d_ws;
    } else {
        void* sym = nullptr;
        if (hipGetSymbolAddress(&sym, HIP_SYMBOL(g_arena)) == hipSuccess && sym)
            base = (char*)sym;
        else
            base = (char*)d_ws;
    }
    char* pp = base;
    auto alloc = [&](long long bytes) -> void* {
        void* r = (void*)pp;
        pp += (bytes + 255) & ~255LL;
        return r;
    };
    int* flag = (int*)alloc(256);
    int* flagD = flag + 1;

    // ---- single-launch tiled weight conversion ----
    CvTab tab;
    long long tcur = 0;
    int slot = 0;
    auto addcv = [&](const float* src, u16* dst, int K, int N, int L,
                     long long srcLs, long long dstLs) {
        tab.d[slot] = CvD{src, dst, K, N, L, srcLs, dstLs, tcur};
        tcur += (long long)L * (K >> 6) * (N >> 6);
        ++slot;
    };
    auto cvaT = [&](const float* W, int K, int N, int L) -> u16* {
        u16* dst = (u16*)alloc((long long)L * K * N * 2);
        addcv(W, dst, K, N, L, (long long)K * N, (long long)K * N);
        return dst;
    };
    u16* encWqkv = cvaT(IN(7), D, 3 * D, 3);
    u16* encWo = cvaT(IN(9), D, D, 3);
    u16* encW1 = cvaT(IN(13), D, FF, 3);
    u16* encW2 = cvaT(IN(15), FF, D, 3);
    u16* decWqkv = cvaT(IN(19), D, 3 * D, 3);
    u16* decWo = cvaT(IN(21), D, D, 3);
    u16* decW1 = cvaT(IN(25), D, FF, 3);
    u16* decW2 = cvaT(IN(27), FF, D, 3);
    u16* caWq = cvaT(IN(29), D, D, 3);
    u16* caWkv = (u16*)alloc((long long)3 * 2 * D * D * 2);
    addcv(IN(31), caWkv, D, D, 3, (long long)D * D, (long long)2 * D * D);
    addcv(IN(33), caWkv + (long long)D * D, D, D, 3, (long long)D * D, (long long)2 * D * D);
    u16* caWo = cvaT(IN(35), D, D, 3);
    k_wtransT<<<dim3((int)tcur), dim3(256), 0, stream>>>(tab);

    float* bkv0 = (float*)alloc(2 * D * 4);
    float* bkv1 = (float*)alloc(2 * D * 4);
    float* bkv2 = (float*)alloc(2 * D * 4);
    (void)bkv1; (void)bkv2;
    k_bkv<<<dim3(6), dim3(256), 0, stream>>>(IN(32), IN(34), bkv0);

    float* x = (float*)alloc((long long)Menc * D * 4);
    float* q = (float*)alloc((long long)Mdec * D * 4);
    u16* xb = (u16*)alloc((long long)Menc * D * 2);
    u16* qb = (u16*)alloc((long long)Mdec * D * 2);
    u16* hb = (u16*)alloc((long long)Menc * D * 2);
    u16* s1b = (u16*)alloc((long long)Menc * FF * 2);

    hipMemsetAsync(flagD, 0x01, 4, stream);
    k_detect_i64<<<dim3((Mdec / 2 + 255) / 256), dim3(256), 0, stream>>>(tpos, Mdec / 2, flagD);

    // modes: 0 plain->bf16 | 1 res->fp32+bf16 | 2 gelu->bf16 | 3 plain->fp32+bf16
    // Narrow-N path (128x64 tile) for the under-filled M=6272,N=768 launches.
    auto gemm = [&](int mode, const u16* A, const u16* WT, const float* bias,
                    const float* R, float* Cf, u16* Cb, int M, int N, int K) {
        if (M == 6272 && N == 768 && (mode == 1 || mode == 3)) {
            dim3 g(M / 128, N / 64), blk(256);
            if (mode == 1) k_gemmN<false, true, true, true><<<g, blk, 0, stream>>>(A, WT, bias, R, Cf, Cb, M, N, K);
            else           k_gemmN<false, false, true, true><<<g, blk, 0, stream>>>(A, WT, bias, nullptr, Cf, Cb, M, N, K);
            return;
        }
        dim3 g(M / 128, N / 128), blk(256);
        switch (mode) {
            case 0: k_gemmB<false, false, false, true><<<g, blk, 0, stream>>>(A, WT, bias, nullptr, nullptr, Cb, M, N, K); break;
            case 1: k_gemmB<false, true, true, true><<<g, blk, 0, stream>>>(A, WT, bias, R, Cf, Cb, M, N, K); break;
            case 2: k_gemmB<true, false, false, true><<<g, blk, 0, stream>>>(A, WT, bias, nullptr, nullptr, Cb, M, N, K); break;
            case 3: k_gemmB<false, false, true, true><<<g, blk, 0, stream>>>(A, WT, bias, nullptr, Cf, Cb, M, N, K); break;
        }
    };
    auto ln = [&](const float* X, const float* gg, const float* bb, u16* Ob, float* Of, int M) {
        if (Ob) k_ln<0><<<dim3(M), dim3(256), 0, stream>>>(X, gg, bb, Ob, nullptr);
        else    k_ln<1><<<dim3(M), dim3(256), 0, stream>>>(X, gg, bb, nullptr, Of);
    };
    auto attn = [&](const u16* Q, int qs, const u16* Kp, int ks2, const u16* Vp, int vs,
                    u16* O, int Tq, int Tk) {
        int sp = (Tq >= 128) ? 2 : 1;
        k_attnM<<<dim3(NB * 12, sp), dim3(256), 0, stream>>>(Q, qs, Kp, ks2, Vp, vs, O, D, Tq, Tk);
    };

    // pre-norm transformer block. Xin: residual input; Xf/Xb: fp32 residual + bf16 mirror.
    auto tblock = [&](const float* Xin, float* Xf, u16* Xb, int Mtok, int Tseq, int basei,
                      int l, const u16* Wqkv, const u16* Wo, const u16* W1, const u16* W2) {
        const float* ln1g = IN(basei + 0) + l * D;
        const float* ln1b = IN(basei + 1) + l * D;
        const float* bqkv = IN(basei + 3) + l * 3 * D;
        const float* bo = IN(basei + 5) + l * D;
        const float* ln2g = IN(basei + 6) + l * D;
        const float* ln2b = IN(basei + 7) + l * D;
        const float* b1 = IN(basei + 9) + l * FF;
        const float* b2 = IN(basei + 11) + l * D;

        ln(Xin, ln1g, ln1b, hb, nullptr, Mtok);
        gemm(0, hb, Wqkv, bqkv, nullptr, nullptr, s1b, Mtok, 3 * D, D);         // qkv -> bf16
        attn(s1b, 3 * D, s1b + D, 3 * D, s1b + 2 * D, 3 * D, hb, Tseq, Tseq);   // self-attn -> hb
        gemm(1, hb, Wo, bo, Xin, Xf, Xb, Mtok, D, D);                           // Xf = Xin + ao@wo+bo
        ln(Xf, ln2g, ln2b, hb, nullptr, Mtok);
        gemm(2, hb, W1, b1, nullptr, nullptr, s1b, Mtok, FF, D);                // gelu -> bf16
        gemm(1, s1b, W2, b2, Xf, Xf, Xb, Mtok, D, FF);                          // x += ff@w2+b2
    };

    // ---------------- encoder (layer 0 reads ctx directly; no memcpy) ----------------
    for (int l = 0; l < NL; ++l)
        tblock((l == 0) ? IN(0) : x, x, xb, Menc, S, 5, l,
               encWqkv + (long long)l * D * 3 * D, encWo + (long long)l * D * D,
               encW1 + (long long)l * D * FF, encW2 + (long long)l * FF * D);

    // ---------------- decoder ----------------
    k_gatherB<<<dim3(Mdec), dim3(256), 0, stream>>>(spe, tpos, flagD, qb);
    u16* qq = s1b;                                       // [Mdec, D]
    u16* kkvv = s1b + (long long)Mdec * D;               // [Menc, 1536] (kk | vv)
    for (int l = 0; l < NL; ++l) {
        // fused independent pair: qq = qb@wq+bq  AND  kkvv = xb@(wk|wv)+bkv  (one launch)
        {
            const int nb1 = (Mdec / 128) * (D / 128);          // 294
            const int nb2 = (Menc / 128) * (2 * D / 128);      // 1176
            k_gemmD<<<dim3(nb1 + nb2), dim3(256), 0, stream>>>(
                qb, caWq + (long long)l * D * D, IN(30) + l * D, qq, Mdec, D,
                xb, caWkv + (long long)l * 2 * D * D, bkv0 + (long long)l * 1536, kkvv, Menc, 2 * D,
                D, nb1);
        }
        attn(qq, D, kkvv, 2 * D, kkvv + D, 2 * D, hb, T, S);                    // cross-attn
        gemm(3, hb, caWo + (long long)l * D * D, IN(36) + l * D, nullptr, q, qb, Mdec, D, D);
        tblock(q, q, qb, Mdec, T, 17, l,
               decWqkv + (long long)l * D * 3 * D, decWo + (long long)l * D * D,
               decW1 + (long long)l * D * FF, decW2 + (long long)l * FF * D);
    }
    ln(q, norm_g, norm_b, nullptr, (float*)d_out, Mdec);
}

// Round 29
// 2280.672 us; speedup vs baseline: 1.1241x; 1.0382x over previous
//
#include <hip/hip_runtime.h>

typedef unsigned short u16;
typedef __attribute__((ext_vector_type(8))) __bf16 bf16x8;
typedef __attribute__((ext_vector_type(4))) float f32x4;

#define DEV static __device__ __forceinline__

#define ARENA_BYTES 349700096ULL
__device__ __align__(256) char g_arena[ARENA_BYTES];

DEV float bf2f(u16 u) { return __uint_as_float(((unsigned)u) << 16); }
DEV u16 f2bf(float f) {
    unsigned u = __float_as_uint(f);
    return (u16)((u + 0x7fffu + ((u >> 16) & 1u)) >> 16);
}
// tanh-GELU via sigmoid identity + hw exp (proven r17)
DEV float gelu_fast(float x) {
    float x3 = x * x * x;
    float u = 1.5957691216057308f * x + 0.0713548162726009f * x3;
    return x / (1.f + __expf(-u));
}

// ---- async global->LDS, 16B per lane (m97 pattern; lane i -> ldsbase + i*16) ----
DEV void gload16(const u16* gp, u16* lp) {
    __builtin_amdgcn_global_load_lds((const __attribute__((address_space(1))) void*)gp,
                                     (__attribute__((address_space(3))) void*)lp, 16, 0, 0);
}

// ---- target_positions dtype sniff ----
__global__ __launch_bounds__(256) void k_detect_i64(const int* __restrict__ pos, int nhalf,
                                                    int* __restrict__ flagD) {
    int i = blockIdx.x * 256 + threadIdx.x;
    if (i < nhalf && pos[2 * i + 1] != 0) atomicAnd(flagD, 0);
}

// ---- gather rows of spatial_pos_embed -> bf16 (vectorized: 8 elems/thread) ----
__global__ __launch_bounds__(256) void k_gatherB(const float* __restrict__ spe,
                                                 const int* __restrict__ pos,
                                                 const int* __restrict__ flagD,
                                                 u16* __restrict__ qb) {
    int row = blockIdx.x;
    int p = (*flagD) ? pos[2 * row] : pos[row];
    p = (p < 0) ? 0 : (p > 195 ? 195 : p);
    const float* src = spe + (size_t)p * 768;
    u16* dst = qb + (size_t)row * 768;
    int j = threadIdx.x;               // 96 chunks of 8
    if (j < 96) {
        float4 a = *(const float4*)&src[j * 8];
        float4 b = *(const float4*)&src[j * 8 + 4];
        union { u16 u[8]; int4 v; } t;
        t.u[0] = f2bf(a.x); t.u[1] = f2bf(a.y); t.u[2] = f2bf(a.z); t.u[3] = f2bf(a.w);
        t.u[4] = f2bf(b.x); t.u[5] = f2bf(b.y); t.u[6] = f2bf(b.z); t.u[7] = f2bf(b.w);
        *(int4*)&dst[j * 8] = t.v;
    }
}

// ---- LayerNorm over 768 (vectorized, proven r24) ----
template <int OUTF32>
__global__ __launch_bounds__(256) void k_ln(const float* __restrict__ X,
                                            const float* __restrict__ g,
                                            const float* __restrict__ b,
                                            u16* __restrict__ Ob, float* __restrict__ Of) {
    const int row = blockIdx.x, tid = threadIdx.x;
    const float* xr = X + (size_t)row * 768;
    const bool act = tid < 192;
    float4 v = act ? *(const float4*)&xr[tid * 4] : float4{0.f, 0.f, 0.f, 0.f};
    float s = v.x + v.y + v.z + v.w;
    float s2 = v.x * v.x + v.y * v.y + v.z * v.z + v.w * v.w;
#pragma unroll
    for (int off = 32; off; off >>= 1) {
        s += __shfl_xor(s, off);
        s2 += __shfl_xor(s2, off);
    }
    __shared__ float red[8];
    const int wid = tid >> 6, lane = tid & 63;
    if (lane == 0) { red[wid] = s; red[4 + wid] = s2; }
    __syncthreads();
    s = red[0] + red[1] + red[2] + red[3];
    s2 = red[4] + red[5] + red[6] + red[7];
    const float mu = s * (1.f / 768.f);
    const float var = fmaxf(s2 * (1.f / 768.f) - mu * mu, 0.f);
    const float rs = rsqrtf(var + 1e-5f);
    if (act) {
        float4 gg = *(const float4*)&g[tid * 4];
        float4 bb = *(const float4*)&b[tid * 4];
        float y0 = (v.x - mu) * rs * gg.x + bb.x;
        float y1 = (v.y - mu) * rs * gg.y + bb.y;
        float y2 = (v.z - mu) * rs * gg.z + bb.z;
        float y3 = (v.w - mu) * rs * gg.w + bb.w;
        if (OUTF32) {
            *(float4*)&Of[(size_t)row * 768 + tid * 4] = float4{y0, y1, y2, y3};
        } else {
            union { u16 u[4]; int2 v2; } t;
            t.u[0] = f2bf(y0); t.u[1] = f2bf(y1); t.u[2] = f2bf(y2); t.u[3] = f2bf(y3);
            *(int2*)&Ob[(size_t)row * 768 + tid * 4] = t.v2;
        }
    }
}

// ---- single-launch LDS-transpose weight conversion (proven r27) ----
struct CvD { const float* src; u16* dst; int K; int N; int L;
             long long srcLs; long long dstLs; long long tStart; };
struct CvTab { CvD d[12]; };

__global__ __launch_bounds__(256) void k_wtransT(CvTab tab) {
    __shared__ u16 lds[64][65];
    const long long bid = blockIdx.x;
    int di = 0;
#pragma unroll
    for (int i = 1; i < 12; ++i)
        if (bid >= tab.d[i].tStart) di = i;
    const CvD dd = tab.d[di];
    const int tid = threadIdx.x;
    const int ntn = dd.N >> 6;
    const int perL = ntn * (dd.K >> 6);
    const long long tloc = bid - dd.tStart;
    const int l = (int)(tloc / perL);
    const int t = (int)(tloc % perL);
    const int kbase = (t / ntn) << 6;
    const int nbase = (t % ntn) << 6;
    const float* Wl = dd.src + (long long)l * dd.srcLs;
    u16* WTl = dd.dst + (long long)l * dd.dstLs;

    const int rn = tid & 63;
    const int rk0 = tid >> 6;
#pragma unroll
    for (int it = 0; it < 16; ++it) {
        const int k = rk0 + it * 4;
        lds[k][rn] = f2bf(Wl[(size_t)(kbase + k) * dd.N + nbase + rn]);
    }
    __syncthreads();

#pragma unroll
    for (int c = tid; c < 512; c += 256) {
        const int n_local = c >> 3, kc = c & 7;
        union { u16 u[8]; int4 v; } tcv;
#pragma unroll
        for (int j = 0; j < 8; ++j) tcv.u[j] = lds[kc * 8 + j][n_local];
        *(int4*)&WTl[(size_t)(nbase + n_local) * dd.K + kbase + kc * 8] = tcv.v;
    }
}

// ---- bkv assembly (proven r25) ----
__global__ __launch_bounds__(256) void k_bkv(const float* __restrict__ bk,
                                             const float* __restrict__ bv,
                                             float* __restrict__ dst) {
    int l = blockIdx.x >> 1, half = blockIdx.x & 1;
    const float* s = (half ? bv : bk) + l * 768;
    float* d = dst + (long long)l * 1536 + half * 768;
    for (int i = threadIdx.x; i < 768; i += 256) d[i] = s[i];
}

// ---- bf16 MFMA GEMM (r17-proven): 128x128 tile, BK=64, dbuf 2-phase prefetch,
//      XOR-swizzled gload_lds staging, bijective XCD block swizzle. ----
template <bool GELU_, bool RES_, bool OF32, bool OBF>
__global__ __launch_bounds__(256) void k_gemmB(const u16* __restrict__ A,
                                               const u16* __restrict__ BT,
                                               const float* __restrict__ bias,
                                               const float* __restrict__ R,
                                               float* __restrict__ Cf, u16* __restrict__ Cb,
                                               int M, int N, int K) {
    __shared__ __align__(16) u16 Asm[2][128 * 64];
    __shared__ __align__(16) u16 Bsm[2][128 * 64];
    const int tid = threadIdx.x;
    const int lane = tid & 63;
    const int wid = tid >> 6;
    const int wm = wid >> 1, wn = wid & 1;

    const int nbx = gridDim.x, nby = gridDim.y;
    const int nwg = nbx * nby;
    const int bid = blockIdx.y * nbx + blockIdx.x;
    const int q8 = nwg >> 3, r8 = nwg & 7;
    const int xcd = bid & 7, pos = bid >> 3;
    const int swz = (xcd < r8 ? xcd * (q8 + 1) : r8 * (q8 + 1) + (xcd - r8) * q8) + pos;
    const int tyy = swz % nby;
    const int txx = swz / nby;

    const int srow = lane >> 3;
    const int sgr = (lane & 7) ^ srow;
    const int fr = lane & 15, g = lane >> 4;
    const int s7 = fr & 7;

    const u16* Ab = A + (size_t)txx * 128 * K + (size_t)srow * K + sgr * 8;
    const u16* Bb = BT + (size_t)tyy * 128 * K + (size_t)srow * K + sgr * 8;

    f32x4 acc[4][4] = {};
    const int nIter = K >> 6;

#pragma unroll
    for (int n = 0; n < 4; ++n) {
        const int rg = wid * 32 + n * 8;
        gload16(Ab + (size_t)rg * K, &Asm[0][rg * 64]);
        gload16(Bb + (size_t)rg * K, &Bsm[0][rg * 64]);
    }
    __syncthreads();

    int cur = 0;
    for (int t = 0; t < nIter; ++t) {
        if (t + 1 < nIter) {
            const int k0 = (t + 1) << 6;
#pragma unroll
            for (int n = 0; n < 4; ++n) {
                const int rg = wid * 32 + n * 8;
                gload16(Ab + (size_t)rg * K + k0, &Asm[cur ^ 1][rg * 64]);
                gload16(Bb + (size_t)rg * K + k0, &Bsm[cur ^ 1][rg * 64]);
            }
        }
        const u16* As = &Asm[cur][0];
        const u16* Bs = &Bsm[cur][0];
#pragma unroll
        for (int kk = 0; kk < 2; ++kk) {
            const int gr8 = (((kk * 4 + g) ^ s7) << 3);
            bf16x8 af[4], bfr[4];
#pragma unroll
            for (int i = 0; i < 4; ++i)
                af[i] = *(const bf16x8*)&As[(wm * 64 + i * 16 + fr) * 64 + gr8];
#pragma unroll
            for (int j = 0; j < 4; ++j)
                bfr[j] = *(const bf16x8*)&Bs[(wn * 64 + j * 16 + fr) * 64 + gr8];
#pragma unroll
            for (int i = 0; i < 4; ++i)
#pragma unroll
                for (int j = 0; j < 4; ++j)
                    acc[i][j] = __builtin_amdgcn_mfma_f32_16x16x32_bf16(af[i], bfr[j], acc[i][j], 0, 0, 0);
        }
        __syncthreads();
        cur ^= 1;
    }

    const int g4 = (lane >> 4) * 4;
#pragma unroll
    for (int j = 0; j < 4; ++j) {
        const int col = tyy * 128 + wn * 64 + j * 16 + fr;
        const float bc = bias[col];
#pragma unroll
        for (int i = 0; i < 4; ++i) {
#pragma unroll
            for (int r = 0; r < 4; ++r) {
                const int row = txx * 128 + wm * 64 + i * 16 + g4 + r;
                float v = acc[i][j][r] + bc;
                if (GELU_) v = gelu_fast(v);
                if (RES_)  v += R[(size_t)row * N + col];
                if (OF32)  Cf[(size_t)row * N + col] = v;
                if (OBF)   Cb[(size_t)row * N + col] = f2bf(v);
            }
        }
    }
}

// ---- narrow-N GEMM: 128x64 tile for under-filled N=768 launches (proven r28).
//      Same 4 waves (2Mx2N, wave=64x32, acc[4][2]); staging/read swizzle and K-order
//      identical to k_gemmB -> bit-exact per output element. LDS 48KB -> 3 blocks/CU. ----
template <bool GELU_, bool RES_, bool OF32, bool OBF>
__global__ __launch_bounds__(256) void k_gemmN(const u16* __restrict__ A,
                                               const u16* __restrict__ BT,
                                               const float* __restrict__ bias,
                                               const float* __restrict__ R,
                                               float* __restrict__ Cf, u16* __restrict__ Cb,
                                               int M, int N, int K) {
    __shared__ __align__(16) u16 Asm[2][128 * 64];
    __shared__ __align__(16) u16 Bsm[2][64 * 64];
    const int tid = threadIdx.x;
    const int lane = tid & 63;
    const int wid = tid >> 6;
    const int wm = wid >> 1, wn = wid & 1;

    const int nbx = gridDim.x, nby = gridDim.y;   // (M/128, N/64)
    const int nwg = nbx * nby;
    const int bid = blockIdx.y * nbx + blockIdx.x;
    const int q8 = nwg >> 3, r8 = nwg & 7;
    const int xcd = bid & 7, pos = bid >> 3;
    const int swz = (xcd < r8 ? xcd * (q8 + 1) : r8 * (q8 + 1) + (xcd - r8) * q8) + pos;
    const int tyy = swz % nby;
    const int txx = swz / nby;

    const int srow = lane >> 3;
    const int sgr = (lane & 7) ^ srow;
    const int fr = lane & 15, g = lane >> 4;
    const int s7 = fr & 7;

    const u16* Ab = A + (size_t)txx * 128 * K + (size_t)srow * K + sgr * 8;
    const u16* Bb = BT + (size_t)tyy * 64 * K + (size_t)srow * K + sgr * 8;

    f32x4 acc[4][2] = {};
    const int nIter = K >> 6;

#pragma unroll
    for (int n = 0; n < 4; ++n) {
        const int rg = wid * 32 + n * 8;
        gload16(Ab + (size_t)rg * K, &Asm[0][rg * 64]);
    }
#pragma unroll
    for (int n = 0; n < 2; ++n) {
        const int rg = wid * 16 + n * 8;
        gload16(Bb + (size_t)rg * K, &Bsm[0][rg * 64]);
    }
    __syncthreads();

    int cur = 0;
    for (int t = 0; t < nIter; ++t) {
        if (t + 1 < nIter) {
            const int k0 = (t + 1) << 6;
#pragma unroll
            for (int n = 0; n < 4; ++n) {
                const int rg = wid * 32 + n * 8;
                gload16(Ab + (size_t)rg * K + k0, &Asm[cur ^ 1][rg * 64]);
            }
#pragma unroll
            for (int n = 0; n < 2; ++n) {
                const int rg = wid * 16 + n * 8;
                gload16(Bb + (size_t)rg * K + k0, &Bsm[cur ^ 1][rg * 64]);
            }
        }
        const u16* As = &Asm[cur][0];
        const u16* Bs = &Bsm[cur][0];
#pragma unroll
        for (int kk = 0; kk < 2; ++kk) {
            const int gr8 = (((kk * 4 + g) ^ s7) << 3);
            bf16x8 af[4], bfr[2];
#pragma unroll
            for (int i = 0; i < 4; ++i)
                af[i] = *(const bf16x8*)&As[(wm * 64 + i * 16 + fr) * 64 + gr8];
#pragma unroll
            for (int j = 0; j < 2; ++j)
                bfr[j] = *(const bf16x8*)&Bs[(wn * 32 + j * 16 + fr) * 64 + gr8];
#pragma unroll
            for (int i = 0; i < 4; ++i)
#pragma unroll
                for (int j = 0; j < 2; ++j)
                    acc[i][j] = __builtin_amdgcn_mfma_f32_16x16x32_bf16(af[i], bfr[j], acc[i][j], 0, 0, 0);
        }
        __syncthreads();
        cur ^= 1;
    }

    const int g4 = (lane >> 4) * 4;
#pragma unroll
    for (int j = 0; j < 2; ++j) {
        const int col = tyy * 64 + wn * 32 + j * 16 + fr;
        const float bc = bias[col];
#pragma unroll
        for (int i = 0; i < 4; ++i) {
#pragma unroll
            for (int r = 0; r < 4; ++r) {
                const int row = txx * 128 + wm * 64 + i * 16 + g4 + r;
                float v = acc[i][j][r] + bc;
                if (GELU_) v = gelu_fast(v);
                if (RES_)  v += R[(size_t)row * N + col];
                if (OF32)  Cf[(size_t)row * N + col] = v;
                if (OBF)   Cb[(size_t)row * N + col] = f2bf(v);
            }
        }
    }
}

// ---- dual plain-GEMM (proven r25) ----
__global__ __launch_bounds__(256) void k_gemmD(const u16* __restrict__ A1,
                                               const u16* __restrict__ W1,
                                               const float* __restrict__ b1,
                                               u16* __restrict__ C1, int M1, int N1,
                                               const u16* __restrict__ A2,
                                               const u16* __restrict__ W2,
                                               const float* __restrict__ b2,
                                               u16* __restrict__ C2, int M2, int N2,
                                               int K, int nb1) {
    __shared__ __align__(16) u16 Asm[2][128 * 64];
    __shared__ __align__(16) u16 Bsm[2][128 * 64];
    const int tid = threadIdx.x;
    const int lane = tid & 63;
    const int wid = tid >> 6;
    const int wm = wid >> 1, wn = wid & 1;

    const bool p2 = (int)blockIdx.x >= nb1;
    const u16* A = p2 ? A2 : A1;
    const u16* BT = p2 ? W2 : W1;
    const float* bias = p2 ? b2 : b1;
    u16* Cb = p2 ? C2 : C1;
    const int M = p2 ? M2 : M1;
    const int N = p2 ? N2 : N1;
    const int bidl = (int)blockIdx.x - (p2 ? nb1 : 0);

    const int nbx = M >> 7, nby = N >> 7;
    const int nwg = nbx * nby;
    const int q8 = nwg >> 3, r8 = nwg & 7;
    const int xcd = bidl & 7, pos = bidl >> 3;
    const int swz = (xcd < r8 ? xcd * (q8 + 1) : r8 * (q8 + 1) + (xcd - r8) * q8) + pos;
    const int tyy = swz % nby;
    const int txx = swz / nby;

    const int srow = lane >> 3;
    const int sgr = (lane & 7) ^ srow;
    const int fr = lane & 15, g = lane >> 4;
    const int s7 = fr & 7;

    const u16* Ab = A + (size_t)txx * 128 * K + (size_t)srow * K + sgr * 8;
    const u16* Bb = BT + (size_t)tyy * 128 * K + (size_t)srow * K + sgr * 8;

    f32x4 acc[4][4] = {};
    const int nIter = K >> 6;

#pragma unroll
    for (int n = 0; n < 4; ++n) {
        const int rg = wid * 32 + n * 8;
        gload16(Ab + (size_t)rg * K, &Asm[0][rg * 64]);
        gload16(Bb + (size_t)rg * K, &Bsm[0][rg * 64]);
    }
    __syncthreads();

    int cur = 0;
    for (int t = 0; t < nIter; ++t) {
        if (t + 1 < nIter) {
            const int k0 = (t + 1) << 6;
#pragma unroll
            for (int n = 0; n < 4; ++n) {
                const int rg = wid * 32 + n * 8;
                gload16(Ab + (size_t)rg * K + k0, &Asm[cur ^ 1][rg * 64]);
                gload16(Bb + (size_t)rg * K + k0, &Bsm[cur ^ 1][rg * 64]);
            }
        }
        const u16* As = &Asm[cur][0];
        const u16* Bs = &Bsm[cur][0];
#pragma unroll
        for (int kk = 0; kk < 2; ++kk) {
            const int gr8 = (((kk * 4 + g) ^ s7) << 3);
            bf16x8 af[4], bfr[4];
#pragma unroll
            for (int i = 0; i < 4; ++i)
                af[i] = *(const bf16x8*)&As[(wm * 64 + i * 16 + fr) * 64 + gr8];
#pragma unroll
            for (int j = 0; j < 4; ++j)
                bfr[j] = *(const bf16x8*)&Bs[(wn * 64 + j * 16 + fr) * 64 + gr8];
#pragma unroll
            for (int i = 0; i < 4; ++i)
#pragma unroll
                for (int j = 0; j < 4; ++j)
                    acc[i][j] = __builtin_amdgcn_mfma_f32_16x16x32_bf16(af[i], bfr[j], acc[i][j], 0, 0, 0);
        }
        __syncthreads();
        cur ^= 1;
    }

    const int g4 = (lane >> 4) * 4;
#pragma unroll
    for (int j = 0; j < 4; ++j) {
        const int col = tyy * 128 + wn * 64 + j * 16 + fr;
        const float bc = bias[col];
#pragma unroll
        for (int i = 0; i < 4; ++i) {
#pragma unroll
            for (int r = 0; r < 4; ++r) {
                const int row = txx * 128 + wm * 64 + i * 16 + g4 + r;
                Cb[(size_t)row * N + col] = f2bf(acc[i][j][r] + bc);
            }
        }
    }
}

// ---- MFMA flash attention, bf16 in/out (r22 structure; Q split across gridDim.y) ----
__global__ __launch_bounds__(256) void k_attnM(const u16* __restrict__ Qp, int qs,
                                               const u16* __restrict__ Kp, int ks,
                                               const u16* __restrict__ Vp, int vs,
                                               u16* __restrict__ Op, int os,
                                               int Tq, int Tk) {
    __shared__ u16 kl[208][72];
    __shared__ u16 vt[64][272];
    __shared__ u16 pl[4][16][72];
    const int bh = blockIdx.x, b = bh / 12, h = bh % 12;
    const int tid = threadIdx.x, lane = tid & 63, wid = tid >> 6;
    const int fr = lane & 15, g = lane >> 4, g4 = g * 4;

    const int chunk = (Tq + gridDim.y - 1) / gridDim.y;
    const int q0 = blockIdx.y * chunk;
    int q1 = q0 + chunk; if (q1 > Tq) q1 = Tq;
    if (q0 >= Tq) return;

    const int Tkp = (Tk + 15) & ~15;
    const int NC = (Tkp + 63) >> 6;
    const int TC = NC << 6;

    const int4 zero4 = {0, 0, 0, 0};
    for (int c = tid; c < Tkp * 8; c += 256) {
        int r = c >> 3, j = c & 7;
        int4 v = (r < Tk) ? *(const int4*)&Kp[((size_t)b * Tk + r) * ks + h * 64 + j * 8]
                          : zero4;
        *(int4*)&kl[r][j * 8] = v;
    }
    for (int c = tid; c < TC * 8; c += 256) {
        int t = c >> 3, j = c & 7;
        union { u16 u[8]; int4 v; } w;
        w.v = (t < Tk) ? *(const int4*)&Vp[((size_t)b * Tk + t) * vs + h * 64 + j * 8]
                       : zero4;
#pragma unroll
        for (int i = 0; i < 8; ++i) vt[j * 8 + i][t] = w.u[i];
    }
    __syncthreads();

    const int rows = q1 - q0;
    const int NT = (rows + 63) >> 6;
    for (int it = 0; it < NT; ++it) {
        const int qb = q0 + (it << 6) + (wid << 4);
        if (qb >= q1) continue;

        int qr = qb + fr;
        if (qr >= q1) qr = q0;
        const u16* Qrow = Qp + ((size_t)b * Tq + qr) * qs + h * 64;
        bf16x8 afq0 = *(const bf16x8*)&Qrow[g * 8];
        bf16x8 afq1 = *(const bf16x8*)&Qrow[32 + g * 8];

        f32x4 acc_o[4] = {};
        float m_r[4] = {-1e30f, -1e30f, -1e30f, -1e30f};
        float lp[4] = {0.f, 0.f, 0.f, 0.f};

        for (int c = 0; c < NC; ++c) {
            const int tk0 = c << 6;
            int NF = (Tkp - tk0) >> 4;
            if (NF > 4) NF = 4;

            f32x4 acc_s[4] = {};
#pragma unroll
            for (int nf = 0; nf < 4; ++nf) {
                if (nf < NF) {
                    const u16* kr = &kl[tk0 + nf * 16 + fr][0];
                    acc_s[nf] = __builtin_amdgcn_mfma_f32_16x16x32_bf16(
                        afq0, *(const bf16x8*)&kr[g * 8], acc_s[nf], 0, 0, 0);
                    acc_s[nf] = __builtin_amdgcn_mfma_f32_16x16x32_bf16(
                        afq1, *(const bf16x8*)&kr[32 + g * 8], acc_s[nf], 0, 0, 0);
                }
            }
            float pm[4] = {-1e30f, -1e30f, -1e30f, -1e30f};
#pragma unroll
            for (int nf = 0; nf < 4; ++nf) {
                if (nf < NF) {
                    const bool cv = (tk0 + nf * 16 + fr) < Tk;
#pragma unroll
                    for (int r = 0; r < 4; ++r) {
                        float sv = acc_s[nf][r] * 0.125f;
                        acc_s[nf][r] = sv;
                        if (cv) pm[r] = fmaxf(pm[r], sv);
                    }
                }
            }
#pragma unroll
            for (int off = 1; off < 16; off <<= 1)
#pragma unroll
                for (int r = 0; r < 4; ++r) pm[r] = fmaxf(pm[r], __shfl_xor(pm[r], off));
            float al[4];
#pragma unroll
            for (int r = 0; r < 4; ++r) {
                float mn = fmaxf(m_r[r], pm[r]);
                al[r] = __expf(m_r[r] - mn);
                m_r[r] = mn;
                lp[r] *= al[r];
            }
#pragma unroll
            for (int nfd = 0; nfd < 4; ++nfd)
#pragma unroll
                for (int r = 0; r < 4; ++r) acc_o[nfd][r] *= al[r];
#pragma unroll
            for (int nf = 0; nf < 4; ++nf) {
                const bool cv = (nf < NF) && ((tk0 + nf * 16 + fr) < Tk);
#pragma unroll
                for (int r = 0; r < 4; ++r) {
                    float w = cv ? __expf(acc_s[nf][r] - m_r[r]) : 0.f;
                    lp[r] += w;
                    pl[wid][g4 + r][nf * 16 + fr] = f2bf(w);
                }
            }
#pragma unroll
            for (int ksp = 0; ksp < 2; ++ksp) {
                bf16x8 ap = *(const bf16x8*)&pl[wid][fr][ksp * 32 + g * 8];
#pragma unroll
                for (int nfd = 0; nfd < 4; ++nfd)
                    acc_o[nfd] = __builtin_amdgcn_mfma_f32_16x16x32_bf16(
                        ap, *(const bf16x8*)&vt[nfd * 16 + fr][tk0 + ksp * 32 + g * 8],
                        acc_o[nfd], 0, 0, 0);
            }
        }
#pragma unroll
        for (int off = 1; off < 16; off <<= 1)
#pragma unroll
            for (int r = 0; r < 4; ++r) lp[r] += __shfl_xor(lp[r], off);
#pragma unroll
        for (int r = 0; r < 4; ++r) {
            int qrow = qb + g4 + r;
            if (qrow < q1) {
                float inv = 1.f / lp[r];
#pragma unroll
                for (int nfd = 0; nfd < 4; ++nfd)
                    Op[((size_t)b * Tq + qrow) * os + h * 64 + nfd * 16 + fr] =
                        f2bf(acc_o[nfd][r] * inv);
            }
        }
    }
}

// =======================================================================================
extern "C" void kernel_launch(void* const* d_in, const int* in_sizes, int n_in,
                              void* d_out, int out_size, void* d_ws, size_t ws_size,
                              hipStream_t stream) {
    const int D = 768, FF = 3072, NB = 64, S = 196, T = 98, NL = 3;
    const int Menc = NB * S;   // 12544
    const int Mdec = NB * T;   // 6272

    auto IN = [&](int i) { return (const float*)d_in[i]; };
    const int* tpos = (const int*)d_in[1];
    const float* spe = IN(2);
    const float* norm_g = IN(3);
    const float* norm_b = IN(4);

    char* base;
    if (ws_size >= ARENA_BYTES) {
        base = (char*)d_ws;
    } else {
        void* sym = nullptr;
        if (hipGetSymbolAddress(&sym, HIP_SYMBOL(g_arena)) == hipSuccess && sym)
            base = (char*)sym;
        else
            base = (char*)d_ws;
    }
    char* pp = base;
    auto alloc = [&](long long bytes) -> void* {
        void* r = (void*)pp;
        pp += (bytes + 255) & ~255LL;
        return r;
    };
    int* flag = (int*)alloc(256);
    int* flagD = flag + 1;

    // ---- single-launch tiled weight conversion ----
    CvTab tab;
    long long tcur = 0;
    int slot = 0;
    auto addcv = [&](const float* src, u16* dst, int K, int N, int L,
                     long long srcLs, long long dstLs) {
        tab.d[slot] = CvD{src, dst, K, N, L, srcLs, dstLs, tcur};
        tcur += (long long)L * (K >> 6) * (N >> 6);
        ++slot;
    };
    auto cvaT = [&](const float* W, int K, int N, int L) -> u16* {
        u16* dst = (u16*)alloc((long long)L * K * N * 2);
        addcv(W, dst, K, N, L, (long long)K * N, (long long)K * N);
        return dst;
    };
    u16* encWqkv = cvaT(IN(7), D, 3 * D, 3);
    u16* encWo = cvaT(IN(9), D, D, 3);
    u16* encW1 = cvaT(IN(13), D, FF, 3);
    u16* encW2 = cvaT(IN(15), FF, D, 3);
    u16* decWqkv = cvaT(IN(19), D, 3 * D, 3);
    u16* decWo = cvaT(IN(21), D, D, 3);
    u16* decW1 = cvaT(IN(25), D, FF, 3);
    u16* decW2 = cvaT(IN(27), FF, D, 3);
    u16* caWq = cvaT(IN(29), D, D, 3);
    u16* caWkv = (u16*)alloc((long long)3 * 2 * D * D * 2);
    addcv(IN(31), caWkv, D, D, 3, (long long)D * D, (long long)2 * D * D);
    addcv(IN(33), caWkv + (long long)D * D, D, D, 3, (long long)D * D, (long long)2 * D * D);
    u16* caWo = cvaT(IN(35), D, D, 3);
    k_wtransT<<<dim3((int)tcur), dim3(256), 0, stream>>>(tab);

    float* bkv0 = (float*)alloc(2 * D * 4);
    float* bkv1 = (float*)alloc(2 * D * 4);
    float* bkv2 = (float*)alloc(2 * D * 4);
    (void)bkv1; (void)bkv2;
    k_bkv<<<dim3(6), dim3(256), 0, stream>>>(IN(32), IN(34), bkv0);

    float* x = (float*)alloc((long long)Menc * D * 4);
    float* q = (float*)alloc((long long)Mdec * D * 4);
    u16* xb = (u16*)alloc((long long)Menc * D * 2);
    u16* qb = (u16*)alloc((long long)Mdec * D * 2);
    u16* hb = (u16*)alloc((long long)Menc * D * 2);
    u16* s1b = (u16*)alloc((long long)Menc * FF * 2);

    hipMemsetAsync(flagD, 0x01, 4, stream);
    k_detect_i64<<<dim3((Mdec / 2 + 255) / 256), dim3(256), 0, stream>>>(tpos, Mdec / 2, flagD);

    // modes: 0 plain->bf16 | 1 res->fp32+bf16 | 2 gelu->bf16 | 3 plain->fp32+bf16
    // Narrow-N path (128x64 tile) for all under-filled N=768 launches (enc + dec).
    auto gemm = [&](int mode, const u16* A, const u16* WT, const float* bias,
                    const float* R, float* Cf, u16* Cb, int M, int N, int K) {
        if (N == 768 && (mode == 1 || mode == 3)) {
            dim3 g(M / 128, N / 64), blk(256);
            if (mode == 1) k_gemmN<false, true, true, true><<<g, blk, 0, stream>>>(A, WT, bias, R, Cf, Cb, M, N, K);
            else           k_gemmN<false, false, true, true><<<g, blk, 0, stream>>>(A, WT, bias, nullptr, Cf, Cb, M, N, K);
            return;
        }
        dim3 g(M / 128, N / 128), blk(256);
        switch (mode) {
            case 0: k_gemmB<false, false, false, true><<<g, blk, 0, stream>>>(A, WT, bias, nullptr, nullptr, Cb, M, N, K); break;
            case 1: k_gemmB<false, true, true, true><<<g, blk, 0, stream>>>(A, WT, bias, R, Cf, Cb, M, N, K); break;
            case 2: k_gemmB<true, false, false, true><<<g, blk, 0, stream>>>(A, WT, bias, nullptr, nullptr, Cb, M, N, K); break;
            case 3: k_gemmB<false, false, true, true><<<g, blk, 0, stream>>>(A, WT, bias, nullptr, Cf, Cb, M, N, K); break;
        }
    };
    auto ln = [&](const float* X, const float* gg, const float* bb, u16* Ob, float* Of, int M) {
        if (Ob) k_ln<0><<<dim3(M), dim3(256), 0, stream>>>(X, gg, bb, Ob, nullptr);
        else    k_ln<1><<<dim3(M), dim3(256), 0, stream>>>(X, gg, bb, nullptr, Of);
    };
    auto attn = [&](const u16* Q, int qs, const u16* Kp, int ks2, const u16* Vp, int vs,
                    u16* O, int Tq, int Tk) {
        int sp = (Tq >= 128) ? 2 : 1;
        k_attnM<<<dim3(NB * 12, sp), dim3(256), 0, stream>>>(Q, qs, Kp, ks2, Vp, vs, O, D, Tq, Tk);
    };

    // pre-norm transformer block. Xin: residual input; Xf/Xb: fp32 residual + bf16 mirror.
    auto tblock = [&](const float* Xin, float* Xf, u16* Xb, int Mtok, int Tseq, int basei,
                      int l, const u16* Wqkv, const u16* Wo, const u16* W1, const u16* W2) {
        const float* ln1g = IN(basei + 0) + l * D;
        const float* ln1b = IN(basei + 1) + l * D;
        const float* bqkv = IN(basei + 3) + l * 3 * D;
        const float* bo = IN(basei + 5) + l * D;
        const float* ln2g = IN(basei + 6) + l * D;
        const float* ln2b = IN(basei + 7) + l * D;
        const float* b1 = IN(basei + 9) + l * FF;
        const float* b2 = IN(basei + 11) + l * D;

        ln(Xin, ln1g, ln1b, hb, nullptr, Mtok);
        gemm(0, hb, Wqkv, bqkv, nullptr, nullptr, s1b, Mtok, 3 * D, D);         // qkv -> bf16
        attn(s1b, 3 * D, s1b + D, 3 * D, s1b + 2 * D, 3 * D, hb, Tseq, Tseq);   // self-attn -> hb
        gemm(1, hb, Wo, bo, Xin, Xf, Xb, Mtok, D, D);                           // Xf = Xin + ao@wo+bo
        ln(Xf, ln2g, ln2b, hb, nullptr, Mtok);
        gemm(2, hb, W1, b1, nullptr, nullptr, s1b, Mtok, FF, D);                // gelu -> bf16
        gemm(1, s1b, W2, b2, Xf, Xf, Xb, Mtok, D, FF);                          // x += ff@w2+b2
    };

    // ---------------- encoder (layer 0 reads ctx directly; no memcpy) ----------------
    for (int l = 0; l < NL; ++l)
        tblock((l == 0) ? IN(0) : x, x, xb, Menc, S, 5, l,
               encWqkv + (long long)l * D * 3 * D, encWo + (long long)l * D * D,
               encW1 + (long long)l * D * FF, encW2 + (long long)l * FF * D);

    // ---------------- decoder ----------------
    k_gatherB<<<dim3(Mdec), dim3(256), 0, stream>>>(spe, tpos, flagD, qb);
    u16* qq = s1b;                                       // [Mdec, D]
    u16* kkvv = s1b + (long long)Mdec * D;               // [Menc, 1536] (kk | vv)
    for (int l = 0; l < NL; ++l) {
        // fused independent pair: qq = qb@wq+bq  AND  kkvv = xb@(wk|wv)+bkv  (one launch)
        {
            const int nb1 = (Mdec / 128) * (D / 128);          // 294
            const int nb2 = (Menc / 128) * (2 * D / 128);      // 1176
            k_gemmD<<<dim3(nb1 + nb2), dim3(256), 0, stream>>>(
                qb, caWq + (long long)l * D * D, IN(30) + l * D, qq, Mdec, D,
                xb, caWkv + (long long)l * 2 * D * D, bkv0 + (long long)l * 1536, kkvv, Menc, 2 * D,
                D, nb1);
        }
        attn(qq, D, kkvv, 2 * D, kkvv + D, 2 * D, hb, T, S);                    // cross-attn
        gemm(3, hb, caWo + (long long)l * D * D, IN(36) + l * D, nullptr, q, qb, Mdec, D, D);
        tblock(q, q, qb, Mdec, T, 17, l,
               decWqkv + (long long)l * D * 3 * D, decWo + (long long)l * D * D,
               decW1 + (long long)l * D * FF, decW2 + (long long)l * FF * D);
    }
    ln(q, norm_g, norm_b, nullptr, (float*)d_out, Mdec);
}

// Round 31
// 2262.144 us; speedup vs baseline: 1.1333x; 1.0082x over previous
//
#include <hip/hip_runtime.h>

typedef unsigned short u16;
typedef __attribute__((ext_vector_type(8))) __bf16 bf16x8;
typedef __attribute__((ext_vector_type(4))) float f32x4;

#define DEV static __device__ __forceinline__

#define ARENA_BYTES 349700096ULL
__device__ __align__(256) char g_arena[ARENA_BYTES];

DEV float bf2f(u16 u) { return __uint_as_float(((unsigned)u) << 16); }
DEV u16 f2bf(float f) {
    unsigned u = __float_as_uint(f);
    return (u16)((u + 0x7fffu + ((u >> 16) & 1u)) >> 16);
}
// tanh-GELU via sigmoid identity + hw exp (proven r17)
DEV float gelu_fast(float x) {
    float x3 = x * x * x;
    float u = 1.5957691216057308f * x + 0.0713548162726009f * x3;
    return x / (1.f + __expf(-u));
}

// ---- async global->LDS, 16B per lane (m97 pattern; lane i -> ldsbase + i*16) ----
DEV void gload16(const u16* gp, u16* lp) {
    __builtin_amdgcn_global_load_lds((const __attribute__((address_space(1))) void*)gp,
                                     (__attribute__((address_space(3))) void*)lp, 16, 0, 0);
}

// ---- target_positions dtype sniff ----
__global__ __launch_bounds__(256) void k_detect_i64(const int* __restrict__ pos, int nhalf,
                                                    int* __restrict__ flagD) {
    int i = blockIdx.x * 256 + threadIdx.x;
    if (i < nhalf && pos[2 * i + 1] != 0) atomicAnd(flagD, 0);
}

// ---- gather rows of spatial_pos_embed -> bf16 (vectorized, proven r22) ----
__global__ __launch_bounds__(256) void k_gatherB(const float* __restrict__ spe,
                                                 const int* __restrict__ pos,
                                                 const int* __restrict__ flagD,
                                                 u16* __restrict__ qb) {
    int row = blockIdx.x;
    int p = (*flagD) ? pos[2 * row] : pos[row];
    p = (p < 0) ? 0 : (p > 195 ? 195 : p);
    const float* src = spe + (size_t)p * 768;
    u16* dst = qb + (size_t)row * 768;
    int j = threadIdx.x;
    if (j < 96) {
        float4 a = *(const float4*)&src[j * 8];
        float4 b = *(const float4*)&src[j * 8 + 4];
        union { u16 u[8]; int4 v; } t;
        t.u[0] = f2bf(a.x); t.u[1] = f2bf(a.y); t.u[2] = f2bf(a.z); t.u[3] = f2bf(a.w);
        t.u[4] = f2bf(b.x); t.u[5] = f2bf(b.y); t.u[6] = f2bf(b.z); t.u[7] = f2bf(b.w);
        *(int4*)&dst[j * 8] = t.v;
    }
}

// ---- LayerNorm over 768 (vectorized, proven r24) ----
template <int OUTF32>
__global__ __launch_bounds__(256) void k_ln(const float* __restrict__ X,
                                            const float* __restrict__ g,
                                            const float* __restrict__ b,
                                            u16* __restrict__ Ob, float* __restrict__ Of) {
    const int row = blockIdx.x, tid = threadIdx.x;
    const float* xr = X + (size_t)row * 768;
    const bool act = tid < 192;
    float4 v = act ? *(const float4*)&xr[tid * 4] : float4{0.f, 0.f, 0.f, 0.f};
    float s = v.x + v.y + v.z + v.w;
    float s2 = v.x * v.x + v.y * v.y + v.z * v.z + v.w * v.w;
#pragma unroll
    for (int off = 32; off; off >>= 1) {
        s += __shfl_xor(s, off);
        s2 += __shfl_xor(s2, off);
    }
    __shared__ float red[8];
    const int wid = tid >> 6, lane = tid & 63;
    if (lane == 0) { red[wid] = s; red[4 + wid] = s2; }
    __syncthreads();
    s = red[0] + red[1] + red[2] + red[3];
    s2 = red[4] + red[5] + red[6] + red[7];
    const float mu = s * (1.f / 768.f);
    const float var = fmaxf(s2 * (1.f / 768.f) - mu * mu, 0.f);
    const float rs = rsqrtf(var + 1e-5f);
    if (act) {
        float4 gg = *(const float4*)&g[tid * 4];
        float4 bb = *(const float4*)&b[tid * 4];
        float y0 = (v.x - mu) * rs * gg.x + bb.x;
        float y1 = (v.y - mu) * rs * gg.y + bb.y;
        float y2 = (v.z - mu) * rs * gg.z + bb.z;
        float y3 = (v.w - mu) * rs * gg.w + bb.w;
        if (OUTF32) {
            *(float4*)&Of[(size_t)row * 768 + tid * 4] = float4{y0, y1, y2, y3};
        } else {
            union { u16 u[4]; int2 v2; } t;
            t.u[0] = f2bf(y0); t.u[1] = f2bf(y1); t.u[2] = f2bf(y2); t.u[3] = f2bf(y3);
            *(int2*)&Ob[(size_t)row * 768 + tid * 4] = t.v2;
        }
    }
}

// ---- single-launch LDS-transpose weight conversion (proven r27) ----
struct CvD { const float* src; u16* dst; int K; int N; int L;
             long long srcLs; long long dstLs; long long tStart; };
struct CvTab { CvD d[12]; };

__global__ __launch_bounds__(256) void k_wtransT(CvTab tab) {
    __shared__ u16 lds[64][65];
    const long long bid = blockIdx.x;
    int di = 0;
#pragma unroll
    for (int i = 1; i < 12; ++i)
        if (bid >= tab.d[i].tStart) di = i;
    const CvD dd = tab.d[di];
    const int tid = threadIdx.x;
    const int ntn = dd.N >> 6;
    const int perL = ntn * (dd.K >> 6);
    const long long tloc = bid - dd.tStart;
    const int l = (int)(tloc / perL);
    const int t = (int)(tloc % perL);
    const int kbase = (t / ntn) << 6;
    const int nbase = (t % ntn) << 6;
    const float* Wl = dd.src + (long long)l * dd.srcLs;
    u16* WTl = dd.dst + (long long)l * dd.dstLs;

    const int rn = tid & 63;
    const int rk0 = tid >> 6;
#pragma unroll
    for (int it = 0; it < 16; ++it) {
        const int k = rk0 + it * 4;
        lds[k][rn] = f2bf(Wl[(size_t)(kbase + k) * dd.N + nbase + rn]);
    }
    __syncthreads();

#pragma unroll
    for (int c = tid; c < 512; c += 256) {
        const int n_local = c >> 3, kc = c & 7;
        union { u16 u[8]; int4 v; } tcv;
#pragma unroll
        for (int j = 0; j < 8; ++j) tcv.u[j] = lds[kc * 8 + j][n_local];
        *(int4*)&WTl[(size_t)(nbase + n_local) * dd.K + kbase + kc * 8] = tcv.v;
    }
}

// ---- bkv assembly (proven r25) ----
__global__ __launch_bounds__(256) void k_bkv(const float* __restrict__ bk,
                                             const float* __restrict__ bv,
                                             float* __restrict__ dst) {
    int l = blockIdx.x >> 1, half = blockIdx.x & 1;
    const float* s = (half ? bv : bk) + l * 768;
    float* d = dst + (long long)l * 1536 + half * 768;
    for (int i = threadIdx.x; i < 768; i += 256) d[i] = s[i];
}

// ---- bf16 MFMA GEMM (r17-proven loop): 128x128 tile, BK=64, dbuf 2-phase prefetch,
//      XOR-swizzled gload_lds staging, bijective XCD block swizzle.
//      r29 epilogue: bf16-only output staged through LDS for wide coalesced stores.
//      (LDS buffers addressed by offset arithmetic, not pointer arrays.) ----
template <bool GELU_, bool RES_, bool OF32, bool OBF>
__global__ __launch_bounds__(256) void k_gemmB(const u16* __restrict__ A,
                                               const u16* __restrict__ BT,
                                               const float* __restrict__ bias,
                                               const float* __restrict__ R,
                                               float* __restrict__ Cf, u16* __restrict__ Cb,
                                               int M, int N, int K) {
    __shared__ __align__(16) u16 smem[4 * 128 * 64];   // A dbuf | B dbuf; epilogue reuses
    const int tid = threadIdx.x;
    const int lane = tid & 63;
    const int wid = tid >> 6;
    const int wm = wid >> 1, wn = wid & 1;

    const int nbx = gridDim.x, nby = gridDim.y;
    const int nwg = nbx * nby;
    const int bid = blockIdx.y * nbx + blockIdx.x;
    const int q8 = nwg >> 3, r8 = nwg & 7;
    const int xcd = bid & 7, pos = bid >> 3;
    const int swz = (xcd < r8 ? xcd * (q8 + 1) : r8 * (q8 + 1) + (xcd - r8) * q8) + pos;
    const int tyy = swz % nby;
    const int txx = swz / nby;

    const int srow = lane >> 3;
    const int sgr = (lane & 7) ^ srow;
    const int fr = lane & 15, g = lane >> 4;
    const int s7 = fr & 7;

    const u16* Ab = A + (size_t)txx * 128 * K + (size_t)srow * K + sgr * 8;
    const u16* Bb = BT + (size_t)tyy * 128 * K + (size_t)srow * K + sgr * 8;

    f32x4 acc[4][4] = {};
    const int nIter = K >> 6;

#pragma unroll
    for (int n = 0; n < 4; ++n) {
        const int rg = wid * 32 + n * 8;
        gload16(Ab + (size_t)rg * K, &smem[rg * 64]);
        gload16(Bb + (size_t)rg * K, &smem[2 * 8192 + rg * 64]);
    }
    __syncthreads();

    int cur = 0;
    for (int t = 0; t < nIter; ++t) {
        if (t + 1 < nIter) {
            const int k0 = (t + 1) << 6;
            const int nb = (cur ^ 1) * 8192;
#pragma unroll
            for (int n = 0; n < 4; ++n) {
                const int rg = wid * 32 + n * 8;
                gload16(Ab + (size_t)rg * K + k0, &smem[nb + rg * 64]);
                gload16(Bb + (size_t)rg * K + k0, &smem[2 * 8192 + nb + rg * 64]);
            }
        }
        const u16* As = &smem[cur * 8192];
        const u16* Bs = &smem[2 * 8192 + cur * 8192];
#pragma unroll
        for (int kk = 0; kk < 2; ++kk) {
            const int gr8 = (((kk * 4 + g) ^ s7) << 3);
            bf16x8 af[4], bfr[4];
#pragma unroll
            for (int i = 0; i < 4; ++i)
                af[i] = *(const bf16x8*)&As[(wm * 64 + i * 16 + fr) * 64 + gr8];
#pragma unroll
            for (int j = 0; j < 4; ++j)
                bfr[j] = *(const bf16x8*)&Bs[(wn * 64 + j * 16 + fr) * 64 + gr8];
#pragma unroll
            for (int i = 0; i < 4; ++i)
#pragma unroll
                for (int j = 0; j < 4; ++j)
                    acc[i][j] = __builtin_amdgcn_mfma_f32_16x16x32_bf16(af[i], bfr[j], acc[i][j], 0, 0, 0);
        }
        __syncthreads();
        cur ^= 1;
    }

    // epilogue. C/D layout: col=lane&15, row=(lane>>4)*4+reg  [HW-verified m89/m91]
    const int g4 = (lane >> 4) * 4;
    if constexpr (!RES_ && !OF32 && OBF) {
        // LDS-staged wide-store path (bit-exact values; 128x136 u16 tile in dead smem)
        u16* lt = smem;
#pragma unroll
        for (int j = 0; j < 4; ++j) {
            const int col = tyy * 128 + wn * 64 + j * 16 + fr;
            const float bc = bias[col];
            const int lcol = wn * 64 + j * 16 + fr;
#pragma unroll
            for (int i = 0; i < 4; ++i) {
#pragma unroll
                for (int r = 0; r < 4; ++r) {
                    const int lrow = wm * 64 + i * 16 + g4 + r;
                    float v = acc[i][j][r] + bc;
                    if (GELU_) v = gelu_fast(v);
                    lt[lrow * 136 + lcol] = f2bf(v);
                }
            }
        }
        __syncthreads();
#pragma unroll
        for (int c = tid; c < 2048; c += 256) {
            const int lrow = c >> 4;
            const int lcol8 = (c & 15) * 8;
            int4 v = *(const int4*)&lt[lrow * 136 + lcol8];
            *(int4*)&Cb[(size_t)(txx * 128 + lrow) * N + tyy * 128 + lcol8] = v;
        }
    } else {
#pragma unroll
        for (int j = 0; j < 4; ++j) {
            const int col = tyy * 128 + wn * 64 + j * 16 + fr;
            const float bc = bias[col];
#pragma unroll
            for (int i = 0; i < 4; ++i) {
#pragma unroll
                for (int r = 0; r < 4; ++r) {
                    const int row = txx * 128 + wm * 64 + i * 16 + g4 + r;
                    float v = acc[i][j][r] + bc;
                    if (GELU_) v = gelu_fast(v);
                    if (RES_)  v += R[(size_t)row * N + col];
                    if (OF32)  Cf[(size_t)row * N + col] = v;
                    if (OBF)   Cb[(size_t)row * N + col] = f2bf(v);
                }
            }
        }
    }
}

// ---- narrow-N GEMM: 128x64 tile for under-filled N=768 launches (proven r28). ----
template <bool GELU_, bool RES_, bool OF32, bool OBF>
__global__ __launch_bounds__(256) void k_gemmN(const u16* __restrict__ A,
                                               const u16* __restrict__ BT,
                                               const float* __restrict__ bias,
                                               const float* __restrict__ R,
                                               float* __restrict__ Cf, u16* __restrict__ Cb,
                                               int M, int N, int K) {
    __shared__ __align__(16) u16 Asm[2][128 * 64];
    __shared__ __align__(16) u16 Bsm[2][64 * 64];
    const int tid = threadIdx.x;
    const int lane = tid & 63;
    const int wid = tid >> 6;
    const int wm = wid >> 1, wn = wid & 1;

    const int nbx = gridDim.x, nby = gridDim.y;   // (M/128, N/64)
    const int nwg = nbx * nby;
    const int bid = blockIdx.y * nbx + blockIdx.x;
    const int q8 = nwg >> 3, r8 = nwg & 7;
    const int xcd = bid & 7, pos = bid >> 3;
    const int swz = (xcd < r8 ? xcd * (q8 + 1) : r8 * (q8 + 1) + (xcd - r8) * q8) + pos;
    const int tyy = swz % nby;
    const int txx = swz / nby;

    const int srow = lane >> 3;
    const int sgr = (lane & 7) ^ srow;
    const int fr = lane & 15, g = lane >> 4;
    const int s7 = fr & 7;

    const u16* Ab = A + (size_t)txx * 128 * K + (size_t)srow * K + sgr * 8;
    const u16* Bb = BT + (size_t)tyy * 64 * K + (size_t)srow * K + sgr * 8;

    f32x4 acc[4][2] = {};
    const int nIter = K >> 6;

#pragma unroll
    for (int n = 0; n < 4; ++n) {
        const int rg = wid * 32 + n * 8;
        gload16(Ab + (size_t)rg * K, &Asm[0][rg * 64]);
    }
#pragma unroll
    for (int n = 0; n < 2; ++n) {
        const int rg = wid * 16 + n * 8;
        gload16(Bb + (size_t)rg * K, &Bsm[0][rg * 64]);
    }
    __syncthreads();

    int cur = 0;
    for (int t = 0; t < nIter; ++t) {
        if (t + 1 < nIter) {
            const int k0 = (t + 1) << 6;
#pragma unroll
            for (int n = 0; n < 4; ++n) {
                const int rg = wid * 32 + n * 8;
                gload16(Ab + (size_t)rg * K + k0, &Asm[cur ^ 1][rg * 64]);
            }
#pragma unroll
            for (int n = 0; n < 2; ++n) {
                const int rg = wid * 16 + n * 8;
                gload16(Bb + (size_t)rg * K + k0, &Bsm[cur ^ 1][rg * 64]);
            }
        }
        const u16* As = &Asm[cur][0];
        const u16* Bs = &Bsm[cur][0];
#pragma unroll
        for (int kk = 0; kk < 2; ++kk) {
            const int gr8 = (((kk * 4 + g) ^ s7) << 3);
            bf16x8 af[4], bfr[2];
#pragma unroll
            for (int i = 0; i < 4; ++i)
                af[i] = *(const bf16x8*)&As[(wm * 64 + i * 16 + fr) * 64 + gr8];
#pragma unroll
            for (int j = 0; j < 2; ++j)
                bfr[j] = *(const bf16x8*)&Bs[(wn * 32 + j * 16 + fr) * 64 + gr8];
#pragma unroll
            for (int i = 0; i < 4; ++i)
#pragma unroll
                for (int j = 0; j < 2; ++j)
                    acc[i][j] = __builtin_amdgcn_mfma_f32_16x16x32_bf16(af[i], bfr[j], acc[i][j], 0, 0, 0);
        }
        __syncthreads();
        cur ^= 1;
    }

    const int g4 = (lane >> 4) * 4;
#pragma unroll
    for (int j = 0; j < 2; ++j) {
        const int col = tyy * 64 + wn * 32 + j * 16 + fr;
        const float bc = bias[col];
#pragma unroll
        for (int i = 0; i < 4; ++i) {
#pragma unroll
            for (int r = 0; r < 4; ++r) {
                const int row = txx * 128 + wm * 64 + i * 16 + g4 + r;
                float v = acc[i][j][r] + bc;
                if (GELU_) v = gelu_fast(v);
                if (RES_)  v += R[(size_t)row * N + col];
                if (OF32)  Cf[(size_t)row * N + col] = v;
                if (OBF)   Cb[(size_t)row * N + col] = f2bf(v);
            }
        }
    }
}

// ---- dual plain-GEMM (proven r25; r29 LDS-staged epilogue, offset addressing) ----
__global__ __launch_bounds__(256) void k_gemmD(const u16* __restrict__ A1,
                                               const u16* __restrict__ W1,
                                               const float* __restrict__ b1,
                                               u16* __restrict__ C1, int M1, int N1,
                                               const u16* __restrict__ A2,
                                               const u16* __restrict__ W2,
                                               const float* __restrict__ b2,
                                               u16* __restrict__ C2, int M2, int N2,
                                               int K, int nb1) {
    __shared__ __align__(16) u16 smem[4 * 128 * 64];
    const int tid = threadIdx.x;
    const int lane = tid & 63;
    const int wid = tid >> 6;
    const int wm = wid >> 1, wn = wid & 1;

    const bool p2 = (int)blockIdx.x >= nb1;
    const u16* A = p2 ? A2 : A1;
    const u16* BT = p2 ? W2 : W1;
    const float* bias = p2 ? b2 : b1;
    u16* Cb = p2 ? C2 : C1;
    const int M = p2 ? M2 : M1;
    const int N = p2 ? N2 : N1;
    const int bidl = (int)blockIdx.x - (p2 ? nb1 : 0);

    const int nbx = M >> 7, nby = N >> 7;
    const int nwg = nbx * nby;
    const int q8 = nwg >> 3, r8 = nwg & 7;
    const int xcd = bidl & 7, pos = bidl >> 3;
    const int swz = (xcd < r8 ? xcd * (q8 + 1) : r8 * (q8 + 1) + (xcd - r8) * q8) + pos;
    const int tyy = swz % nby;
    const int txx = swz / nby;

    const int srow = lane >> 3;
    const int sgr = (lane & 7) ^ srow;
    const int fr = lane & 15, g = lane >> 4;
    const int s7 = fr & 7;

    const u16* Ab = A + (size_t)txx * 128 * K + (size_t)srow * K + sgr * 8;
    const u16* Bb = BT + (size_t)tyy * 128 * K + (size_t)srow * K + sgr * 8;

    f32x4 acc[4][4] = {};
    const int nIter = K >> 6;

#pragma unroll
    for (int n = 0; n < 4; ++n) {
        const int rg = wid * 32 + n * 8;
        gload16(Ab + (size_t)rg * K, &smem[rg * 64]);
        gload16(Bb + (size_t)rg * K, &smem[2 * 8192 + rg * 64]);
    }
    __syncthreads();

    int cur = 0;
    for (int t = 0; t < nIter; ++t) {
        if (t + 1 < nIter) {
            const int k0 = (t + 1) << 6;
            const int nb = (cur ^ 1) * 8192;
#pragma unroll
            for (int n = 0; n < 4; ++n) {
                const int rg = wid * 32 + n * 8;
                gload16(Ab + (size_t)rg * K + k0, &smem[nb + rg * 64]);
                gload16(Bb + (size_t)rg * K + k0, &smem[2 * 8192 + nb + rg * 64]);
            }
        }
        const u16* As = &smem[cur * 8192];
        const u16* Bs = &smem[2 * 8192 + cur * 8192];
#pragma unroll
        for (int kk = 0; kk < 2; ++kk) {
            const int gr8 = (((kk * 4 + g) ^ s7) << 3);
            bf16x8 af[4], bfr[4];
#pragma unroll
            for (int i = 0; i < 4; ++i)
                af[i] = *(const bf16x8*)&As[(wm * 64 + i * 16 + fr) * 64 + gr8];
#pragma unroll
            for (int j = 0; j < 4; ++j)
                bfr[j] = *(const bf16x8*)&Bs[(wn * 64 + j * 16 + fr) * 64 + gr8];
#pragma unroll
            for (int i = 0; i < 4; ++i)
#pragma unroll
                for (int j = 0; j < 4; ++j)
                    acc[i][j] = __builtin_amdgcn_mfma_f32_16x16x32_bf16(af[i], bfr[j], acc[i][j], 0, 0, 0);
        }
        __syncthreads();
        cur ^= 1;
    }

    // LDS-staged wide-store epilogue (bf16-only output; bit-exact values)
    const int g4 = (lane >> 4) * 4;
    u16* lt = smem;
#pragma unroll
    for (int j = 0; j < 4; ++j) {
        const int col = tyy * 128 + wn * 64 + j * 16 + fr;
        const float bc = bias[col];
        const int lcol = wn * 64 + j * 16 + fr;
#pragma unroll
        for (int i = 0; i < 4; ++i) {
#pragma unroll
            for (int r = 0; r < 4; ++r) {
                const int lrow = wm * 64 + i * 16 + g4 + r;
                lt[lrow * 136 + lcol] = f2bf(acc[i][j][r] + bc);
            }
        }
    }
    __syncthreads();
#pragma unroll
    for (int c = tid; c < 2048; c += 256) {
        const int lrow = c >> 4;
        const int lcol8 = (c & 15) * 8;
        int4 v = *(const int4*)&lt[lrow * 136 + lcol8];
        *(int4*)&Cb[(size_t)(txx * 128 + lrow) * N + tyy * 128 + lcol8] = v;
    }
}

// ---- MFMA flash attention, bf16 in/out (r22 structure; Q split across gridDim.y) ----
__global__ __launch_bounds__(256) void k_attnM(const u16* __restrict__ Qp, int qs,
                                               const u16* __restrict__ Kp, int ks,
                                               const u16* __restrict__ Vp, int vs,
                                               u16* __restrict__ Op, int os,
                                               int Tq, int Tk) {
    __shared__ u16 kl[208][72];
    __shared__ u16 vt[64][272];
    __shared__ u16 pl[4][16][72];
    const int bh = blockIdx.x, b = bh / 12, h = bh % 12;
    const int tid = threadIdx.x, lane = tid & 63, wid = tid >> 6;
    const int fr = lane & 15, g = lane >> 4, g4 = g * 4;

    const int chunk = (Tq + gridDim.y - 1) / gridDim.y;
    const int q0 = blockIdx.y * chunk;
    int q1 = q0 + chunk; if (q1 > Tq) q1 = Tq;
    if (q0 >= Tq) return;

    const int Tkp = (Tk + 15) & ~15;
    const int NC = (Tkp + 63) >> 6;
    const int TC = NC << 6;

    const int4 zero4 = {0, 0, 0, 0};
    for (int c = tid; c < Tkp * 8; c += 256) {
        int r = c >> 3, j = c & 7;
        int4 v = (r < Tk) ? *(const int4*)&Kp[((size_t)b * Tk + r) * ks + h * 64 + j * 8]
                          : zero4;
        *(int4*)&kl[r][j * 8] = v;
    }
    for (int c = tid; c < TC * 8; c += 256) {
        int t = c >> 3, j = c & 7;
        union { u16 u[8]; int4 v; } w;
        w.v = (t < Tk) ? *(const int4*)&Vp[((size_t)b * Tk + t) * vs + h * 64 + j * 8]
                       : zero4;
#pragma unroll
        for (int i = 0; i < 8; ++i) vt[j * 8 + i][t] = w.u[i];
    }
    __syncthreads();

    const int rows = q1 - q0;
    const int NT = (rows + 63) >> 6;
    for (int it = 0; it < NT; ++it) {
        const int qb = q0 + (it << 6) + (wid << 4);
        if (qb >= q1) continue;

        int qr = qb + fr;
        if (qr >= q1) qr = q0;
        const u16* Qrow = Qp + ((size_t)b * Tq + qr) * qs + h * 64;
        bf16x8 afq0 = *(const bf16x8*)&Qrow[g * 8];
        bf16x8 afq1 = *(const bf16x8*)&Qrow[32 + g * 8];

        f32x4 acc_o[4] = {};
        float m_r[4] = {-1e30f, -1e30f, -1e30f, -1e30f};
        float lp[4] = {0.f, 0.f, 0.f, 0.f};

        for (int c = 0; c < NC; ++c) {
            const int tk0 = c << 6;
            int NF = (Tkp - tk0) >> 4;
            if (NF > 4) NF = 4;

            f32x4 acc_s[4] = {};
#pragma unroll
            for (int nf = 0; nf < 4; ++nf) {
                if (nf < NF) {
                    const u16* kr = &kl[tk0 + nf * 16 + fr][0];
                    acc_s[nf] = __builtin_amdgcn_mfma_f32_16x16x32_bf16(
                        afq0, *(const bf16x8*)&kr[g * 8], acc_s[nf], 0, 0, 0);
                    acc_s[nf] = __builtin_amdgcn_mfma_f32_16x16x32_bf16(
                        afq1, *(const bf16x8*)&kr[32 + g * 8], acc_s[nf], 0, 0, 0);
                }
            }
            float pm[4] = {-1e30f, -1e30f, -1e30f, -1e30f};
#pragma unroll
            for (int nf = 0; nf < 4; ++nf) {
                if (nf < NF) {
                    const bool cv = (tk0 + nf * 16 + fr) < Tk;
#pragma unroll
                    for (int r = 0; r < 4; ++r) {
                        float sv = acc_s[nf][r] * 0.125f;
                        acc_s[nf][r] = sv;
                        if (cv) pm[r] = fmaxf(pm[r], sv);
                    }
                }
            }
#pragma unroll
            for (int off = 1; off < 16; off <<= 1)
#pragma unroll
                for (int r = 0; r < 4; ++r) pm[r] = fmaxf(pm[r], __shfl_xor(pm[r], off));
            float al[4];
#pragma unroll
            for (int r = 0; r < 4; ++r) {
                float mn = fmaxf(m_r[r], pm[r]);
                al[r] = __expf(m_r[r] - mn);
                m_r[r] = mn;
                lp[r] *= al[r];
            }
#pragma unroll
            for (int nfd = 0; nfd < 4; ++nfd)
#pragma unroll
                for (int r = 0; r < 4; ++r) acc_o[nfd][r] *= al[r];
#pragma unroll
            for (int nf = 0; nf < 4; ++nf) {
                const bool cv = (nf < NF) && ((tk0 + nf * 16 + fr) < Tk);
#pragma unroll
                for (int r = 0; r < 4; ++r) {
                    float w = cv ? __expf(acc_s[nf][r] - m_r[r]) : 0.f;
                    lp[r] += w;
                    pl[wid][g4 + r][nf * 16 + fr] = f2bf(w);
                }
            }
#pragma unroll
            for (int ksp = 0; ksp < 2; ++ksp) {
                bf16x8 ap = *(const bf16x8*)&pl[wid][fr][ksp * 32 + g * 8];
#pragma unroll
                for (int nfd = 0; nfd < 4; ++nfd)
                    acc_o[nfd] = __builtin_amdgcn_mfma_f32_16x16x32_bf16(
                        ap, *(const bf16x8*)&vt[nfd * 16 + fr][tk0 + ksp * 32 + g * 8],
                        acc_o[nfd], 0, 0, 0);
            }
        }
#pragma unroll
        for (int off = 1; off < 16; off <<= 1)
#pragma unroll
            for (int r = 0; r < 4; ++r) lp[r] += __shfl_xor(lp[r], off);
#pragma unroll
        for (int r = 0; r < 4; ++r) {
            int qrow = qb + g4 + r;
            if (qrow < q1) {
                float inv = 1.f / lp[r];
#pragma unroll
                for (int nfd = 0; nfd < 4; ++nfd)
                    Op[((size_t)b * Tq + qrow) * os + h * 64 + nfd * 16 + fr] =
                        f2bf(acc_o[nfd][r] * inv);
            }
        }
    }
}

// =======================================================================================
extern "C" void kernel_launch(void* const* d_in, const int* in_sizes, int n_in,
                              void* d_out, int out_size, void* d_ws, size_t ws_size,
                              hipStream_t stream) {
    const int D = 768, FF = 3072, NB = 64, S = 196, T = 98, NL = 3;
    const int Menc = NB * S;   // 12544
    const int Mdec = NB * T;   // 6272

    auto IN = [&](int i) { return (const float*)d_in[i]; };
    const int* tpos = (const int*)d_in[1];
    const float* spe = IN(2);
    const float* norm_g = IN(3);
    const float* norm_b = IN(4);

    char* base;
    if (ws_size >= ARENA_BYTES) {
        base = (char*)d_ws;
    } else {
        void* sym = nullptr;
        if (hipGetSymbolAddress(&sym, HIP_SYMBOL(g_arena)) == hipSuccess && sym)
            base = (char*)sym;
        else
            base = (char*)d_ws;
    }
    char* pp = base;
    auto alloc = [&](long long bytes) -> void* {
        void* r = (void*)pp;
        pp += (bytes + 255) & ~255LL;
        return r;
    };
    int* flag = (int*)alloc(256);
    int* flagD = flag + 1;

    // ---- single-launch tiled weight conversion ----
    CvTab tab;
    long long tcur = 0;
    int slot = 0;
    auto addcv = [&](const float* src, u16* dst, int K, int N, int L,
                     long long srcLs, long long dstLs) {
        tab.d[slot] = CvD{src, dst, K, N, L, srcLs, dstLs, tcur};
        tcur += (long long)L * (K >> 6) * (N >> 6);
        ++slot;
    };
    auto cvaT = [&](const float* W, int K, int N, int L) -> u16* {
        u16* dst = (u16*)alloc((long long)L * K * N * 2);
        addcv(W, dst, K, N, L, (long long)K * N, (long long)K * N);
        return dst;
    };
    u16* encWqkv = cvaT(IN(7), D, 3 * D, 3);
    u16* encWo = cvaT(IN(9), D, D, 3);
    u16* encW1 = cvaT(IN(13), D, FF, 3);
    u16* encW2 = cvaT(IN(15), FF, D, 3);
    u16* decWqkv = cvaT(IN(19), D, 3 * D, 3);
    u16* decWo = cvaT(IN(21), D, D, 3);
    u16* decW1 = cvaT(IN(25), D, FF, 3);
    u16* decW2 = cvaT(IN(27), FF, D, 3);
    u16* caWq = cvaT(IN(29), D, D, 3);
    u16* caWkv = (u16*)alloc((long long)3 * 2 * D * D * 2);
    addcv(IN(31), caWkv, D, D, 3, (long long)D * D, (long long)2 * D * D);
    addcv(IN(33), caWkv + (long long)D * D, D, D, 3, (long long)D * D, (long long)2 * D * D);
    u16* caWo = cvaT(IN(35), D, D, 3);
    k_wtransT<<<dim3((int)tcur), dim3(256), 0, stream>>>(tab);

    float* bkv0 = (float*)alloc(2 * D * 4);
    float* bkv1 = (float*)alloc(2 * D * 4);
    float* bkv2 = (float*)alloc(2 * D * 4);
    (void)bkv1; (void)bkv2;
    k_bkv<<<dim3(6), dim3(256), 0, stream>>>(IN(32), IN(34), bkv0);

    float* x = (float*)alloc((long long)Menc * D * 4);
    float* q = (float*)alloc((long long)Mdec * D * 4);
    u16* xb = (u16*)alloc((long long)Menc * D * 2);
    u16* qb = (u16*)alloc((long long)Mdec * D * 2);
    u16* hb = (u16*)alloc((long long)Menc * D * 2);
    u16* s1b = (u16*)alloc((long long)Menc * FF * 2);

    hipMemsetAsync(flagD, 0x01, 4, stream);
    k_detect_i64<<<dim3((Mdec / 2 + 255) / 256), dim3(256), 0, stream>>>(tpos, Mdec / 2, flagD);

    // modes: 0 plain->bf16 | 1 res->fp32+bf16 | 2 gelu->bf16 | 3 plain->fp32+bf16
    auto gemm = [&](int mode, const u16* A, const u16* WT, const float* bias,
                    const float* R, float* Cf, u16* Cb, int M, int N, int K) {
        if (N == 768 && (mode == 1 || mode == 3)) {
            dim3 g(M / 128, N / 64), blk(256);
            if (mode == 1) k_gemmN<false, true, true, true><<<g, blk, 0, stream>>>(A, WT, bias, R, Cf, Cb, M, N, K);
            else           k_gemmN<false, false, true, true><<<g, blk, 0, stream>>>(A, WT, bias, nullptr, Cf, Cb, M, N, K);
            return;
        }
        dim3 g(M / 128, N / 128), blk(256);
        switch (mode) {
            case 0: k_gemmB<false, false, false, true><<<g, blk, 0, stream>>>(A, WT, bias, nullptr, nullptr, Cb, M, N, K); break;
            case 1: k_gemmB<false, true, true, true><<<g, blk, 0, stream>>>(A, WT, bias, R, Cf, Cb, M, N, K); break;
            case 2: k_gemmB<true, false, false, true><<<g, blk, 0, stream>>>(A, WT, bias, nullptr, nullptr, Cb, M, N, K); break;
            case 3: k_gemmB<false, false, true, true><<<g, blk, 0, stream>>>(A, WT, bias, nullptr, Cf, Cb, M, N, K); break;
        }
    };
    auto ln = [&](const float* X, const float* gg, const float* bb, u16* Ob, float* Of, int M) {
        if (Ob) k_ln<0><<<dim3(M), dim3(256), 0, stream>>>(X, gg, bb, Ob, nullptr);
        else    k_ln<1><<<dim3(M), dim3(256), 0, stream>>>(X, gg, bb, nullptr, Of);
    };
    auto attn = [&](const u16* Q, int qs, const u16* Kp, int ks2, const u16* Vp, int vs,
                    u16* O, int Tq, int Tk) {
        int sp = (Tq >= 128) ? 2 : 1;
        k_attnM<<<dim3(NB * 12, sp), dim3(256), 0, stream>>>(Q, qs, Kp, ks2, Vp, vs, O, D, Tq, Tk);
    };

    // pre-norm transformer block. Xin: residual input; Xf/Xb: fp32 residual + bf16 mirror.
    auto tblock = [&](const float* Xin, float* Xf, u16* Xb, int Mtok, int Tseq, int basei,
                      int l, const u16* Wqkv, const u16* Wo, const u16* W1, const u16* W2) {
        const float* ln1g = IN(basei + 0) + l * D;
        const float* ln1b = IN(basei + 1) + l * D;
        const float* bqkv = IN(basei + 3) + l * 3 * D;
        const float* bo = IN(basei + 5) + l * D;
        const float* ln2g = IN(basei + 6) + l * D;
        const float* ln2b = IN(basei + 7) + l * D;
        const float* b1 = IN(basei + 9) + l * FF;
        const float* b2 = IN(basei + 11) + l * D;

        ln(Xin, ln1g, ln1b, hb, nullptr, Mtok);
        gemm(0, hb, Wqkv, bqkv, nullptr, nullptr, s1b, Mtok, 3 * D, D);         // qkv -> bf16
        attn(s1b, 3 * D, s1b + D, 3 * D, s1b + 2 * D, 3 * D, hb, Tseq, Tseq);   // self-attn -> hb
        gemm(1, hb, Wo, bo, Xin, Xf, Xb, Mtok, D, D);                           // Xf = Xin + ao@wo+bo
        ln(Xf, ln2g, ln2b, hb, nullptr, Mtok);
        gemm(2, hb, W1, b1, nullptr, nullptr, s1b, Mtok, FF, D);                // gelu -> bf16
        gemm(1, s1b, W2, b2, Xf, Xf, Xb, Mtok, D, FF);                          // x += ff@w2+b2
    };

    // ---------------- encoder (layer 0 reads ctx directly; no memcpy) ----------------
    for (int l = 0; l < NL; ++l)
        tblock((l == 0) ? IN(0) : x, x, xb, Menc, S, 5, l,
               encWqkv + (long long)l * D * 3 * D, encWo + (long long)l * D * D,
               encW1 + (long long)l * D * FF, encW2 + (long long)l * FF * D);

    // ---------------- decoder ----------------
    k_gatherB<<<dim3(Mdec), dim3(256), 0, stream>>>(spe, tpos, flagD, qb);
    u16* qq = s1b;                                       // [Mdec, D]
    u16* kkvv = s1b + (long long)Mdec * D;               // [Menc, 1536] (kk | vv)
    for (int l = 0; l < NL; ++l) {
        // fused independent pair: qq = qb@wq+bq  AND  kkvv = xb@(wk|wv)+bkv  (one launch)
        {
            const int nb1 = (Mdec / 128) * (D / 128);          // 294
            const int nb2 = (Menc / 128) * (2 * D / 128);      // 1176
            k_gemmD<<<dim3(nb1 + nb2), dim3(256), 0, stream>>>(
                qb, caWq + (long long)l * D * D, IN(30) + l * D, qq, Mdec, D,
                xb, caWkv + (long long)l * 2 * D * D, bkv0 + (long long)l * 1536, kkvv, Menc, 2 * D,
                D, nb1);
        }
        attn(qq, D, kkvv, 2 * D, kkvv + D, 2 * D, hb, T, S);                    // cross-attn
        gemm(3, hb, caWo + (long long)l * D * D, IN(36) + l * D, nullptr, q, qb, Mdec, D, D);
        tblock(q, q, qb, Mdec, T, 17, l,
               decWqkv + (long long)l * D * 3 * D, decWo + (long long)l * D * D,
               decW1 + (long long)l * D * FF, decW2 + (long long)l * FF * D);
    }
    ln(q, norm_g, norm_b, nullptr, (float*)d_out, Mdec);
}